// Round 2
// baseline (435.565 us; speedup 1.0000x reference)
//
#include <hip/hip_runtime.h>
#include <hip/hip_bf16.h>

// Problem: B=2, T=2048, C=2048, H=16, HD=128.
// Round 6 (resubmit; round-1 bench was lost to a GPU-broker timeout).
// Pipelined GEMMs: the m97-class 2-barrier K-loop capped both dense
// GEMMs at ~690 TF (MfmaUtil 30%, HBM 15% -> barrier-drain-bound). Replaced
// with a 128x256-tile, 8-wave, BK=64 kernel in the 8-phase family:
//   - 2 counted phases per K-tile (one per 32-wide kk half, 16 MFMA each)
//   - global_load_lds prefetch 2 K-tiles deep, s_waitcnt vmcnt(6) (never 0)
//   - raw s_barrier (no implicit vmcnt drain), s_setprio(1) around MFMA
//   - LDS [2buf][2kk][rows][32] with XOR chunk swizzle (slot(r,c) holds
//     global (r, c^((r>>1)&3))); ds_read_b128 start-banks spread 8x8 = optimal
// Prefetch ledger (per-wave load groups of 3 = {A,Blo,Bhi}):
//   entering tile t: outstanding {k1(t), k0(t+1)} = 6
//   ph1 stages k1(t+1) -> 9; vmcnt(6) retires k1(t)   (read by ph2)
//   ph2 stages k0(t+2) -> 9; vmcnt(6) retires k0(t+1) (read by next ph1)
// Stage targets are barrier-dead at issue (>=1 full barrier pair after the
// region's last read). Tails: tile NT-2 (skip S2, vmcnt 6/3), NT-1 (0/none).
// Grids tail-free: QKV (24x32)=768 = 3x256 CUs; out-proj (8x32)=256 = 1x256.

typedef __attribute__((ext_vector_type(8))) short short8;   // 8 bf16 MFMA A/B frag
typedef __attribute__((ext_vector_type(4))) float f32x4;    // MFMA C/D frag

#define B_  2
#define T_  2048
#define C_  2048
#define H_  16
#define HD_ 128

#define BARRIER() asm volatile("s_barrier" ::: "memory")
#define LGKM0()   asm volatile("s_waitcnt lgkmcnt(0)" ::: "memory")

template<int N> __device__ __forceinline__ void vmwait() {
  if constexpr (N == 6)      asm volatile("s_waitcnt vmcnt(6)" ::: "memory");
  else if constexpr (N == 3) asm volatile("s_waitcnt vmcnt(3)" ::: "memory");
  else if constexpr (N == 0) asm volatile("s_waitcnt vmcnt(0)" ::: "memory");
  // N < 0: no wait
}

__device__ __forceinline__ float bf2f(unsigned short u) {
  union { unsigned int i; float f; } v; v.i = ((unsigned int)u) << 16; return v.f;
}
__device__ __forceinline__ unsigned short f2bf(float f) {
  union { float f; unsigned int i; } v; v.f = f;
  unsigned int x = v.i;
  return (unsigned short)((x + 0x7fffu + ((x >> 16) & 1u)) >> 16);  // RNE
}
__device__ __forceinline__ float fexp2(float x) {
#if __has_builtin(__builtin_amdgcn_exp2f)
  return __builtin_amdgcn_exp2f(x);
#else
  return exp2f(x);
#endif
}

// async 16B global->LDS; lds base wave-uniform, lane l lands at base + l*16.
__device__ __forceinline__ void gll16(const unsigned short* g, unsigned short* lds_base) {
  __builtin_amdgcn_global_load_lds(
      (const __attribute__((address_space(1))) void*)g,
      (__attribute__((address_space(3))) void*)lds_base, 16, 0, 0);
}

// ---------------------------------------------------------------------------
// f32 -> bf16 elementwise convert, 4 elems/thread.
// ---------------------------------------------------------------------------
__global__ void cvt_k(const float* __restrict__ src, unsigned short* __restrict__ dst, int n4)
{
  int i = blockIdx.x * blockDim.x + threadIdx.x;
  if (i < n4) {
    float4 v = ((const float4*)src)[i];
    ushort4 h;
    h.x = f2bf(v.x); h.y = f2bf(v.y); h.z = f2bf(v.z); h.w = f2bf(v.w);
    ((ushort4*)dst)[i] = h;
  }
}

// ---------------------------------------------------------------------------
// One K-tile (BK=64) of the pipelined 128x256 GEMM: two counted phases.
// CB: LDS buffer (= tile parity). S1/S2: stage guards. V1/V2: vmcnt values.
// ---------------------------------------------------------------------------
template<int CB, bool S1, bool S2, int V1, int V2>
__device__ __forceinline__ void ktile(
    int t,
    const unsigned short* __restrict__ Ag,
    const unsigned short* __restrict__ Bg, int K,
    unsigned short (&LA)[2][2][128][32],
    unsigned short (&LB)[2][2][256][32],
    f32x4 (&acc)[4][4],
    int wave, int wm, int wn, int l15, int csw8, int sra, int sc)
{
  short8 af[4], bf[4];
  const int ca = sc ^ ((sra >> 1) & 3);          // source chunk swizzle

  // ---- phase 1 : kk = 0 ----
#pragma unroll
  for (int m = 0; m < 4; ++m)
    af[m] = *(const short8*)&LA[CB][0][wm * 64 + m * 16 + l15][csw8];
#pragma unroll
  for (int n = 0; n < 4; ++n)
    bf[n] = *(const short8*)&LB[CB][0][wn * 64 + n * 16 + l15][csw8];
  if constexpr (S1) {                            // k1-halves of tile t+1 -> buf CB^1
    const int kb = (t + 1) * 64 + 32;
    gll16(Ag + (size_t)sra * K + kb + ca * 8,         &LA[CB ^ 1][1][wave * 16][0]);
    gll16(Bg + (size_t)sra * K + kb + ca * 8,         &LB[CB ^ 1][1][wave * 16][0]);
    gll16(Bg + (size_t)(128 + sra) * K + kb + ca * 8, &LB[CB ^ 1][1][128 + wave * 16][0]);
  }
  BARRIER();
  LGKM0();
  __builtin_amdgcn_s_setprio(1);
#pragma unroll
  for (int m = 0; m < 4; ++m)
#pragma unroll
    for (int n = 0; n < 4; ++n)
      acc[m][n] = __builtin_amdgcn_mfma_f32_16x16x32_bf16(af[m], bf[n], acc[m][n], 0, 0, 0);
  __builtin_amdgcn_s_setprio(0);
  vmwait<V1>();
  BARRIER();

  // ---- phase 2 : kk = 1 ----
#pragma unroll
  for (int m = 0; m < 4; ++m)
    af[m] = *(const short8*)&LA[CB][1][wm * 64 + m * 16 + l15][csw8];
#pragma unroll
  for (int n = 0; n < 4; ++n)
    bf[n] = *(const short8*)&LB[CB][1][wn * 64 + n * 16 + l15][csw8];
  if constexpr (S2) {                            // k0-halves of tile t+2 -> buf CB
    const int kb = (t + 2) * 64;
    gll16(Ag + (size_t)sra * K + kb + ca * 8,         &LA[CB][0][wave * 16][0]);
    gll16(Bg + (size_t)sra * K + kb + ca * 8,         &LB[CB][0][wave * 16][0]);
    gll16(Bg + (size_t)(128 + sra) * K + kb + ca * 8, &LB[CB][0][128 + wave * 16][0]);
  }
  BARRIER();
  LGKM0();
  __builtin_amdgcn_s_setprio(1);
#pragma unroll
  for (int m = 0; m < 4; ++m)
#pragma unroll
    for (int n = 0; n < 4; ++n)
      acc[m][n] = __builtin_amdgcn_mfma_f32_16x16x32_bf16(af[m], bf[n], acc[m][n], 0, 0, 0);
  __builtin_amdgcn_s_setprio(0);
  vmwait<V2>();
  BARRIER();
}

// ---------------------------------------------------------------------------
// Pipelined NT GEMM: C[M][N] = A[M][K]*Bw[N][K]^T + bias.
// 128x256 tile, 8 waves (2Mx4N, 64x64 each), 1D grid with XCD-chunked swizzle.
// MODE 0: f32 row-major store. MODE 1: bf16 qkv scatter (V transposed).
// MFMA layouts (HW-verified m89/m91): A: A[m=l15][k=quad*8+j];
// B: B[k=quad*8+j][n=l15]; C/D: col=l15, row=quad*4+reg.
// ---------------------------------------------------------------------------
template<int MODE>
__global__ __launch_bounds__(512, 2)
void gemm128(const unsigned short* __restrict__ A,
             const unsigned short* __restrict__ Bw,
             const float* __restrict__ bias,
             float* __restrict__ Cout,
             unsigned short* __restrict__ Qb,
             unsigned short* __restrict__ Kb,
             unsigned short* __restrict__ Vb,
             int N, int K)
{
  __shared__ unsigned short LA[2][2][128][32];   // 32 KB
  __shared__ unsigned short LB[2][2][256][32];   // 64 KB

  const int tid  = threadIdx.x;
  const int wave = tid >> 6, lane = tid & 63;
  const int quad = lane >> 4, l15 = lane & 15;
  const int wm = wave >> 2, wn = wave & 3;                 // 2 x 4 wave grid
  const int csw8 = (quad ^ ((l15 >> 1) & 3)) * 8;          // read chunk swizzle
  const int sra = tid >> 2, sc = tid & 3;                  // staging row/chunk

  // XCD-chunked bijective block swizzle (gridDim.x % 8 == 0 for our launches)
  const int ntx = N >> 8;
  const int q8  = gridDim.x >> 3;
  const int id  = blockIdx.x;
  const int sw  = (id & 7) * q8 + (id >> 3);
  const int n0  = (sw % ntx) * 256;
  const int m0  = (sw / ntx) * 128;

  const unsigned short* Ag = A  + (size_t)m0 * K;
  const unsigned short* Bg = Bw + (size_t)n0 * K;

  f32x4 acc[4][4];
#pragma unroll
  for (int i = 0; i < 4; i++)
#pragma unroll
    for (int j = 0; j < 4; j++) acc[i][j] = (f32x4){0.f, 0.f, 0.f, 0.f};

  // prologue: stage k0(0), k1(0), k0(1); retire k0(0); leave 6 in flight
  {
    const int ca = sc ^ ((sra >> 1) & 3);
    gll16(Ag + (size_t)sra * K + ca * 8,              &LA[0][0][wave * 16][0]);
    gll16(Bg + (size_t)sra * K + ca * 8,              &LB[0][0][wave * 16][0]);
    gll16(Bg + (size_t)(128 + sra) * K + ca * 8,      &LB[0][0][128 + wave * 16][0]);
    gll16(Ag + (size_t)sra * K + 32 + ca * 8,         &LA[0][1][wave * 16][0]);
    gll16(Bg + (size_t)sra * K + 32 + ca * 8,         &LB[0][1][wave * 16][0]);
    gll16(Bg + (size_t)(128 + sra) * K + 32 + ca * 8, &LB[0][1][128 + wave * 16][0]);
    gll16(Ag + (size_t)sra * K + 64 + ca * 8,         &LA[1][0][wave * 16][0]);
    gll16(Bg + (size_t)sra * K + 64 + ca * 8,         &LB[1][0][wave * 16][0]);
    gll16(Bg + (size_t)(128 + sra) * K + 64 + ca * 8, &LB[1][0][128 + wave * 16][0]);
    asm volatile("s_waitcnt vmcnt(6)" ::: "memory");
    BARRIER();
  }

  const int NT = K >> 6;   // 32 for K=2048 (even, >=4)
#pragma unroll 1
  for (int t = 0; t + 2 < NT; t += 2) {
    ktile<0, true, true, 6, 6>(t,     Ag, Bg, K, LA, LB, acc, wave, wm, wn, l15, csw8, sra, sc);
    ktile<1, true, true, 6, 6>(t + 1, Ag, Bg, K, LA, LB, acc, wave, wm, wn, l15, csw8, sra, sc);
  }
  ktile<0, true,  false, 6,  3>(NT - 2, Ag, Bg, K, LA, LB, acc, wave, wm, wn, l15, csw8, sra, sc);
  ktile<1, false, false, 0, -1>(NT - 1, Ag, Bg, K, LA, LB, acc, wave, wm, wn, l15, csw8, sra, sc);

  if constexpr (MODE == 0) {
#pragma unroll
    for (int mi = 0; mi < 4; mi++)
#pragma unroll
      for (int n = 0; n < 4; n++) {
        int col = n0 + wn * 64 + n * 16 + l15;
        float bv = bias[col];
#pragma unroll
        for (int r = 0; r < 4; r++) {
          int row = m0 + wm * 64 + mi * 16 + quad * 4 + r;
          Cout[(size_t)row * N + col] = acc[mi][n][r] + bv;
        }
      }
  } else {
    const int which = n0 >> 11;                  // block never straddles Q/K/V
    unsigned short* P = (which == 0) ? Qb : (which == 1) ? Kb : Vb;
#pragma unroll
    for (int mi = 0; mi < 4; mi++)
#pragma unroll
      for (int n = 0; n < 4; n++) {
        int col = n0 + wn * 64 + n * 16 + l15;
        float bv = bias[col];
        int h = (col >> 7) & 15, d = col & 127;
#pragma unroll
        for (int r = 0; r < 4; r++) {
          int m = m0 + wm * 64 + mi * 16 + quad * 4 + r;
          int b = m >> 11, t = m & (T_ - 1);
          size_t addr = (which == 2)
              ? ((size_t)((b * H_ + h) * HD_ + d)) * T_ + t    // V transposed
              : ((size_t)((b * H_ + h) * T_ + t)) * HD_ + d;   // Q,K row-major
          P[addr] = f2bf(acc[mi][n][r] + bv);
        }
      }
  }
}

// ---------------------------------------------------------------------------
// RoPE in-place on bf16 Q and K, layout [B*H*T][128].
// theta_p = 10000^(-(2**p)/128) (faithful 2**p quirk), pos 1-indexed,
// pair (d, d+64). Q pre-scaled by 1/sqrt(HD)*log2(e) for exp2 softmax.
// ---------------------------------------------------------------------------
__global__ void rope_k(unsigned short* __restrict__ Q, unsigned short* __restrict__ K)
{
  const int tid = threadIdx.x;
  const int w = tid >> 6, l = tid & 63;
  const int r = blockIdx.x * 4 + w;
  const int t = r & (T_ - 1);
  const float pos = (float)(t + 1);
  const float theta = expf(-exp2f((float)l) * 0.07195578415606394f); // ln(1e4)/128
  const float ang = pos * theta;
  const float c = cosf(ang), s = sinf(ang);
  const float QS = 0.08838834764831845f * 1.4426950408889634f; // 1/sqrt(128)*log2(e)
  const size_t base = (size_t)r * HD_;

  float q0 = bf2f(Q[base + l]), q1 = bf2f(Q[base + l + 64]);
  Q[base + l]      = f2bf((q0 * c - q1 * s) * QS);
  Q[base + l + 64] = f2bf((q1 * c + q0 * s) * QS);
  float k0 = bf2f(K[base + l]), k1 = bf2f(K[base + l + 64]);
  K[base + l]      = f2bf(k0 * c - k1 * s);
  K[base + l + 64] = f2bf(k1 * c + k0 * s);
}

// ---------------------------------------------------------------------------
// Flash-style causal attention (round-4 structure + XOR-swizzled K/V tiles).
// Grid 512 = (bh 32, XCD-swizzled) x (qpair 16); each block does Q-tiles
// qp*64 and (31-qp)*64 -> uniform 33 k-iters. 4 waves x 16 rows.
// Kl [64][128]: slot (r,c16) holds global (r, c16^(r&15)); read col-chunk
// (kc*4+quad)^l15. Vl [128][64]: slot (r,c8) holds (r, c8^(r&7)); read
// (kc*4+quad)^(l15&7). Both -> residual 2-way bank aliasing (free).
// ---------------------------------------------------------------------------
__global__ __launch_bounds__(256, 2)
void attn_k(const unsigned short* __restrict__ Q,
            const unsigned short* __restrict__ K,
            const unsigned short* __restrict__ Vt_g,
            unsigned short* __restrict__ AO)
{
  __shared__ unsigned short Kl[64 * 128];
  __shared__ unsigned short Vl[128 * 64];
  __shared__ unsigned short Pl[4 * 16 * 72];

  const int tid  = threadIdx.x;
  const int wave = tid >> 6, lane = tid & 63;
  const int quad = lane >> 4, l15 = lane & 15;
  const int blk = blockIdx.x;
  const int bh = (blk & 7) + 8 * ((blk >> 3) & 3);
  const int qp = (blk >> 5) & 15;
  const unsigned short* Qh = Q    + (size_t)bh * T_ * HD_;
  const unsigned short* Kh = K    + (size_t)bh * T_ * HD_;
  const unsigned short* Vh = Vt_g + (size_t)bh * T_ * HD_;  // [d][t]
  const int b = bh >> 4, h = bh & 15;

#pragma unroll
  for (int tile = 0; tile < 2; tile++) {
    const int q0 = (tile == 0 ? qp : 31 - qp) * 64;
    const int wq = q0 + wave * 16;
    short8 qf[4];
#pragma unroll
    for (int kc = 0; kc < 4; kc++)
      qf[kc] = *(const short8*)&Qh[(size_t)(wq + l15) * HD_ + kc * 32 + quad * 8];

    f32x4 oacc[8];
#pragma unroll
    for (int n = 0; n < 8; n++) oacc[n] = (f32x4){0.f, 0.f, 0.f, 0.f};
    float mst[4], lst[4];
#pragma unroll
    for (int r = 0; r < 4; r++) { mst[r] = -1e30f; lst[r] = 0.f; }

    const int niter = (q0 >> 6) + 1;
    for (int it = 0; it < niter; it++) {
      const int kt = it * 64;
      __syncthreads();
      // stage K [64][128] and V^T [128][64], source-col XOR swizzle
#pragma unroll
      for (int i = 0; i < 4; i++) {
        int cc = i * 256 + wave * 64 + lane;  // slot id 0..1023
        int kr = cc >> 4, kcs = (cc & 15) ^ (kr & 15);
        gll16(Kh + (size_t)(kt + kr) * HD_ + kcs * 8, &Kl[(i * 4 + wave) * 512]);
        int vr = cc >> 3, vcs = (cc & 7) ^ (vr & 7);
        gll16(Vh + (size_t)vr * T_ + kt + vcs * 8, &Vl[(i * 4 + wave) * 512]);
      }
      __syncthreads();

      // S' = (Q*s) K^T
      f32x4 sa[4];
#pragma unroll
      for (int ni = 0; ni < 4; ni++) sa[ni] = (f32x4){0.f, 0.f, 0.f, 0.f};
#pragma unroll
      for (int kc = 0; kc < 4; kc++) {
        const int cswK = (((kc * 4 + quad) ^ l15) * 8);
        short8 bfr[4];
#pragma unroll
        for (int ni = 0; ni < 4; ni++)
          bfr[ni] = *(const short8*)&Kl[(ni * 16 + l15) * HD_ + cswK];
#pragma unroll
        for (int ni = 0; ni < 4; ni++)
          sa[ni] = __builtin_amdgcn_mfma_f32_16x16x32_bf16(qf[kc], bfr[ni], sa[ni], 0, 0, 0);
      }

      if (kt == q0) {   // causal mask, diagonal tile only (uniform branch)
#pragma unroll
        for (int ni = 0; ni < 4; ni++) {
          int gcol = kt + ni * 16 + l15;
#pragma unroll
          for (int r = 0; r < 4; r++) {
            int grow = wq + quad * 4 + r;
            if (gcol > grow) sa[ni][r] = -1e30f;
          }
        }
      }

      // online softmax, base-2
      float rmax[4] = {-1e30f, -1e30f, -1e30f, -1e30f};
#pragma unroll
      for (int ni = 0; ni < 4; ni++)
#pragma unroll
        for (int r = 0; r < 4; r++) rmax[r] = fmaxf(rmax[r], sa[ni][r]);
#pragma unroll
      for (int r = 0; r < 4; r++)
#pragma unroll
        for (int off = 1; off < 16; off <<= 1)
          rmax[r] = fmaxf(rmax[r], __shfl_xor(rmax[r], off));
      float alpha[4];
#pragma unroll
      for (int r = 0; r < 4; r++) {
        float mnew = fmaxf(mst[r], rmax[r]);
        alpha[r] = fexp2(fminf(mst[r] - mnew, 0.f));
        mst[r] = mnew;
      }
      float rsum[4] = {0.f, 0.f, 0.f, 0.f};
#pragma unroll
      for (int ni = 0; ni < 4; ni++)
#pragma unroll
        for (int r = 0; r < 4; r++) {
          float p = fexp2(fminf(sa[ni][r] - mst[r], 0.f));
          sa[ni][r] = p;
          rsum[r] += p;
        }
#pragma unroll
      for (int r = 0; r < 4; r++) {
#pragma unroll
        for (int off = 1; off < 16; off <<= 1)
          rsum[r] += __shfl_xor(rsum[r], off);
        lst[r] = lst[r] * alpha[r] + rsum[r];
      }
#pragma unroll
      for (int nv = 0; nv < 8; nv++)
#pragma unroll
        for (int r = 0; r < 4; r++) oacc[nv][r] *= alpha[r];
#pragma unroll
      for (int ni = 0; ni < 4; ni++)
#pragma unroll
        for (int r = 0; r < 4; r++)
          Pl[wave * 16 * 72 + (quad * 4 + r) * 72 + ni * 16 + l15] = f2bf(sa[ni][r]);
      __syncthreads();

      // O += P V
      short8 pf[2];
#pragma unroll
      for (int kc = 0; kc < 2; kc++)
        pf[kc] = *(const short8*)&Pl[wave * 16 * 72 + l15 * 72 + kc * 32 + quad * 8];
#pragma unroll
      for (int kc = 0; kc < 2; kc++) {
        const int cswV = (((kc * 4 + quad) ^ (l15 & 7)) * 8);
#pragma unroll
        for (int nv = 0; nv < 8; nv++) {
          short8 vb = *(const short8*)&Vl[(nv * 16 + l15) * 64 + cswV];
          oacc[nv] = __builtin_amdgcn_mfma_f32_16x16x32_bf16(pf[kc], vb, oacc[nv], 0, 0, 0);
        }
      }
    }

    float linv[4];
#pragma unroll
    for (int r = 0; r < 4; r++) linv[r] = 1.0f / fmaxf(lst[r], 1e-20f);
#pragma unroll
    for (int nv = 0; nv < 8; nv++)
#pragma unroll
      for (int r = 0; r < 4; r++) {
        int t = wq + quad * 4 + r;
        int d = nv * 16 + l15;
        AO[((size_t)(b * T_ + t)) * C_ + h * HD_ + d] = f2bf(oacc[nv][r] * linv[r]);
      }
  }
}

// ---------------------------------------------------------------------------
// Fallback GEMM (f32 sources converted during staging) — only if ws too small.
// ---------------------------------------------------------------------------
template<int A32, int B32, int MODE>
__global__ __launch_bounds__(256, 2)
void gemm_nt(const void* __restrict__ Ap, const void* __restrict__ Bp,
             const float* __restrict__ bias,
             float* __restrict__ Cout,
             unsigned short* __restrict__ Qb,
             unsigned short* __restrict__ Kb,
             unsigned short* __restrict__ Vb,
             int N, int K)
{
  __shared__ unsigned short Al[128 * 72];
  __shared__ unsigned short Bl[128 * 72];
  const int tid  = threadIdx.x;
  const int wave = tid >> 6, lane = tid & 63;
  const int quad = lane >> 4, l15 = lane & 15;
  const int wm = wave >> 1, wn = wave & 1;
  const int n0 = blockIdx.x * 128, m0 = blockIdx.y * 128;

  f32x4 acc[4][4];
#pragma unroll
  for (int i = 0; i < 4; i++)
#pragma unroll
    for (int j = 0; j < 4; j++) acc[i][j] = (f32x4){0.f, 0.f, 0.f, 0.f};

  for (int k0 = 0; k0 < K; k0 += 64) {
    __syncthreads();
    if constexpr (A32) {
      const float* A = (const float*)Ap;
#pragma unroll
      for (int i = 0; i < 8; i++) {
        int cid = tid + i * 256;
        int r = cid >> 4, c = cid & 15;
        float4 v = *(const float4*)&A[(size_t)(m0 + r) * K + k0 + c * 4];
        ushort4 hh;
        hh.x = f2bf(v.x); hh.y = f2bf(v.y); hh.z = f2bf(v.z); hh.w = f2bf(v.w);
        *(ushort4*)&Al[r * 72 + c * 4] = hh;
      }
    } else {
      const unsigned short* A = (const unsigned short*)Ap;
#pragma unroll
      for (int i = 0; i < 4; i++) {
        int cid = tid + i * 256;
        int r = cid >> 3, c = cid & 7;
        *(float4*)&Al[r * 72 + c * 8] =
            *(const float4*)&A[(size_t)(m0 + r) * K + k0 + c * 8];
      }
    }
    if constexpr (B32) {
      const float* Bm = (const float*)Bp;
#pragma unroll
      for (int i = 0; i < 8; i++) {
        int cid = tid + i * 256;
        int r = cid >> 4, c = cid & 15;
        float4 v = *(const float4*)&Bm[(size_t)(n0 + r) * K + k0 + c * 4];
        ushort4 hh;
        hh.x = f2bf(v.x); hh.y = f2bf(v.y); hh.z = f2bf(v.z); hh.w = f2bf(v.w);
        *(ushort4*)&Bl[r * 72 + c * 4] = hh;
      }
    } else {
      const unsigned short* Bm = (const unsigned short*)Bp;
#pragma unroll
      for (int i = 0; i < 4; i++) {
        int cid = tid + i * 256;
        int r = cid >> 3, c = cid & 7;
        *(float4*)&Bl[r * 72 + c * 8] =
            *(const float4*)&Bm[(size_t)(n0 + r) * K + k0 + c * 8];
      }
    }
    __syncthreads();
#pragma unroll
    for (int kc = 0; kc < 2; kc++) {
      short8 af[4], bfr[4];
#pragma unroll
      for (int mi = 0; mi < 4; mi++)
        af[mi] = *(const short8*)&Al[(wm * 64 + mi * 16 + l15) * 72 + kc * 32 + quad * 8];
#pragma unroll
      for (int ni = 0; ni < 4; ni++)
        bfr[ni] = *(const short8*)&Bl[(wn * 64 + ni * 16 + l15) * 72 + kc * 32 + quad * 8];
#pragma unroll
      for (int mi = 0; mi < 4; mi++)
#pragma unroll
        for (int ni = 0; ni < 4; ni++)
          acc[mi][ni] = __builtin_amdgcn_mfma_f32_16x16x32_bf16(af[mi], bfr[ni], acc[mi][ni], 0, 0, 0);
    }
  }

  if constexpr (MODE == 0) {
#pragma unroll
    for (int mi = 0; mi < 4; mi++)
#pragma unroll
      for (int ni = 0; ni < 4; ni++) {
        int col = n0 + wn * 64 + ni * 16 + l15;
        float bv = bias[col];
#pragma unroll
        for (int r = 0; r < 4; r++) {
          int row = m0 + wm * 64 + mi * 16 + quad * 4 + r;
          Cout[(size_t)row * N + col] = acc[mi][ni][r] + bv;
        }
      }
  } else {
    int which = n0 >> 11;
    int h = (n0 >> 7) & 15;
    unsigned short* P = (which == 0) ? Qb : (which == 1) ? Kb : Vb;
#pragma unroll
    for (int mi = 0; mi < 4; mi++)
#pragma unroll
      for (int ni = 0; ni < 4; ni++) {
        int d = wn * 64 + ni * 16 + l15;
        float bv = bias[n0 + d];
#pragma unroll
        for (int r = 0; r < 4; r++) {
          int m = m0 + wm * 64 + mi * 16 + quad * 4 + r;
          int b = m >> 11, t = m & (T_ - 1);
          size_t addr = (which == 2)
              ? ((size_t)((b * H_ + h) * HD_ + d)) * T_ + t
              : ((size_t)((b * H_ + h) * T_ + t)) * HD_ + d;
          P[addr] = f2bf(acc[mi][ni][r] + bv);
        }
      }
  }
}

// ---------------------------------------------------------------------------
extern "C" void kernel_launch(void* const* d_in, const int* in_sizes, int n_in,
                              void* d_out, int out_size, void* d_ws, size_t ws_size,
                              hipStream_t stream)
{
  const float* x    = (const float*)d_in[0];  // [2,2048,2048] f32
  const float* Wqkv = (const float*)d_in[1];  // [6144,2048]   f32
  const float* bqkv = (const float*)d_in[2];  // [6144]        f32
  const float* Wo   = (const float*)d_in[3];  // [2048,2048]   f32
  const float* bo   = (const float*)d_in[4];  // [2048]        f32
  float* out = (float*)d_out;                 // [2,2048,2048] f32

  const size_t SZ   = (size_t)B_ * H_ * T_ * HD_;   // 8,388,608
  const size_t NX   = SZ;
  const size_t NWQ  = (size_t)3 * C_ * C_;
  const size_t NWO  = (size_t)C_ * C_;
  unsigned short* ws = (unsigned short*)d_ws;

  dim3 blk(256, 1, 1);
  dim3 blk512(512, 1, 1);
  const size_t need = (NX + NWQ + 3 * SZ) * sizeof(unsigned short);  // 92.3 MB

  if (ws_size >= need) {
    unsigned short* xb    = ws;
    unsigned short* Wqkvb = xb + NX;
    unsigned short* Qb    = Wqkvb + NWQ;
    unsigned short* Kb    = Qb + SZ;
    unsigned short* Vb    = Kb + SZ;      // transposed [bh][d][t]
    unsigned short* AO    = xb;           // alias: x dead after QKV GEMM
    unsigned short* Wob   = Wqkvb;        // alias: Wqkv dead after QKV GEMM

    cvt_k<<<dim3((unsigned)(NX / 1024)), blk, 0, stream>>>(x, xb, (int)(NX / 4));
    cvt_k<<<dim3((unsigned)(NWQ / 1024)), blk, 0, stream>>>(Wqkv, Wqkvb, (int)(NWQ / 4));
    // QKV: M=4096, N=6144 -> (24 x 32) = 768 blocks = exactly 3 x 256 CUs
    gemm128<1><<<dim3(768, 1, 1), blk512, 0, stream>>>(
        xb, Wqkvb, bqkv, nullptr, Qb, Kb, Vb, 6144, 2048);
    cvt_k<<<dim3((unsigned)(NWO / 1024)), blk, 0, stream>>>(Wo, Wob, (int)(NWO / 4));
    rope_k<<<dim3((B_ * H_ * T_) / 4, 1, 1), blk, 0, stream>>>(Qb, Kb);
    attn_k<<<dim3(512, 1, 1), blk, 0, stream>>>(Qb, Kb, Vb, AO);
    // out-proj: M=4096, N=2048 -> (8 x 32) = 256 blocks = exactly 1 x 256 CUs
    gemm128<0><<<dim3(256, 1, 1), blk512, 0, stream>>>(
        AO, Wob, bo, out, nullptr, nullptr, nullptr, 2048, 2048);
  } else {
    unsigned short* Qb = ws;
    unsigned short* Kb = Qb + SZ;
    unsigned short* Vb = Kb + SZ;
    unsigned short* AO = Vb + SZ;
    gemm_nt<1, 1, 1><<<dim3(48, 32, 1), blk, 0, stream>>>(
        (const void*)x, (const void*)Wqkv, bqkv, nullptr, Qb, Kb, Vb, 6144, 2048);
    rope_k<<<dim3((B_ * H_ * T_) / 4, 1, 1), blk, 0, stream>>>(Qb, Kb);
    attn_k<<<dim3(512, 1, 1), blk, 0, stream>>>(Qb, Kb, Vb, AO);
    gemm_nt<0, 1, 0><<<dim3(16, 32, 1), blk, 0, stream>>>(
        (const void*)AO, (const void*)Wo, bo, out, nullptr, nullptr, nullptr, 2048, 2048);
  }
}

// Round 3
// 434.368 us; speedup vs baseline: 1.0028x; 1.0028x over previous
//
#include <hip/hip_runtime.h>
#include <hip/hip_bf16.h>

// Problem: B=2, T=2048, C=2048, H=16, HD=128.
// Round 7: fix the round-6 regression. Counters showed FETCH 103->341 MB:
// the manual XCD-chunk swizzle gave each XCD full-N sweeps (24 MB B panel
// set thrashing a 4 MB L2). The old 2D grid's implicit mod-8 dispatch had
// partitioned N across XCDs (3 MB B-band per XCD, L2-resident). Revert to
// plain 2D grid (x=n-tile fastest, gridDim.x % 8 == 0 keeps the implicit
// N-partition); keep the pipelined ktile structure unchanged:
//   - 2 counted phases per K-tile (one per 32-wide kk half, 16 MFMA each)
//   - global_load_lds prefetch 2 K-tiles deep, s_waitcnt vmcnt(6) (never 0)
//   - raw s_barrier (no implicit vmcnt drain), s_setprio(1) around MFMA
//   - LDS [2buf][2kk][rows][32] with XOR chunk swizzle; 0 bank conflicts (r2)
// Prefetch ledger (per-wave load groups of 3 = {A,Blo,Bhi}):
//   entering tile t: outstanding {k1(t), k0(t+1)} = 6
//   ph1 stages k1(t+1) -> 9; vmcnt(6) retires k1(t)   (read by ph2)
//   ph2 stages k0(t+2) -> 9; vmcnt(6) retires k0(t+1) (read by next ph1)
// Tails: tile NT-2 (skip S2, vmcnt 6/3), NT-1 (no stage, vmcnt 0/none).
// Grids tail-free: QKV (24x32)=768 = 3x256 CUs; out-proj (8x32)=256 = 1x256.

typedef __attribute__((ext_vector_type(8))) short short8;   // 8 bf16 MFMA A/B frag
typedef __attribute__((ext_vector_type(4))) float f32x4;    // MFMA C/D frag

#define B_  2
#define T_  2048
#define C_  2048
#define H_  16
#define HD_ 128

#define BARRIER() asm volatile("s_barrier" ::: "memory")
#define LGKM0()   asm volatile("s_waitcnt lgkmcnt(0)" ::: "memory")

template<int N> __device__ __forceinline__ void vmwait() {
  if constexpr (N == 6)      asm volatile("s_waitcnt vmcnt(6)" ::: "memory");
  else if constexpr (N == 3) asm volatile("s_waitcnt vmcnt(3)" ::: "memory");
  else if constexpr (N == 0) asm volatile("s_waitcnt vmcnt(0)" ::: "memory");
  // N < 0: no wait
}

__device__ __forceinline__ float bf2f(unsigned short u) {
  union { unsigned int i; float f; } v; v.i = ((unsigned int)u) << 16; return v.f;
}
__device__ __forceinline__ unsigned short f2bf(float f) {
  union { float f; unsigned int i; } v; v.f = f;
  unsigned int x = v.i;
  return (unsigned short)((x + 0x7fffu + ((x >> 16) & 1u)) >> 16);  // RNE
}
__device__ __forceinline__ float fexp2(float x) {
#if __has_builtin(__builtin_amdgcn_exp2f)
  return __builtin_amdgcn_exp2f(x);
#else
  return exp2f(x);
#endif
}

// async 16B global->LDS; lds base wave-uniform, lane l lands at base + l*16.
__device__ __forceinline__ void gll16(const unsigned short* g, unsigned short* lds_base) {
  __builtin_amdgcn_global_load_lds(
      (const __attribute__((address_space(1))) void*)g,
      (__attribute__((address_space(3))) void*)lds_base, 16, 0, 0);
}

// ---------------------------------------------------------------------------
// f32 -> bf16 elementwise convert, 4 elems/thread.
// ---------------------------------------------------------------------------
__global__ void cvt_k(const float* __restrict__ src, unsigned short* __restrict__ dst, int n4)
{
  int i = blockIdx.x * blockDim.x + threadIdx.x;
  if (i < n4) {
    float4 v = ((const float4*)src)[i];
    ushort4 h;
    h.x = f2bf(v.x); h.y = f2bf(v.y); h.z = f2bf(v.z); h.w = f2bf(v.w);
    ((ushort4*)dst)[i] = h;
  }
}

// ---------------------------------------------------------------------------
// One K-tile (BK=64) of the pipelined 128x256 GEMM: two counted phases.
// CB: LDS buffer (= tile parity). S1/S2: stage guards. V1/V2: vmcnt values.
// ---------------------------------------------------------------------------
template<int CB, bool S1, bool S2, int V1, int V2>
__device__ __forceinline__ void ktile(
    int t,
    const unsigned short* __restrict__ Ag,
    const unsigned short* __restrict__ Bg, int K,
    unsigned short (&LA)[2][2][128][32],
    unsigned short (&LB)[2][2][256][32],
    f32x4 (&acc)[4][4],
    int wave, int wm, int wn, int l15, int csw8, int sra, int sc)
{
  short8 af[4], bf[4];
  const int ca = sc ^ ((sra >> 1) & 3);          // source chunk swizzle

  // ---- phase 1 : kk = 0 ----
#pragma unroll
  for (int m = 0; m < 4; ++m)
    af[m] = *(const short8*)&LA[CB][0][wm * 64 + m * 16 + l15][csw8];
#pragma unroll
  for (int n = 0; n < 4; ++n)
    bf[n] = *(const short8*)&LB[CB][0][wn * 64 + n * 16 + l15][csw8];
  if constexpr (S1) {                            // k1-halves of tile t+1 -> buf CB^1
    const int kb = (t + 1) * 64 + 32;
    gll16(Ag + (size_t)sra * K + kb + ca * 8,         &LA[CB ^ 1][1][wave * 16][0]);
    gll16(Bg + (size_t)sra * K + kb + ca * 8,         &LB[CB ^ 1][1][wave * 16][0]);
    gll16(Bg + (size_t)(128 + sra) * K + kb + ca * 8, &LB[CB ^ 1][1][128 + wave * 16][0]);
  }
  BARRIER();
  LGKM0();
  __builtin_amdgcn_s_setprio(1);
#pragma unroll
  for (int m = 0; m < 4; ++m)
#pragma unroll
    for (int n = 0; n < 4; ++n)
      acc[m][n] = __builtin_amdgcn_mfma_f32_16x16x32_bf16(af[m], bf[n], acc[m][n], 0, 0, 0);
  __builtin_amdgcn_s_setprio(0);
  vmwait<V1>();
  BARRIER();

  // ---- phase 2 : kk = 1 ----
#pragma unroll
  for (int m = 0; m < 4; ++m)
    af[m] = *(const short8*)&LA[CB][1][wm * 64 + m * 16 + l15][csw8];
#pragma unroll
  for (int n = 0; n < 4; ++n)
    bf[n] = *(const short8*)&LB[CB][1][wn * 64 + n * 16 + l15][csw8];
  if constexpr (S2) {                            // k0-halves of tile t+2 -> buf CB
    const int kb = (t + 2) * 64;
    gll16(Ag + (size_t)sra * K + kb + ca * 8,         &LA[CB][0][wave * 16][0]);
    gll16(Bg + (size_t)sra * K + kb + ca * 8,         &LB[CB][0][wave * 16][0]);
    gll16(Bg + (size_t)(128 + sra) * K + kb + ca * 8, &LB[CB][0][128 + wave * 16][0]);
  }
  BARRIER();
  LGKM0();
  __builtin_amdgcn_s_setprio(1);
#pragma unroll
  for (int m = 0; m < 4; ++m)
#pragma unroll
    for (int n = 0; n < 4; ++n)
      acc[m][n] = __builtin_amdgcn_mfma_f32_16x16x32_bf16(af[m], bf[n], acc[m][n], 0, 0, 0);
  __builtin_amdgcn_s_setprio(0);
  vmwait<V2>();
  BARRIER();
}

// ---------------------------------------------------------------------------
// Pipelined NT GEMM: C[M][N] = A[M][K]*Bw[N][K]^T + bias.
// 128x256 tile, 8 waves (2Mx4N, 64x64 each). Plain 2D grid: x = n-tile
// (fastest; gridDim.x % 8 == 0 -> implicit XCD N-partition, B-band
// L2-resident), y = m-tile.
// MODE 0: f32 row-major store. MODE 1: bf16 qkv scatter (V transposed).
// MFMA layouts (HW-verified m89/m91): A: A[m=l15][k=quad*8+j];
// B: B[k=quad*8+j][n=l15]; C/D: col=l15, row=quad*4+reg.
// ---------------------------------------------------------------------------
template<int MODE>
__global__ __launch_bounds__(512, 2)
void gemm128(const unsigned short* __restrict__ A,
             const unsigned short* __restrict__ Bw,
             const float* __restrict__ bias,
             float* __restrict__ Cout,
             unsigned short* __restrict__ Qb,
             unsigned short* __restrict__ Kb,
             unsigned short* __restrict__ Vb,
             int N, int K)
{
  __shared__ unsigned short LA[2][2][128][32];   // 32 KB
  __shared__ unsigned short LB[2][2][256][32];   // 64 KB

  const int tid  = threadIdx.x;
  const int wave = tid >> 6, lane = tid & 63;
  const int quad = lane >> 4, l15 = lane & 15;
  const int wm = wave >> 2, wn = wave & 3;                 // 2 x 4 wave grid
  const int csw8 = (quad ^ ((l15 >> 1) & 3)) * 8;          // read chunk swizzle
  const int sra = tid >> 2, sc = tid & 3;                  // staging row/chunk

  const int n0 = blockIdx.x * 256;
  const int m0 = blockIdx.y * 128;

  const unsigned short* Ag = A  + (size_t)m0 * K;
  const unsigned short* Bg = Bw + (size_t)n0 * K;

  f32x4 acc[4][4];
#pragma unroll
  for (int i = 0; i < 4; i++)
#pragma unroll
    for (int j = 0; j < 4; j++) acc[i][j] = (f32x4){0.f, 0.f, 0.f, 0.f};

  // prologue: stage k0(0), k1(0), k0(1); retire k0(0); leave 6 in flight
  {
    const int ca = sc ^ ((sra >> 1) & 3);
    gll16(Ag + (size_t)sra * K + ca * 8,              &LA[0][0][wave * 16][0]);
    gll16(Bg + (size_t)sra * K + ca * 8,              &LB[0][0][wave * 16][0]);
    gll16(Bg + (size_t)(128 + sra) * K + ca * 8,      &LB[0][0][128 + wave * 16][0]);
    gll16(Ag + (size_t)sra * K + 32 + ca * 8,         &LA[0][1][wave * 16][0]);
    gll16(Bg + (size_t)sra * K + 32 + ca * 8,         &LB[0][1][wave * 16][0]);
    gll16(Bg + (size_t)(128 + sra) * K + 32 + ca * 8, &LB[0][1][128 + wave * 16][0]);
    gll16(Ag + (size_t)sra * K + 64 + ca * 8,         &LA[1][0][wave * 16][0]);
    gll16(Bg + (size_t)sra * K + 64 + ca * 8,         &LB[1][0][wave * 16][0]);
    gll16(Bg + (size_t)(128 + sra) * K + 64 + ca * 8, &LB[1][0][128 + wave * 16][0]);
    asm volatile("s_waitcnt vmcnt(6)" ::: "memory");
    BARRIER();
  }

  const int NT = K >> 6;   // 32 for K=2048 (even, >=4)
#pragma unroll 1
  for (int t = 0; t + 2 < NT; t += 2) {
    ktile<0, true, true, 6, 6>(t,     Ag, Bg, K, LA, LB, acc, wave, wm, wn, l15, csw8, sra, sc);
    ktile<1, true, true, 6, 6>(t + 1, Ag, Bg, K, LA, LB, acc, wave, wm, wn, l15, csw8, sra, sc);
  }
  ktile<0, true,  false, 6,  3>(NT - 2, Ag, Bg, K, LA, LB, acc, wave, wm, wn, l15, csw8, sra, sc);
  ktile<1, false, false, 0, -1>(NT - 1, Ag, Bg, K, LA, LB, acc, wave, wm, wn, l15, csw8, sra, sc);

  if constexpr (MODE == 0) {
#pragma unroll
    for (int mi = 0; mi < 4; mi++)
#pragma unroll
      for (int n = 0; n < 4; n++) {
        int col = n0 + wn * 64 + n * 16 + l15;
        float bv = bias[col];
#pragma unroll
        for (int r = 0; r < 4; r++) {
          int row = m0 + wm * 64 + mi * 16 + quad * 4 + r;
          Cout[(size_t)row * N + col] = acc[mi][n][r] + bv;
        }
      }
  } else {
    const int which = n0 >> 11;                  // block never straddles Q/K/V
    unsigned short* P = (which == 0) ? Qb : (which == 1) ? Kb : Vb;
#pragma unroll
    for (int mi = 0; mi < 4; mi++)
#pragma unroll
      for (int n = 0; n < 4; n++) {
        int col = n0 + wn * 64 + n * 16 + l15;
        float bv = bias[col];
        int h = (col >> 7) & 15, d = col & 127;
#pragma unroll
        for (int r = 0; r < 4; r++) {
          int m = m0 + wm * 64 + mi * 16 + quad * 4 + r;
          int b = m >> 11, t = m & (T_ - 1);
          size_t addr = (which == 2)
              ? ((size_t)((b * H_ + h) * HD_ + d)) * T_ + t    // V transposed
              : ((size_t)((b * H_ + h) * T_ + t)) * HD_ + d;   // Q,K row-major
          P[addr] = f2bf(acc[mi][n][r] + bv);
        }
      }
  }
}

// ---------------------------------------------------------------------------
// RoPE in-place on bf16 Q and K, layout [B*H*T][128].
// theta_p = 10000^(-(2**p)/128) (faithful 2**p quirk), pos 1-indexed,
// pair (d, d+64). Q pre-scaled by 1/sqrt(HD)*log2(e) for exp2 softmax.
// ---------------------------------------------------------------------------
__global__ void rope_k(unsigned short* __restrict__ Q, unsigned short* __restrict__ K)
{
  const int tid = threadIdx.x;
  const int w = tid >> 6, l = tid & 63;
  const int r = blockIdx.x * 4 + w;
  const int t = r & (T_ - 1);
  const float pos = (float)(t + 1);
  const float theta = expf(-exp2f((float)l) * 0.07195578415606394f); // ln(1e4)/128
  const float ang = pos * theta;
  const float c = cosf(ang), s = sinf(ang);
  const float QS = 0.08838834764831845f * 1.4426950408889634f; // 1/sqrt(128)*log2(e)
  const size_t base = (size_t)r * HD_;

  float q0 = bf2f(Q[base + l]), q1 = bf2f(Q[base + l + 64]);
  Q[base + l]      = f2bf((q0 * c - q1 * s) * QS);
  Q[base + l + 64] = f2bf((q1 * c + q0 * s) * QS);
  float k0 = bf2f(K[base + l]), k1 = bf2f(K[base + l + 64]);
  K[base + l]      = f2bf(k0 * c - k1 * s);
  K[base + l + 64] = f2bf(k1 * c + k0 * s);
}

// ---------------------------------------------------------------------------
// Flash-style causal attention (round-4 structure + XOR-swizzled K/V tiles).
// Grid 512 = (bh 32, XCD-swizzled) x (qpair 16); each block does Q-tiles
// qp*64 and (31-qp)*64 -> uniform 33 k-iters. 4 waves x 16 rows.
// Kl [64][128]: slot (r,c16) holds global (r, c16^(r&15)); read col-chunk
// (kc*4+quad)^l15. Vl [128][64]: slot (r,c8) holds (r, c8^(r&7)); read
// (kc*4+quad)^(l15&7). Both -> residual 2-way bank aliasing (free).
// ---------------------------------------------------------------------------
__global__ __launch_bounds__(256, 2)
void attn_k(const unsigned short* __restrict__ Q,
            const unsigned short* __restrict__ K,
            const unsigned short* __restrict__ Vt_g,
            unsigned short* __restrict__ AO)
{
  __shared__ unsigned short Kl[64 * 128];
  __shared__ unsigned short Vl[128 * 64];
  __shared__ unsigned short Pl[4 * 16 * 72];

  const int tid  = threadIdx.x;
  const int wave = tid >> 6, lane = tid & 63;
  const int quad = lane >> 4, l15 = lane & 15;
  const int blk = blockIdx.x;
  const int bh = (blk & 7) + 8 * ((blk >> 3) & 3);
  const int qp = (blk >> 5) & 15;
  const unsigned short* Qh = Q    + (size_t)bh * T_ * HD_;
  const unsigned short* Kh = K    + (size_t)bh * T_ * HD_;
  const unsigned short* Vh = Vt_g + (size_t)bh * T_ * HD_;  // [d][t]
  const int b = bh >> 4, h = bh & 15;

#pragma unroll
  for (int tile = 0; tile < 2; tile++) {
    const int q0 = (tile == 0 ? qp : 31 - qp) * 64;
    const int wq = q0 + wave * 16;
    short8 qf[4];
#pragma unroll
    for (int kc = 0; kc < 4; kc++)
      qf[kc] = *(const short8*)&Qh[(size_t)(wq + l15) * HD_ + kc * 32 + quad * 8];

    f32x4 oacc[8];
#pragma unroll
    for (int n = 0; n < 8; n++) oacc[n] = (f32x4){0.f, 0.f, 0.f, 0.f};
    float mst[4], lst[4];
#pragma unroll
    for (int r = 0; r < 4; r++) { mst[r] = -1e30f; lst[r] = 0.f; }

    const int niter = (q0 >> 6) + 1;
    for (int it = 0; it < niter; it++) {
      const int kt = it * 64;
      __syncthreads();
      // stage K [64][128] and V^T [128][64], source-col XOR swizzle
#pragma unroll
      for (int i = 0; i < 4; i++) {
        int cc = i * 256 + wave * 64 + lane;  // slot id 0..1023
        int kr = cc >> 4, kcs = (cc & 15) ^ (kr & 15);
        gll16(Kh + (size_t)(kt + kr) * HD_ + kcs * 8, &Kl[(i * 4 + wave) * 512]);
        int vr = cc >> 3, vcs = (cc & 7) ^ (vr & 7);
        gll16(Vh + (size_t)vr * T_ + kt + vcs * 8, &Vl[(i * 4 + wave) * 512]);
      }
      __syncthreads();

      // S' = (Q*s) K^T
      f32x4 sa[4];
#pragma unroll
      for (int ni = 0; ni < 4; ni++) sa[ni] = (f32x4){0.f, 0.f, 0.f, 0.f};
#pragma unroll
      for (int kc = 0; kc < 4; kc++) {
        const int cswK = (((kc * 4 + quad) ^ l15) * 8);
        short8 bfr[4];
#pragma unroll
        for (int ni = 0; ni < 4; ni++)
          bfr[ni] = *(const short8*)&Kl[(ni * 16 + l15) * HD_ + cswK];
#pragma unroll
        for (int ni = 0; ni < 4; ni++)
          sa[ni] = __builtin_amdgcn_mfma_f32_16x16x32_bf16(qf[kc], bfr[ni], sa[ni], 0, 0, 0);
      }

      if (kt == q0) {   // causal mask, diagonal tile only (uniform branch)
#pragma unroll
        for (int ni = 0; ni < 4; ni++) {
          int gcol = kt + ni * 16 + l15;
#pragma unroll
          for (int r = 0; r < 4; r++) {
            int grow = wq + quad * 4 + r;
            if (gcol > grow) sa[ni][r] = -1e30f;
          }
        }
      }

      // online softmax, base-2
      float rmax[4] = {-1e30f, -1e30f, -1e30f, -1e30f};
#pragma unroll
      for (int ni = 0; ni < 4; ni++)
#pragma unroll
        for (int r = 0; r < 4; r++) rmax[r] = fmaxf(rmax[r], sa[ni][r]);
#pragma unroll
      for (int r = 0; r < 4; r++)
#pragma unroll
        for (int off = 1; off < 16; off <<= 1)
          rmax[r] = fmaxf(rmax[r], __shfl_xor(rmax[r], off));
      float alpha[4];
#pragma unroll
      for (int r = 0; r < 4; r++) {
        float mnew = fmaxf(mst[r], rmax[r]);
        alpha[r] = fexp2(fminf(mst[r] - mnew, 0.f));
        mst[r] = mnew;
      }
      float rsum[4] = {0.f, 0.f, 0.f, 0.f};
#pragma unroll
      for (int ni = 0; ni < 4; ni++)
#pragma unroll
        for (int r = 0; r < 4; r++) {
          float p = fexp2(fminf(sa[ni][r] - mst[r], 0.f));
          sa[ni][r] = p;
          rsum[r] += p;
        }
#pragma unroll
      for (int r = 0; r < 4; r++) {
#pragma unroll
        for (int off = 1; off < 16; off <<= 1)
          rsum[r] += __shfl_xor(rsum[r], off);
        lst[r] = lst[r] * alpha[r] + rsum[r];
      }
#pragma unroll
      for (int nv = 0; nv < 8; nv++)
#pragma unroll
        for (int r = 0; r < 4; r++) oacc[nv][r] *= alpha[r];
#pragma unroll
      for (int ni = 0; ni < 4; ni++)
#pragma unroll
        for (int r = 0; r < 4; r++)
          Pl[wave * 16 * 72 + (quad * 4 + r) * 72 + ni * 16 + l15] = f2bf(sa[ni][r]);
      __syncthreads();

      // O += P V
      short8 pf[2];
#pragma unroll
      for (int kc = 0; kc < 2; kc++)
        pf[kc] = *(const short8*)&Pl[wave * 16 * 72 + l15 * 72 + kc * 32 + quad * 8];
#pragma unroll
      for (int kc = 0; kc < 2; kc++) {
        const int cswV = (((kc * 4 + quad) ^ (l15 & 7)) * 8);
#pragma unroll
        for (int nv = 0; nv < 8; nv++) {
          short8 vb = *(const short8*)&Vl[(nv * 16 + l15) * 64 + cswV];
          oacc[nv] = __builtin_amdgcn_mfma_f32_16x16x32_bf16(pf[kc], vb, oacc[nv], 0, 0, 0);
        }
      }
    }

    float linv[4];
#pragma unroll
    for (int r = 0; r < 4; r++) linv[r] = 1.0f / fmaxf(lst[r], 1e-20f);
#pragma unroll
    for (int nv = 0; nv < 8; nv++)
#pragma unroll
      for (int r = 0; r < 4; r++) {
        int t = wq + quad * 4 + r;
        int d = nv * 16 + l15;
        AO[((size_t)(b * T_ + t)) * C_ + h * HD_ + d] = f2bf(oacc[nv][r] * linv[r]);
      }
  }
}

// ---------------------------------------------------------------------------
// Fallback GEMM (f32 sources converted during staging) — only if ws too small.
// ---------------------------------------------------------------------------
template<int A32, int B32, int MODE>
__global__ __launch_bounds__(256, 2)
void gemm_nt(const void* __restrict__ Ap, const void* __restrict__ Bp,
             const float* __restrict__ bias,
             float* __restrict__ Cout,
             unsigned short* __restrict__ Qb,
             unsigned short* __restrict__ Kb,
             unsigned short* __restrict__ Vb,
             int N, int K)
{
  __shared__ unsigned short Al[128 * 72];
  __shared__ unsigned short Bl[128 * 72];
  const int tid  = threadIdx.x;
  const int wave = tid >> 6, lane = tid & 63;
  const int quad = lane >> 4, l15 = lane & 15;
  const int wm = wave >> 1, wn = wave & 1;
  const int n0 = blockIdx.x * 128, m0 = blockIdx.y * 128;

  f32x4 acc[4][4];
#pragma unroll
  for (int i = 0; i < 4; i++)
#pragma unroll
    for (int j = 0; j < 4; j++) acc[i][j] = (f32x4){0.f, 0.f, 0.f, 0.f};

  for (int k0 = 0; k0 < K; k0 += 64) {
    __syncthreads();
    if constexpr (A32) {
      const float* A = (const float*)Ap;
#pragma unroll
      for (int i = 0; i < 8; i++) {
        int cid = tid + i * 256;
        int r = cid >> 4, c = cid & 15;
        float4 v = *(const float4*)&A[(size_t)(m0 + r) * K + k0 + c * 4];
        ushort4 hh;
        hh.x = f2bf(v.x); hh.y = f2bf(v.y); hh.z = f2bf(v.z); hh.w = f2bf(v.w);
        *(ushort4*)&Al[r * 72 + c * 4] = hh;
      }
    } else {
      const unsigned short* A = (const unsigned short*)Ap;
#pragma unroll
      for (int i = 0; i < 4; i++) {
        int cid = tid + i * 256;
        int r = cid >> 3, c = cid & 7;
        *(float4*)&Al[r * 72 + c * 8] =
            *(const float4*)&A[(size_t)(m0 + r) * K + k0 + c * 8];
      }
    }
    if constexpr (B32) {
      const float* Bm = (const float*)Bp;
#pragma unroll
      for (int i = 0; i < 8; i++) {
        int cid = tid + i * 256;
        int r = cid >> 4, c = cid & 15;
        float4 v = *(const float4*)&Bm[(size_t)(n0 + r) * K + k0 + c * 4];
        ushort4 hh;
        hh.x = f2bf(v.x); hh.y = f2bf(v.y); hh.z = f2bf(v.z); hh.w = f2bf(v.w);
        *(ushort4*)&Bl[r * 72 + c * 4] = hh;
      }
    } else {
      const unsigned short* Bm = (const unsigned short*)Bp;
#pragma unroll
      for (int i = 0; i < 4; i++) {
        int cid = tid + i * 256;
        int r = cid >> 3, c = cid & 7;
        *(float4*)&Bl[r * 72 + c * 8] =
            *(const float4*)&Bm[(size_t)(n0 + r) * K + k0 + c * 8];
      }
    }
    __syncthreads();
#pragma unroll
    for (int kc = 0; kc < 2; kc++) {
      short8 af[4], bfr[4];
#pragma unroll
      for (int mi = 0; mi < 4; mi++)
        af[mi] = *(const short8*)&Al[(wm * 64 + mi * 16 + l15) * 72 + kc * 32 + quad * 8];
#pragma unroll
      for (int ni = 0; ni < 4; ni++)
        bfr[ni] = *(const short8*)&Bl[(wn * 64 + ni * 16 + l15) * 72 + kc * 32 + quad * 8];
#pragma unroll
      for (int mi = 0; mi < 4; mi++)
#pragma unroll
        for (int ni = 0; ni < 4; ni++)
          acc[mi][ni] = __builtin_amdgcn_mfma_f32_16x16x32_bf16(af[mi], bfr[ni], acc[mi][ni], 0, 0, 0);
    }
  }

  if constexpr (MODE == 0) {
#pragma unroll
    for (int mi = 0; mi < 4; mi++)
#pragma unroll
      for (int ni = 0; ni < 4; ni++) {
        int col = n0 + wn * 64 + ni * 16 + l15;
        float bv = bias[col];
#pragma unroll
        for (int r = 0; r < 4; r++) {
          int row = m0 + wm * 64 + mi * 16 + quad * 4 + r;
          Cout[(size_t)row * N + col] = acc[mi][ni][r] + bv;
        }
      }
  } else {
    int which = n0 >> 11;
    int h = (n0 >> 7) & 15;
    unsigned short* P = (which == 0) ? Qb : (which == 1) ? Kb : Vb;
#pragma unroll
    for (int mi = 0; mi < 4; mi++)
#pragma unroll
      for (int ni = 0; ni < 4; ni++) {
        int d = wn * 64 + ni * 16 + l15;
        float bv = bias[n0 + d];
#pragma unroll
        for (int r = 0; r < 4; r++) {
          int m = m0 + wm * 64 + mi * 16 + quad * 4 + r;
          int b = m >> 11, t = m & (T_ - 1);
          size_t addr = (which == 2)
              ? ((size_t)((b * H_ + h) * HD_ + d)) * T_ + t
              : ((size_t)((b * H_ + h) * T_ + t)) * HD_ + d;
          P[addr] = f2bf(acc[mi][ni][r] + bv);
        }
      }
  }
}

// ---------------------------------------------------------------------------
extern "C" void kernel_launch(void* const* d_in, const int* in_sizes, int n_in,
                              void* d_out, int out_size, void* d_ws, size_t ws_size,
                              hipStream_t stream)
{
  const float* x    = (const float*)d_in[0];  // [2,2048,2048] f32
  const float* Wqkv = (const float*)d_in[1];  // [6144,2048]   f32
  const float* bqkv = (const float*)d_in[2];  // [6144]        f32
  const float* Wo   = (const float*)d_in[3];  // [2048,2048]   f32
  const float* bo   = (const float*)d_in[4];  // [2048]        f32
  float* out = (float*)d_out;                 // [2,2048,2048] f32

  const size_t SZ   = (size_t)B_ * H_ * T_ * HD_;   // 8,388,608
  const size_t NX   = SZ;
  const size_t NWQ  = (size_t)3 * C_ * C_;
  const size_t NWO  = (size_t)C_ * C_;
  unsigned short* ws = (unsigned short*)d_ws;

  dim3 blk(256, 1, 1);
  dim3 blk512(512, 1, 1);
  const size_t need = (NX + NWQ + 3 * SZ) * sizeof(unsigned short);  // 92.3 MB

  if (ws_size >= need) {
    unsigned short* xb    = ws;
    unsigned short* Wqkvb = xb + NX;
    unsigned short* Qb    = Wqkvb + NWQ;
    unsigned short* Kb    = Qb + SZ;
    unsigned short* Vb    = Kb + SZ;      // transposed [bh][d][t]
    unsigned short* AO    = xb;           // alias: x dead after QKV GEMM
    unsigned short* Wob   = Wqkvb;        // alias: Wqkv dead after QKV GEMM

    cvt_k<<<dim3((unsigned)(NX / 1024)), blk, 0, stream>>>(x, xb, (int)(NX / 4));
    cvt_k<<<dim3((unsigned)(NWQ / 1024)), blk, 0, stream>>>(Wqkv, Wqkvb, (int)(NWQ / 4));
    // QKV: M=4096, N=6144 -> grid (24 x 32) = 768 blocks = exactly 3 x 256 CUs
    gemm128<1><<<dim3(24, 32, 1), blk512, 0, stream>>>(
        xb, Wqkvb, bqkv, nullptr, Qb, Kb, Vb, 6144, 2048);
    cvt_k<<<dim3((unsigned)(NWO / 1024)), blk, 0, stream>>>(Wo, Wob, (int)(NWO / 4));
    rope_k<<<dim3((B_ * H_ * T_) / 4, 1, 1), blk, 0, stream>>>(Qb, Kb);
    attn_k<<<dim3(512, 1, 1), blk, 0, stream>>>(Qb, Kb, Vb, AO);
    // out-proj: M=4096, N=2048 -> grid (8 x 32) = 256 blocks = exactly 256 CUs
    gemm128<0><<<dim3(8, 32, 1), blk512, 0, stream>>>(
        AO, Wob, bo, out, nullptr, nullptr, nullptr, 2048, 2048);
  } else {
    unsigned short* Qb = ws;
    unsigned short* Kb = Qb + SZ;
    unsigned short* Vb = Kb + SZ;
    unsigned short* AO = Vb + SZ;
    gemm_nt<1, 1, 1><<<dim3(48, 32, 1), blk, 0, stream>>>(
        (const void*)x, (const void*)Wqkv, bqkv, nullptr, Qb, Kb, Vb, 6144, 2048);
    rope_k<<<dim3((B_ * H_ * T_) / 4, 1, 1), blk, 0, stream>>>(Qb, Kb);
    attn_k<<<dim3(512, 1, 1), blk, 0, stream>>>(Qb, Kb, Vb, AO);
    gemm_nt<0, 1, 0><<<dim3(16, 32, 1), blk, 0, stream>>>(
        (const void*)AO, (const void*)Wo, bo, out, nullptr, nullptr, nullptr, 2048, 2048);
  }
}

// Round 4
// 432.435 us; speedup vs baseline: 1.0072x; 1.0045x over previous
//
#include <hip/hip_runtime.h>
#include <hip/hip_bf16.h>

// Problem: B=2, T=2048, C=2048, H=16, HD=128.
// Round 8: faithful 256^2 8-phase GEMM port (m201 family). Round-3 showed the
// 128x256 2-phase hybrid is structure-limited (2080 cyc/phase vs ~900
// explainable; MfmaUtil 26%) even after locality was fixed (FETCH 109 MB).
// New gemm256: BM=BN=256, BK=64, 512 thr / 8 waves (2M x 4N), per-wave
// 128x64, acc[8][4]. 4 phases per K-tile, 16 MFMA each, quadrant order
// (h0,kk0),(h1,kk0),(h0,kk1),(h1,kk1). LDS 128 KB [2buf][2kk][2mat][256][32],
// XOR chunk swizzle (slot(r,c) holds global chunk c^((r>>1)&3); read chunk
// quad^((l15>>1)&3)) -> 2-way residual aliasing only (free; 0 conflicts r2).
// Stage unit = 16 KB (one kk-half of one matrix) = 2 gll16/thread/phase.
// Ledger (FIFO retirement, verified by induction):
//   tile T phase p=4T+f: f0 stages A-kk1(T+1)->buf^1, f1 B-kk1(T+1),
//   f2 A-kk0(T+2)->buf, f3 B-kk0(T+2). Every unit staged >=5 phases before
//   first read; uniform vmcnt(8) (=4 units in flight) at each phase end
//   retires exactly the unit read next phase. Regions dead at stage-issue:
//   kk0 dies after f1, kk1 after f3. Prologue: 6 units, vmcnt(8), barrier.
//   Tail: NT-2 f3 vmcnt(4); NT-1 f1 vmcnt(0) (epilogue drain), no stages.
// Grids: QKV (24x16)=384 blocks (1.5 rounds, accepted); out-proj (8x16)=128.
// x = n-tile fastest, gridDim.x % 8 == 0 -> implicit XCD N-partition
// (3 MB B-band per XCD L2-resident; validated round 3: FETCH 109 MB).

typedef __attribute__((ext_vector_type(8))) short short8;   // 8 bf16 MFMA A/B frag
typedef __attribute__((ext_vector_type(4))) float f32x4;    // MFMA C/D frag

#define B_  2
#define T_  2048
#define C_  2048
#define H_  16
#define HD_ 128

#define BARRIER() asm volatile("s_barrier" ::: "memory")
#define LGKM0()   asm volatile("s_waitcnt lgkmcnt(0)" ::: "memory")

template<int N> __device__ __forceinline__ void vmwait() {
  if constexpr (N == 8)      asm volatile("s_waitcnt vmcnt(8)" ::: "memory");
  else if constexpr (N == 6) asm volatile("s_waitcnt vmcnt(6)" ::: "memory");
  else if constexpr (N == 4) asm volatile("s_waitcnt vmcnt(4)" ::: "memory");
  else if constexpr (N == 3) asm volatile("s_waitcnt vmcnt(3)" ::: "memory");
  else if constexpr (N == 0) asm volatile("s_waitcnt vmcnt(0)" ::: "memory");
  // N < 0: no wait
}

__device__ __forceinline__ float bf2f(unsigned short u) {
  union { unsigned int i; float f; } v; v.i = ((unsigned int)u) << 16; return v.f;
}
__device__ __forceinline__ unsigned short f2bf(float f) {
  union { float f; unsigned int i; } v; v.f = f;
  unsigned int x = v.i;
  return (unsigned short)((x + 0x7fffu + ((x >> 16) & 1u)) >> 16);  // RNE
}
__device__ __forceinline__ float fexp2(float x) {
#if __has_builtin(__builtin_amdgcn_exp2f)
  return __builtin_amdgcn_exp2f(x);
#else
  return exp2f(x);
#endif
}

// async 16B global->LDS; lds base wave-uniform, lane l lands at base + l*16.
__device__ __forceinline__ void gll16(const unsigned short* g, unsigned short* lds_base) {
  __builtin_amdgcn_global_load_lds(
      (const __attribute__((address_space(1))) void*)g,
      (__attribute__((address_space(3))) void*)lds_base, 16, 0, 0);
}

// ---------------------------------------------------------------------------
// f32 -> bf16 elementwise convert, 4 elems/thread.
// ---------------------------------------------------------------------------
__global__ void cvt_k(const float* __restrict__ src, unsigned short* __restrict__ dst, int n4)
{
  int i = blockIdx.x * blockDim.x + threadIdx.x;
  if (i < n4) {
    float4 v = ((const float4*)src)[i];
    ushort4 h;
    h.x = f2bf(v.x); h.y = f2bf(v.y); h.z = f2bf(v.z); h.w = f2bf(v.w);
    ((ushort4*)dst)[i] = h;
  }
}

// ---------------------------------------------------------------------------
// 256^2 8-phase GEMM helpers.
// LDS layout: L[buf][kk][mat(A=0,B=1)][row 0..255][col 0..31], 128 KB.
// Stage unit = (mat, buf, kk, tile): 256 rows x 32 cols = 16 KB,
// 2 gll16/thread (rows sra and sra+128), source col chunk ca = sc^((sra>>1)&3)
// (identical swizzle for both rows since 128>>1 % 4 == 0).
// ---------------------------------------------------------------------------
__device__ __forceinline__ void stage_unit(
    const unsigned short* __restrict__ G, int K, int t, int kk,
    unsigned short (&L)[2][2][2][256][32], int buf, int mat,
    int wave, int sra, int ca8)
{
  const unsigned short* s = G + (size_t)sra * K + t * 64 + kk * 32 + ca8;
  gll16(s,                   &L[buf][kk][mat][wave * 16][0]);
  gll16(s + (size_t)128 * K, &L[buf][kk][mat][128 + wave * 16][0]);
}

// One K-tile = 4 phases. CB: buf parity. SN1: stage kk1(t+1); SN2: stage
// kk0(t+2). V0..V3: per-phase vmcnt (-1 = none).
template<int CB, bool SN1, bool SN2, int V0, int V1, int V2, int V3>
__device__ __forceinline__ void ktile256(
    int t,
    const unsigned short* __restrict__ Ag,
    const unsigned short* __restrict__ Bg, int K,
    unsigned short (&L)[2][2][2][256][32],
    f32x4 (&acc)[8][4],
    int wave, int wm, int wn, int l15, int csw8, int sra, int ca8)
{
  short8 af[4], bf[4];

  // ---- phase 0 : quadrant (h=0, kk=0); stage A-kk1(t+1) -> buf CB^1 ----
#pragma unroll
  for (int n = 0; n < 4; ++n)
    bf[n] = *(const short8*)&L[CB][0][1][wn * 64 + n * 16 + l15][csw8];
#pragma unroll
  for (int j = 0; j < 4; ++j)
    af[j] = *(const short8*)&L[CB][0][0][wm * 128 + j * 16 + l15][csw8];
  if constexpr (SN1)
    stage_unit(Ag, K, t + 1, 1, L, CB ^ 1, 0, wave, sra, ca8);
  BARRIER();
  LGKM0();
  __builtin_amdgcn_s_setprio(1);
#pragma unroll
  for (int j = 0; j < 4; ++j)
#pragma unroll
    for (int n = 0; n < 4; ++n)
      acc[j][n] = __builtin_amdgcn_mfma_f32_16x16x32_bf16(af[j], bf[n], acc[j][n], 0, 0, 0);
  __builtin_amdgcn_s_setprio(0);
  vmwait<V0>();
  BARRIER();

  // ---- phase 1 : quadrant (h=1, kk=0); stage B-kk1(t+1) -> buf CB^1 ----
#pragma unroll
  for (int j = 0; j < 4; ++j)
    af[j] = *(const short8*)&L[CB][0][0][wm * 128 + 64 + j * 16 + l15][csw8];
  if constexpr (SN1)
    stage_unit(Bg, K, t + 1, 1, L, CB ^ 1, 1, wave, sra, ca8);
  BARRIER();
  LGKM0();
  __builtin_amdgcn_s_setprio(1);
#pragma unroll
  for (int j = 0; j < 4; ++j)
#pragma unroll
    for (int n = 0; n < 4; ++n)
      acc[4 + j][n] = __builtin_amdgcn_mfma_f32_16x16x32_bf16(af[j], bf[n], acc[4 + j][n], 0, 0, 0);
  __builtin_amdgcn_s_setprio(0);
  vmwait<V1>();
  BARRIER();

  // ---- phase 2 : quadrant (h=0, kk=1); stage A-kk0(t+2) -> buf CB ----
#pragma unroll
  for (int n = 0; n < 4; ++n)
    bf[n] = *(const short8*)&L[CB][1][1][wn * 64 + n * 16 + l15][csw8];
#pragma unroll
  for (int j = 0; j < 4; ++j)
    af[j] = *(const short8*)&L[CB][1][0][wm * 128 + j * 16 + l15][csw8];
  if constexpr (SN2)
    stage_unit(Ag, K, t + 2, 0, L, CB, 0, wave, sra, ca8);
  BARRIER();
  LGKM0();
  __builtin_amdgcn_s_setprio(1);
#pragma unroll
  for (int j = 0; j < 4; ++j)
#pragma unroll
    for (int n = 0; n < 4; ++n)
      acc[j][n] = __builtin_amdgcn_mfma_f32_16x16x32_bf16(af[j], bf[n], acc[j][n], 0, 0, 0);
  __builtin_amdgcn_s_setprio(0);
  vmwait<V2>();
  BARRIER();

  // ---- phase 3 : quadrant (h=1, kk=1); stage B-kk0(t+2) -> buf CB ----
#pragma unroll
  for (int j = 0; j < 4; ++j)
    af[j] = *(const short8*)&L[CB][1][0][wm * 128 + 64 + j * 16 + l15][csw8];
  if constexpr (SN2)
    stage_unit(Bg, K, t + 2, 0, L, CB, 1, wave, sra, ca8);
  BARRIER();
  LGKM0();
  __builtin_amdgcn_s_setprio(1);
#pragma unroll
  for (int j = 0; j < 4; ++j)
#pragma unroll
    for (int n = 0; n < 4; ++n)
      acc[4 + j][n] = __builtin_amdgcn_mfma_f32_16x16x32_bf16(af[j], bf[n], acc[4 + j][n], 0, 0, 0);
  __builtin_amdgcn_s_setprio(0);
  vmwait<V3>();
  BARRIER();
}

// ---------------------------------------------------------------------------
// Pipelined NT GEMM: C[M][N] = A[M][K]*Bw[N][K]^T + bias. 256x256 tile,
// 8 waves (2M x 4N, 128x64 each). 2D grid, x = n-tile fastest.
// MODE 0: f32 row-major store. MODE 1: bf16 qkv scatter (V transposed).
// MFMA layouts (HW-verified m89/m91): A: A[m=l15][k=quad*8+j];
// B: B[k=quad*8+j][n=l15]; C/D: col=l15, row=quad*4+reg.
// ---------------------------------------------------------------------------
template<int MODE>
__global__ __launch_bounds__(512, 2)
void gemm256(const unsigned short* __restrict__ A,
             const unsigned short* __restrict__ Bw,
             const float* __restrict__ bias,
             float* __restrict__ Cout,
             unsigned short* __restrict__ Qb,
             unsigned short* __restrict__ Kb,
             unsigned short* __restrict__ Vb,
             int N, int K)
{
  __shared__ unsigned short L[2][2][2][256][32];   // 128 KB

  const int tid  = threadIdx.x;
  const int wave = tid >> 6, lane = tid & 63;
  const int quad = lane >> 4, l15 = lane & 15;
  const int wm = wave >> 2, wn = wave & 3;                 // 2 x 4 wave grid
  const int csw8 = (quad ^ ((l15 >> 1) & 3)) * 8;          // read chunk swizzle
  const int sra = tid >> 2;                                // staging row 0..127
  const int ca8 = ((tid & 3) ^ ((sra >> 1) & 3)) * 8;      // source chunk swz

  const int n0 = blockIdx.x * 256;
  const int m0 = blockIdx.y * 256;
  const unsigned short* Ag = A  + (size_t)m0 * K;
  const unsigned short* Bg = Bw + (size_t)n0 * K;

  f32x4 acc[8][4];
#pragma unroll
  for (int i = 0; i < 8; i++)
#pragma unroll
    for (int j = 0; j < 4; j++) acc[i][j] = (f32x4){0.f, 0.f, 0.f, 0.f};

  // prologue: 6 units = tile0 {A,B}x{kk0,kk1} + tile1 {A,B}kk0; retire
  // units 1-2 (kk0(0)) via vmcnt(8); barrier.
  stage_unit(Ag, K, 0, 0, L, 0, 0, wave, sra, ca8);
  stage_unit(Bg, K, 0, 0, L, 0, 1, wave, sra, ca8);
  stage_unit(Ag, K, 0, 1, L, 0, 0, wave, sra, ca8);
  stage_unit(Bg, K, 0, 1, L, 0, 1, wave, sra, ca8);
  stage_unit(Ag, K, 1, 0, L, 1, 0, wave, sra, ca8);
  stage_unit(Bg, K, 1, 0, L, 1, 1, wave, sra, ca8);
  vmwait<8>();
  BARRIER();

  const int NT = K >> 6;   // 32 for K=2048 (even, >=4)
#pragma unroll 1
  for (int t = 0; t + 3 < NT; t += 2) {
    ktile256<0, true, true, 8, 8, 8, 8>(t,     Ag, Bg, K, L, acc, wave, wm, wn, l15, csw8, sra, ca8);
    ktile256<1, true, true, 8, 8, 8, 8>(t + 1, Ag, Bg, K, L, acc, wave, wm, wn, l15, csw8, sra, ca8);
  }
  ktile256<0, true,  false, 8,  8,  8,  4>(NT - 2, Ag, Bg, K, L, acc, wave, wm, wn, l15, csw8, sra, ca8);
  ktile256<1, false, false, -1, 0, -1, -1>(NT - 1, Ag, Bg, K, L, acc, wave, wm, wn, l15, csw8, sra, ca8);

  if constexpr (MODE == 0) {
#pragma unroll
    for (int mi = 0; mi < 8; mi++)
#pragma unroll
      for (int n = 0; n < 4; n++) {
        int col = n0 + wn * 64 + n * 16 + l15;
        float bv = bias[col];
#pragma unroll
        for (int r = 0; r < 4; r++) {
          int row = m0 + wm * 128 + mi * 16 + quad * 4 + r;
          Cout[(size_t)row * N + col] = acc[mi][n][r] + bv;
        }
      }
  } else {
    const int which = n0 >> 11;                  // block never straddles Q/K/V
    unsigned short* P = (which == 0) ? Qb : (which == 1) ? Kb : Vb;
#pragma unroll
    for (int mi = 0; mi < 8; mi++)
#pragma unroll
      for (int n = 0; n < 4; n++) {
        int col = n0 + wn * 64 + n * 16 + l15;
        float bv = bias[col];
        int h = (col >> 7) & 15, d = col & 127;
#pragma unroll
        for (int r = 0; r < 4; r++) {
          int m = m0 + wm * 128 + mi * 16 + quad * 4 + r;
          int b = m >> 11, t = m & (T_ - 1);
          size_t addr = (which == 2)
              ? ((size_t)((b * H_ + h) * HD_ + d)) * T_ + t    // V transposed
              : ((size_t)((b * H_ + h) * T_ + t)) * HD_ + d;   // Q,K row-major
          P[addr] = f2bf(acc[mi][n][r] + bv);
        }
      }
  }
}

// ---------------------------------------------------------------------------
// RoPE in-place on bf16 Q and K, layout [B*H*T][128].
// theta_p = 10000^(-(2**p)/128) (faithful 2**p quirk), pos 1-indexed,
// pair (d, d+64). Q pre-scaled by 1/sqrt(HD)*log2(e) for exp2 softmax.
// ---------------------------------------------------------------------------
__global__ void rope_k(unsigned short* __restrict__ Q, unsigned short* __restrict__ K)
{
  const int tid = threadIdx.x;
  const int w = tid >> 6, l = tid & 63;
  const int r = blockIdx.x * 4 + w;
  const int t = r & (T_ - 1);
  const float pos = (float)(t + 1);
  const float theta = expf(-exp2f((float)l) * 0.07195578415606394f); // ln(1e4)/128
  const float ang = pos * theta;
  const float c = cosf(ang), s = sinf(ang);
  const float QS = 0.08838834764831845f * 1.4426950408889634f; // 1/sqrt(128)*log2(e)
  const size_t base = (size_t)r * HD_;

  float q0 = bf2f(Q[base + l]), q1 = bf2f(Q[base + l + 64]);
  Q[base + l]      = f2bf((q0 * c - q1 * s) * QS);
  Q[base + l + 64] = f2bf((q1 * c + q0 * s) * QS);
  float k0 = bf2f(K[base + l]), k1 = bf2f(K[base + l + 64]);
  K[base + l]      = f2bf(k0 * c - k1 * s);
  K[base + l + 64] = f2bf(k1 * c + k0 * s);
}

// ---------------------------------------------------------------------------
// Flash-style causal attention (round-4 structure + XOR-swizzled K/V tiles).
// Grid 512 = (bh 32, XCD-swizzled) x (qpair 16); each block does Q-tiles
// qp*64 and (31-qp)*64 -> uniform 33 k-iters. 4 waves x 16 rows.
// Kl [64][128]: slot (r,c16) holds global (r, c16^(r&15)); read col-chunk
// (kc*4+quad)^l15. Vl [128][64]: slot (r,c8) holds (r, c8^(r&7)); read
// (kc*4+quad)^(l15&7). Both -> residual 2-way bank aliasing (free).
// ---------------------------------------------------------------------------
__global__ __launch_bounds__(256, 2)
void attn_k(const unsigned short* __restrict__ Q,
            const unsigned short* __restrict__ K,
            const unsigned short* __restrict__ Vt_g,
            unsigned short* __restrict__ AO)
{
  __shared__ unsigned short Kl[64 * 128];
  __shared__ unsigned short Vl[128 * 64];
  __shared__ unsigned short Pl[4 * 16 * 72];

  const int tid  = threadIdx.x;
  const int wave = tid >> 6, lane = tid & 63;
  const int quad = lane >> 4, l15 = lane & 15;
  const int blk = blockIdx.x;
  const int bh = (blk & 7) + 8 * ((blk >> 3) & 3);
  const int qp = (blk >> 5) & 15;
  const unsigned short* Qh = Q    + (size_t)bh * T_ * HD_;
  const unsigned short* Kh = K    + (size_t)bh * T_ * HD_;
  const unsigned short* Vh = Vt_g + (size_t)bh * T_ * HD_;  // [d][t]
  const int b = bh >> 4, h = bh & 15;

#pragma unroll
  for (int tile = 0; tile < 2; tile++) {
    const int q0 = (tile == 0 ? qp : 31 - qp) * 64;
    const int wq = q0 + wave * 16;
    short8 qf[4];
#pragma unroll
    for (int kc = 0; kc < 4; kc++)
      qf[kc] = *(const short8*)&Qh[(size_t)(wq + l15) * HD_ + kc * 32 + quad * 8];

    f32x4 oacc[8];
#pragma unroll
    for (int n = 0; n < 8; n++) oacc[n] = (f32x4){0.f, 0.f, 0.f, 0.f};
    float mst[4], lst[4];
#pragma unroll
    for (int r = 0; r < 4; r++) { mst[r] = -1e30f; lst[r] = 0.f; }

    const int niter = (q0 >> 6) + 1;
    for (int it = 0; it < niter; it++) {
      const int kt = it * 64;
      __syncthreads();
      // stage K [64][128] and V^T [128][64], source-col XOR swizzle
#pragma unroll
      for (int i = 0; i < 4; i++) {
        int cc = i * 256 + wave * 64 + lane;  // slot id 0..1023
        int kr = cc >> 4, kcs = (cc & 15) ^ (kr & 15);
        gll16(Kh + (size_t)(kt + kr) * HD_ + kcs * 8, &Kl[(i * 4 + wave) * 512]);
        int vr = cc >> 3, vcs = (cc & 7) ^ (vr & 7);
        gll16(Vh + (size_t)vr * T_ + kt + vcs * 8, &Vl[(i * 4 + wave) * 512]);
      }
      __syncthreads();

      // S' = (Q*s) K^T
      f32x4 sa[4];
#pragma unroll
      for (int ni = 0; ni < 4; ni++) sa[ni] = (f32x4){0.f, 0.f, 0.f, 0.f};
#pragma unroll
      for (int kc = 0; kc < 4; kc++) {
        const int cswK = (((kc * 4 + quad) ^ l15) * 8);
        short8 bfr[4];
#pragma unroll
        for (int ni = 0; ni < 4; ni++)
          bfr[ni] = *(const short8*)&Kl[(ni * 16 + l15) * HD_ + cswK];
#pragma unroll
        for (int ni = 0; ni < 4; ni++)
          sa[ni] = __builtin_amdgcn_mfma_f32_16x16x32_bf16(qf[kc], bfr[ni], sa[ni], 0, 0, 0);
      }

      if (kt == q0) {   // causal mask, diagonal tile only (uniform branch)
#pragma unroll
        for (int ni = 0; ni < 4; ni++) {
          int gcol = kt + ni * 16 + l15;
#pragma unroll
          for (int r = 0; r < 4; r++) {
            int grow = wq + quad * 4 + r;
            if (gcol > grow) sa[ni][r] = -1e30f;
          }
        }
      }

      // online softmax, base-2
      float rmax[4] = {-1e30f, -1e30f, -1e30f, -1e30f};
#pragma unroll
      for (int ni = 0; ni < 4; ni++)
#pragma unroll
        for (int r = 0; r < 4; r++) rmax[r] = fmaxf(rmax[r], sa[ni][r]);
#pragma unroll
      for (int r = 0; r < 4; r++)
#pragma unroll
        for (int off = 1; off < 16; off <<= 1)
          rmax[r] = fmaxf(rmax[r], __shfl_xor(rmax[r], off));
      float alpha[4];
#pragma unroll
      for (int r = 0; r < 4; r++) {
        float mnew = fmaxf(mst[r], rmax[r]);
        alpha[r] = fexp2(fminf(mst[r] - mnew, 0.f));
        mst[r] = mnew;
      }
      float rsum[4] = {0.f, 0.f, 0.f, 0.f};
#pragma unroll
      for (int ni = 0; ni < 4; ni++)
#pragma unroll
        for (int r = 0; r < 4; r++) {
          float p = fexp2(fminf(sa[ni][r] - mst[r], 0.f));
          sa[ni][r] = p;
          rsum[r] += p;
        }
#pragma unroll
      for (int r = 0; r < 4; r++) {
#pragma unroll
        for (int off = 1; off < 16; off <<= 1)
          rsum[r] += __shfl_xor(rsum[r], off);
        lst[r] = lst[r] * alpha[r] + rsum[r];
      }
#pragma unroll
      for (int nv = 0; nv < 8; nv++)
#pragma unroll
        for (int r = 0; r < 4; r++) oacc[nv][r] *= alpha[r];
#pragma unroll
      for (int ni = 0; ni < 4; ni++)
#pragma unroll
        for (int r = 0; r < 4; r++)
          Pl[wave * 16 * 72 + (quad * 4 + r) * 72 + ni * 16 + l15] = f2bf(sa[ni][r]);
      __syncthreads();

      // O += P V
      short8 pf[2];
#pragma unroll
      for (int kc = 0; kc < 2; kc++)
        pf[kc] = *(const short8*)&Pl[wave * 16 * 72 + l15 * 72 + kc * 32 + quad * 8];
#pragma unroll
      for (int kc = 0; kc < 2; kc++) {
        const int cswV = (((kc * 4 + quad) ^ (l15 & 7)) * 8);
#pragma unroll
        for (int nv = 0; nv < 8; nv++) {
          short8 vb = *(const short8*)&Vl[(nv * 16 + l15) * 64 + cswV];
          oacc[nv] = __builtin_amdgcn_mfma_f32_16x16x32_bf16(pf[kc], vb, oacc[nv], 0, 0, 0);
        }
      }
    }

    float linv[4];
#pragma unroll
    for (int r = 0; r < 4; r++) linv[r] = 1.0f / fmaxf(lst[r], 1e-20f);
#pragma unroll
    for (int nv = 0; nv < 8; nv++)
#pragma unroll
      for (int r = 0; r < 4; r++) {
        int t = wq + quad * 4 + r;
        int d = nv * 16 + l15;
        AO[((size_t)(b * T_ + t)) * C_ + h * HD_ + d] = f2bf(oacc[nv][r] * linv[r]);
      }
  }
}

// ---------------------------------------------------------------------------
// Fallback GEMM (f32 sources converted during staging) — only if ws too small.
// ---------------------------------------------------------------------------
template<int A32, int B32, int MODE>
__global__ __launch_bounds__(256, 2)
void gemm_nt(const void* __restrict__ Ap, const void* __restrict__ Bp,
             const float* __restrict__ bias,
             float* __restrict__ Cout,
             unsigned short* __restrict__ Qb,
             unsigned short* __restrict__ Kb,
             unsigned short* __restrict__ Vb,
             int N, int K)
{
  __shared__ unsigned short Al[128 * 72];
  __shared__ unsigned short Bl[128 * 72];
  const int tid  = threadIdx.x;
  const int wave = tid >> 6, lane = tid & 63;
  const int quad = lane >> 4, l15 = lane & 15;
  const int wm = wave >> 1, wn = wave & 1;
  const int n0 = blockIdx.x * 128, m0 = blockIdx.y * 128;

  f32x4 acc[4][4];
#pragma unroll
  for (int i = 0; i < 4; i++)
#pragma unroll
    for (int j = 0; j < 4; j++) acc[i][j] = (f32x4){0.f, 0.f, 0.f, 0.f};

  for (int k0 = 0; k0 < K; k0 += 64) {
    __syncthreads();
    if constexpr (A32) {
      const float* A = (const float*)Ap;
#pragma unroll
      for (int i = 0; i < 8; i++) {
        int cid = tid + i * 256;
        int r = cid >> 4, c = cid & 15;
        float4 v = *(const float4*)&A[(size_t)(m0 + r) * K + k0 + c * 4];
        ushort4 hh;
        hh.x = f2bf(v.x); hh.y = f2bf(v.y); hh.z = f2bf(v.z); hh.w = f2bf(v.w);
        *(ushort4*)&Al[r * 72 + c * 4] = hh;
      }
    } else {
      const unsigned short* A = (const unsigned short*)Ap;
#pragma unroll
      for (int i = 0; i < 4; i++) {
        int cid = tid + i * 256;
        int r = cid >> 3, c = cid & 7;
        *(float4*)&Al[r * 72 + c * 8] =
            *(const float4*)&A[(size_t)(m0 + r) * K + k0 + c * 8];
      }
    }
    if constexpr (B32) {
      const float* Bm = (const float*)Bp;
#pragma unroll
      for (int i = 0; i < 8; i++) {
        int cid = tid + i * 256;
        int r = cid >> 4, c = cid & 15;
        float4 v = *(const float4*)&Bm[(size_t)(n0 + r) * K + k0 + c * 4];
        ushort4 hh;
        hh.x = f2bf(v.x); hh.y = f2bf(v.y); hh.z = f2bf(v.z); hh.w = f2bf(v.w);
        *(ushort4*)&Bl[r * 72 + c * 4] = hh;
      }
    } else {
      const unsigned short* Bm = (const unsigned short*)Bp;
#pragma unroll
      for (int i = 0; i < 4; i++) {
        int cid = tid + i * 256;
        int r = cid >> 3, c = cid & 7;
        *(float4*)&Bl[r * 72 + c * 8] =
            *(const float4*)&Bm[(size_t)(n0 + r) * K + k0 + c * 8];
      }
    }
    __syncthreads();
#pragma unroll
    for (int kc = 0; kc < 2; kc++) {
      short8 af[4], bfr[4];
#pragma unroll
      for (int mi = 0; mi < 4; mi++)
        af[mi] = *(const short8*)&Al[(wm * 64 + mi * 16 + l15) * 72 + kc * 32 + quad * 8];
#pragma unroll
      for (int ni = 0; ni < 4; ni++)
        bfr[ni] = *(const short8*)&Bl[(wn * 64 + ni * 16 + l15) * 72 + kc * 32 + quad * 8];
#pragma unroll
      for (int mi = 0; mi < 4; mi++)
#pragma unroll
        for (int ni = 0; ni < 4; ni++)
          acc[mi][ni] = __builtin_amdgcn_mfma_f32_16x16x32_bf16(af[mi], bfr[ni], acc[mi][ni], 0, 0, 0);
    }
  }

  if constexpr (MODE == 0) {
#pragma unroll
    for (int mi = 0; mi < 4; mi++)
#pragma unroll
      for (int ni = 0; ni < 4; ni++) {
        int col = n0 + wn * 64 + ni * 16 + l15;
        float bv = bias[col];
#pragma unroll
        for (int r = 0; r < 4; r++) {
          int row = m0 + wm * 64 + mi * 16 + quad * 4 + r;
          Cout[(size_t)row * N + col] = acc[mi][ni][r] + bv;
        }
      }
  } else {
    int which = n0 >> 11;
    int h = (n0 >> 7) & 15;
    unsigned short* P = (which == 0) ? Qb : (which == 1) ? Kb : Vb;
#pragma unroll
    for (int mi = 0; mi < 4; mi++)
#pragma unroll
      for (int ni = 0; ni < 4; ni++) {
        int d = wn * 64 + ni * 16 + l15;
        float bv = bias[n0 + d];
#pragma unroll
        for (int r = 0; r < 4; r++) {
          int m = m0 + wm * 64 + mi * 16 + quad * 4 + r;
          int b = m >> 11, t = m & (T_ - 1);
          size_t addr = (which == 2)
              ? ((size_t)((b * H_ + h) * HD_ + d)) * T_ + t
              : ((size_t)((b * H_ + h) * T_ + t)) * HD_ + d;
          P[addr] = f2bf(acc[mi][ni][r] + bv);
        }
      }
  }
}

// ---------------------------------------------------------------------------
extern "C" void kernel_launch(void* const* d_in, const int* in_sizes, int n_in,
                              void* d_out, int out_size, void* d_ws, size_t ws_size,
                              hipStream_t stream)
{
  const float* x    = (const float*)d_in[0];  // [2,2048,2048] f32
  const float* Wqkv = (const float*)d_in[1];  // [6144,2048]   f32
  const float* bqkv = (const float*)d_in[2];  // [6144]        f32
  const float* Wo   = (const float*)d_in[3];  // [2048,2048]   f32
  const float* bo   = (const float*)d_in[4];  // [2048]        f32
  float* out = (float*)d_out;                 // [2,2048,2048] f32

  const size_t SZ   = (size_t)B_ * H_ * T_ * HD_;   // 8,388,608
  const size_t NX   = SZ;
  const size_t NWQ  = (size_t)3 * C_ * C_;
  const size_t NWO  = (size_t)C_ * C_;
  unsigned short* ws = (unsigned short*)d_ws;

  dim3 blk(256, 1, 1);
  dim3 blk512(512, 1, 1);
  const size_t need = (NX + NWQ + 3 * SZ) * sizeof(unsigned short);  // 92.3 MB

  if (ws_size >= need) {
    unsigned short* xb    = ws;
    unsigned short* Wqkvb = xb + NX;
    unsigned short* Qb    = Wqkvb + NWQ;
    unsigned short* Kb    = Qb + SZ;
    unsigned short* Vb    = Kb + SZ;      // transposed [bh][d][t]
    unsigned short* AO    = xb;           // alias: x dead after QKV GEMM
    unsigned short* Wob   = Wqkvb;        // alias: Wqkv dead after QKV GEMM

    cvt_k<<<dim3((unsigned)(NX / 1024)), blk, 0, stream>>>(x, xb, (int)(NX / 4));
    cvt_k<<<dim3((unsigned)(NWQ / 1024)), blk, 0, stream>>>(Wqkv, Wqkvb, (int)(NWQ / 4));
    // QKV: M=4096, N=6144 -> grid (24 x 16) = 384 blocks (256^2 tiles)
    gemm256<1><<<dim3(24, 16, 1), blk512, 0, stream>>>(
        xb, Wqkvb, bqkv, nullptr, Qb, Kb, Vb, 6144, 2048);
    cvt_k<<<dim3((unsigned)(NWO / 1024)), blk, 0, stream>>>(Wo, Wob, (int)(NWO / 4));
    rope_k<<<dim3((B_ * H_ * T_) / 4, 1, 1), blk, 0, stream>>>(Qb, Kb);
    attn_k<<<dim3(512, 1, 1), blk, 0, stream>>>(Qb, Kb, Vb, AO);
    // out-proj: M=4096, N=2048 -> grid (8 x 16) = 128 blocks
    gemm256<0><<<dim3(8, 16, 1), blk512, 0, stream>>>(
        AO, Wob, bo, out, nullptr, nullptr, nullptr, 2048, 2048);
  } else {
    unsigned short* Qb = ws;
    unsigned short* Kb = Qb + SZ;
    unsigned short* Vb = Kb + SZ;
    unsigned short* AO = Vb + SZ;
    gemm_nt<1, 1, 1><<<dim3(48, 32, 1), blk, 0, stream>>>(
        (const void*)x, (const void*)Wqkv, bqkv, nullptr, Qb, Kb, Vb, 6144, 2048);
    rope_k<<<dim3((B_ * H_ * T_) / 4, 1, 1), blk, 0, stream>>>(Qb, Kb);
    attn_k<<<dim3(512, 1, 1), blk, 0, stream>>>(Qb, Kb, Vb, AO);
    gemm_nt<0, 1, 0><<<dim3(16, 32, 1), blk, 0, stream>>>(
        (const void*)AO, (const void*)Wo, bo, out, nullptr, nullptr, nullptr, 2048, 2048);
  }
}

// Round 5
// 420.624 us; speedup vs baseline: 1.0355x; 1.0281x over previous
//
#include <hip/hip_runtime.h>
#include <hip/hip_bf16.h>

// Problem: B=2, T=2048, C=2048, H=16, HD=128.
// Round 9: pipelined fragment reads. Round-4 counters: 1375 cyc/phase =
// 620 (MFMA) + 768 (LDS drain) SERIALIZED - the phase body read its own
// MFMA operands, so LDS pipe and MFMA pipe strictly alternated (MfmaUtil 29%).
// Fix: each phase issues ds_reads for the NEXT phase into the alternate
// register set (af0/af1 by phase parity, bf0/bf1 by kk); MFMA consumes regs
// loaded LAST phase under a compiler-counted lgkmcnt -> LDS drains during the
// MFMA window. vmcnt ledger re-derived for the earlier reads: vmcnt(6) at
// ends of phi0 and phi2 (2x per K-tile); tails (6,4) then (0,-).
// Stage schedule unchanged: A1(t+1)@phi0, B1(t+1)@phi1, A0(t+2)@phi2,
// B0(t+2)@phi3; unit = 256x32 = 16 KB = 2 gll16/thread. LDS 128 KB
// [2buf][2kk][2mat][256][32], XOR chunk swizzle (0 conflicts, r2-verified).
// Invariant at tile-t entry: outstanding = {A1(t),B1(t),A0(t+1),B0(t+1)}.
//   phi0: +A1(t+1); vmcnt(6) retires A1(t),B1(t)  (read at phi1 body)
//   phi1: +B1(t+1)
//   phi2: +A0(t+2); vmcnt(6) retires A0(t+1),B0(t+1) (read at phi3 body)
//   phi3: +B0(t+2) -> invariant at t+1.  All verified WAR-safe vs barriers.
// Grids: QKV (24x16)=384 blocks; out-proj (8x16)=128. x = n-tile fastest,
// gridDim.x % 8 == 0 -> implicit XCD N-partition (FETCH 96 MB, r4-verified).

typedef __attribute__((ext_vector_type(8))) short short8;   // 8 bf16 MFMA A/B frag
typedef __attribute__((ext_vector_type(4))) float f32x4;    // MFMA C/D frag

#define B_  2
#define T_  2048
#define C_  2048
#define H_  16
#define HD_ 128

#define BARRIER() asm volatile("s_barrier" ::: "memory")

template<int N> __device__ __forceinline__ void vmwait() {
  if constexpr (N == 8)      asm volatile("s_waitcnt vmcnt(8)" ::: "memory");
  else if constexpr (N == 6) asm volatile("s_waitcnt vmcnt(6)" ::: "memory");
  else if constexpr (N == 4) asm volatile("s_waitcnt vmcnt(4)" ::: "memory");
  else if constexpr (N == 0) asm volatile("s_waitcnt vmcnt(0)" ::: "memory");
  // N < 0: no wait
}

__device__ __forceinline__ float bf2f(unsigned short u) {
  union { unsigned int i; float f; } v; v.i = ((unsigned int)u) << 16; return v.f;
}
__device__ __forceinline__ unsigned short f2bf(float f) {
  union { float f; unsigned int i; } v; v.f = f;
  unsigned int x = v.i;
  return (unsigned short)((x + 0x7fffu + ((x >> 16) & 1u)) >> 16);  // RNE
}
__device__ __forceinline__ float fexp2(float x) {
#if __has_builtin(__builtin_amdgcn_exp2f)
  return __builtin_amdgcn_exp2f(x);
#else
  return exp2f(x);
#endif
}

// async 16B global->LDS; lds base wave-uniform, lane l lands at base + l*16.
__device__ __forceinline__ void gll16(const unsigned short* g, unsigned short* lds_base) {
  __builtin_amdgcn_global_load_lds(
      (const __attribute__((address_space(1))) void*)g,
      (__attribute__((address_space(3))) void*)lds_base, 16, 0, 0);
}

// ---------------------------------------------------------------------------
// f32 -> bf16 elementwise convert, 4 elems/thread.
// ---------------------------------------------------------------------------
__global__ void cvt_k(const float* __restrict__ src, unsigned short* __restrict__ dst, int n4)
{
  int i = blockIdx.x * blockDim.x + threadIdx.x;
  if (i < n4) {
    float4 v = ((const float4*)src)[i];
    ushort4 h;
    h.x = f2bf(v.x); h.y = f2bf(v.y); h.z = f2bf(v.z); h.w = f2bf(v.w);
    ((ushort4*)dst)[i] = h;
  }
}

// ---------------------------------------------------------------------------
// 256^2 8-phase GEMM helpers.
// LDS: L[buf][kk][mat(A=0,B=1)][row 0..255][col 0..31], 128 KB.
// Stage unit = 16 KB, 2 gll16/thread (rows sra, sra+128), source chunk
// ca8 = (sc ^ ((sra>>1)&3))*8 (same for both rows: 128>>1 % 4 == 0).
// ---------------------------------------------------------------------------
__device__ __forceinline__ void stage_unit(
    const unsigned short* __restrict__ G, int K, int t, int kk,
    unsigned short (&L)[2][2][2][256][32], int buf, int mat,
    int wave, int sra, int ca8)
{
  const unsigned short* s = G + (size_t)sra * K + t * 64 + kk * 32 + ca8;
  gll16(s,                   &L[buf][kk][mat][wave * 16][0]);
  gll16(s + (size_t)128 * K, &L[buf][kk][mat][128 + wave * 16][0]);
}

// One K-tile = 4 phases, fragment-pipelined: phase p MFMAs regs read at p-1,
// and reads phase p+1's regs before its barrier (counted lgkm by compiler).
// CB: buf parity. SN1: stage kk1(t+1) @ phi0/phi1; SN2: stage kk0(t+2) @
// phi2/phi3. V0/V2: vmcnt at ends of phi0/phi2 (-1 = none). RD3: phi3 body
// pre-reads tile t+1 phi0 operands.
template<int CB, bool SN1, bool SN2, int V0, int V2, bool RD3>
__device__ __forceinline__ void ktile256(
    int t,
    const unsigned short* __restrict__ Ag,
    const unsigned short* __restrict__ Bg, int K,
    unsigned short (&L)[2][2][2][256][32],
    f32x4 (&acc)[8][4],
    short8 (&af0)[4], short8 (&af1)[4],
    short8 (&bf0)[4], short8 (&bf1)[4],
    int wave, int wm, int wn, int l15, int csw8, int sra, int ca8)
{
  // ---- phase 0 : MFMA (h0,kk0) = af0 x bf0; read af1 <- A-kk0 half1 ----
#pragma unroll
  for (int j = 0; j < 4; ++j)
    af1[j] = *(const short8*)&L[CB][0][0][wm * 128 + 64 + j * 16 + l15][csw8];
  if constexpr (SN1)
    stage_unit(Ag, K, t + 1, 1, L, CB ^ 1, 0, wave, sra, ca8);
  BARRIER();
  __builtin_amdgcn_s_setprio(1);
#pragma unroll
  for (int j = 0; j < 4; ++j)
#pragma unroll
    for (int n = 0; n < 4; ++n)
      acc[j][n] = __builtin_amdgcn_mfma_f32_16x16x32_bf16(af0[j], bf0[n], acc[j][n], 0, 0, 0);
  __builtin_amdgcn_s_setprio(0);
  vmwait<V0>();
  BARRIER();

  // ---- phase 1 : MFMA (h1,kk0) = af1 x bf0; read bf1 <- B-kk1, af0 <- A-kk1 half0
#pragma unroll
  for (int n = 0; n < 4; ++n)
    bf1[n] = *(const short8*)&L[CB][1][1][wn * 64 + n * 16 + l15][csw8];
#pragma unroll
  for (int j = 0; j < 4; ++j)
    af0[j] = *(const short8*)&L[CB][1][0][wm * 128 + j * 16 + l15][csw8];
  if constexpr (SN1)
    stage_unit(Bg, K, t + 1, 1, L, CB ^ 1, 1, wave, sra, ca8);
  BARRIER();
  __builtin_amdgcn_s_setprio(1);
#pragma unroll
  for (int j = 0; j < 4; ++j)
#pragma unroll
    for (int n = 0; n < 4; ++n)
      acc[4 + j][n] = __builtin_amdgcn_mfma_f32_16x16x32_bf16(af1[j], bf0[n], acc[4 + j][n], 0, 0, 0);
  __builtin_amdgcn_s_setprio(0);
  BARRIER();

  // ---- phase 2 : MFMA (h0,kk1) = af0 x bf1; read af1 <- A-kk1 half1 ----
#pragma unroll
  for (int j = 0; j < 4; ++j)
    af1[j] = *(const short8*)&L[CB][1][0][wm * 128 + 64 + j * 16 + l15][csw8];
  if constexpr (SN2)
    stage_unit(Ag, K, t + 2, 0, L, CB, 0, wave, sra, ca8);
  BARRIER();
  __builtin_amdgcn_s_setprio(1);
#pragma unroll
  for (int j = 0; j < 4; ++j)
#pragma unroll
    for (int n = 0; n < 4; ++n)
      acc[j][n] = __builtin_amdgcn_mfma_f32_16x16x32_bf16(af0[j], bf1[n], acc[j][n], 0, 0, 0);
  __builtin_amdgcn_s_setprio(0);
  vmwait<V2>();
  BARRIER();

  // ---- phase 3 : MFMA (h1,kk1) = af1 x bf1; read bf0/af0 <- tile t+1 kk0 ----
  if constexpr (RD3) {
#pragma unroll
    for (int n = 0; n < 4; ++n)
      bf0[n] = *(const short8*)&L[CB ^ 1][0][1][wn * 64 + n * 16 + l15][csw8];
#pragma unroll
    for (int j = 0; j < 4; ++j)
      af0[j] = *(const short8*)&L[CB ^ 1][0][0][wm * 128 + j * 16 + l15][csw8];
  }
  if constexpr (SN2)
    stage_unit(Bg, K, t + 2, 0, L, CB, 1, wave, sra, ca8);
  BARRIER();
  __builtin_amdgcn_s_setprio(1);
#pragma unroll
  for (int j = 0; j < 4; ++j)
#pragma unroll
    for (int n = 0; n < 4; ++n)
      acc[4 + j][n] = __builtin_amdgcn_mfma_f32_16x16x32_bf16(af1[j], bf1[n], acc[4 + j][n], 0, 0, 0);
  __builtin_amdgcn_s_setprio(0);
  BARRIER();
}

// ---------------------------------------------------------------------------
// Pipelined NT GEMM: C[M][N] = A[M][K]*Bw[N][K]^T + bias. 256x256 tile,
// 8 waves (2M x 4N, 128x64 each). 2D grid, x = n-tile fastest.
// MODE 0: f32 row-major store. MODE 1: bf16 qkv scatter (V transposed).
// MFMA layouts (HW-verified m89/m91): A: A[m=l15][k=quad*8+j];
// B: B[k=quad*8+j][n=l15]; C/D: col=l15, row=quad*4+reg.
// ---------------------------------------------------------------------------
template<int MODE>
__global__ __launch_bounds__(512, 2)
void gemm256(const unsigned short* __restrict__ A,
             const unsigned short* __restrict__ Bw,
             const float* __restrict__ bias,
             float* __restrict__ Cout,
             unsigned short* __restrict__ Qb,
             unsigned short* __restrict__ Kb,
             unsigned short* __restrict__ Vb,
             int N, int K)
{
  __shared__ unsigned short L[2][2][2][256][32];   // 128 KB

  const int tid  = threadIdx.x;
  const int wave = tid >> 6, lane = tid & 63;
  const int quad = lane >> 4, l15 = lane & 15;
  const int wm = wave >> 2, wn = wave & 3;                 // 2 x 4 wave grid
  const int csw8 = (quad ^ ((l15 >> 1) & 3)) * 8;          // read chunk swizzle
  const int sra = tid >> 2;                                // staging row 0..127
  const int ca8 = ((tid & 3) ^ ((sra >> 1) & 3)) * 8;      // source chunk swz

  const int n0 = blockIdx.x * 256;
  const int m0 = blockIdx.y * 256;
  const unsigned short* Ag = A  + (size_t)m0 * K;
  const unsigned short* Bg = Bw + (size_t)n0 * K;

  f32x4 acc[8][4];
#pragma unroll
  for (int i = 0; i < 8; i++)
#pragma unroll
    for (int j = 0; j < 4; j++) acc[i][j] = (f32x4){0.f, 0.f, 0.f, 0.f};

  short8 af0[4], af1[4], bf0[4], bf1[4];

  // prologue: stage A0(0),B0(0) then A1(0),B1(0),A0(1),B0(1); vmcnt(8)
  // retires the first two (12 loads -> <=8) establishing the tile-0 entry
  // invariant {A1(0),B1(0),A0(1),B0(1)}; barrier; pre-read phi0 operands.
  stage_unit(Ag, K, 0, 0, L, 0, 0, wave, sra, ca8);
  stage_unit(Bg, K, 0, 0, L, 0, 1, wave, sra, ca8);
  stage_unit(Ag, K, 0, 1, L, 0, 0, wave, sra, ca8);
  stage_unit(Bg, K, 0, 1, L, 0, 1, wave, sra, ca8);
  stage_unit(Ag, K, 1, 0, L, 1, 0, wave, sra, ca8);
  stage_unit(Bg, K, 1, 0, L, 1, 1, wave, sra, ca8);
  vmwait<8>();
  BARRIER();
#pragma unroll
  for (int n = 0; n < 4; ++n)
    bf0[n] = *(const short8*)&L[0][0][1][wn * 64 + n * 16 + l15][csw8];
#pragma unroll
  for (int j = 0; j < 4; ++j)
    af0[j] = *(const short8*)&L[0][0][0][wm * 128 + j * 16 + l15][csw8];

  const int NT = K >> 6;   // 32 for K=2048 (even, >=4)
#pragma unroll 1
  for (int t = 0; t + 3 < NT; t += 2) {
    ktile256<0, true, true, 6, 6, true>(t,     Ag, Bg, K, L, acc, af0, af1, bf0, bf1, wave, wm, wn, l15, csw8, sra, ca8);
    ktile256<1, true, true, 6, 6, true>(t + 1, Ag, Bg, K, L, acc, af0, af1, bf0, bf1, wave, wm, wn, l15, csw8, sra, ca8);
  }
  ktile256<0, true,  false, 6,  4, true >(NT - 2, Ag, Bg, K, L, acc, af0, af1, bf0, bf1, wave, wm, wn, l15, csw8, sra, ca8);
  ktile256<1, false, false, 0, -1, false>(NT - 1, Ag, Bg, K, L, acc, af0, af1, bf0, bf1, wave, wm, wn, l15, csw8, sra, ca8);

  if constexpr (MODE == 0) {
#pragma unroll
    for (int mi = 0; mi < 8; mi++)
#pragma unroll
      for (int n = 0; n < 4; n++) {
        int col = n0 + wn * 64 + n * 16 + l15;
        float bv = bias[col];
#pragma unroll
        for (int r = 0; r < 4; r++) {
          int row = m0 + wm * 128 + mi * 16 + quad * 4 + r;
          Cout[(size_t)row * N + col] = acc[mi][n][r] + bv;
        }
      }
  } else {
    const int which = n0 >> 11;                  // block never straddles Q/K/V
    unsigned short* P = (which == 0) ? Qb : (which == 1) ? Kb : Vb;
#pragma unroll
    for (int mi = 0; mi < 8; mi++)
#pragma unroll
      for (int n = 0; n < 4; n++) {
        int col = n0 + wn * 64 + n * 16 + l15;
        float bv = bias[col];
        int h = (col >> 7) & 15, d = col & 127;
#pragma unroll
        for (int r = 0; r < 4; r++) {
          int m = m0 + wm * 128 + mi * 16 + quad * 4 + r;
          int b = m >> 11, t = m & (T_ - 1);
          size_t addr = (which == 2)
              ? ((size_t)((b * H_ + h) * HD_ + d)) * T_ + t    // V transposed
              : ((size_t)((b * H_ + h) * T_ + t)) * HD_ + d;   // Q,K row-major
          P[addr] = f2bf(acc[mi][n][r] + bv);
        }
      }
  }
}

// ---------------------------------------------------------------------------
// RoPE in-place on bf16 Q and K, layout [B*H*T][128].
// theta_p = 10000^(-(2**p)/128) (faithful 2**p quirk), pos 1-indexed,
// pair (d, d+64). Q pre-scaled by 1/sqrt(HD)*log2(e) for exp2 softmax.
// ---------------------------------------------------------------------------
__global__ void rope_k(unsigned short* __restrict__ Q, unsigned short* __restrict__ K)
{
  const int tid = threadIdx.x;
  const int w = tid >> 6, l = tid & 63;
  const int r = blockIdx.x * 4 + w;
  const int t = r & (T_ - 1);
  const float pos = (float)(t + 1);
  const float theta = expf(-exp2f((float)l) * 0.07195578415606394f); // ln(1e4)/128
  const float ang = pos * theta;
  const float c = cosf(ang), s = sinf(ang);
  const float QS = 0.08838834764831845f * 1.4426950408889634f; // 1/sqrt(128)*log2(e)
  const size_t base = (size_t)r * HD_;

  float q0 = bf2f(Q[base + l]), q1 = bf2f(Q[base + l + 64]);
  Q[base + l]      = f2bf((q0 * c - q1 * s) * QS);
  Q[base + l + 64] = f2bf((q1 * c + q0 * s) * QS);
  float k0 = bf2f(K[base + l]), k1 = bf2f(K[base + l + 64]);
  K[base + l]      = f2bf(k0 * c - k1 * s);
  K[base + l + 64] = f2bf(k1 * c + k0 * s);
}

// ---------------------------------------------------------------------------
// Flash-style causal attention (round-4 structure + XOR-swizzled K/V tiles).
// Grid 512 = (bh 32, XCD-swizzled) x (qpair 16); each block does Q-tiles
// qp*64 and (31-qp)*64 -> uniform 33 k-iters. 4 waves x 16 rows.
// Kl [64][128]: slot (r,c16) holds global (r, c16^(r&15)); read col-chunk
// (kc*4+quad)^l15. Vl [128][64]: slot (r,c8) holds (r, c8^(r&7)); read
// (kc*4+quad)^(l15&7). Both -> residual 2-way bank aliasing (free).
// ---------------------------------------------------------------------------
__global__ __launch_bounds__(256, 2)
void attn_k(const unsigned short* __restrict__ Q,
            const unsigned short* __restrict__ K,
            const unsigned short* __restrict__ Vt_g,
            unsigned short* __restrict__ AO)
{
  __shared__ unsigned short Kl[64 * 128];
  __shared__ unsigned short Vl[128 * 64];
  __shared__ unsigned short Pl[4 * 16 * 72];

  const int tid  = threadIdx.x;
  const int wave = tid >> 6, lane = tid & 63;
  const int quad = lane >> 4, l15 = lane & 15;
  const int blk = blockIdx.x;
  const int bh = (blk & 7) + 8 * ((blk >> 3) & 3);
  const int qp = (blk >> 5) & 15;
  const unsigned short* Qh = Q    + (size_t)bh * T_ * HD_;
  const unsigned short* Kh = K    + (size_t)bh * T_ * HD_;
  const unsigned short* Vh = Vt_g + (size_t)bh * T_ * HD_;  // [d][t]
  const int b = bh >> 4, h = bh & 15;

#pragma unroll
  for (int tile = 0; tile < 2; tile++) {
    const int q0 = (tile == 0 ? qp : 31 - qp) * 64;
    const int wq = q0 + wave * 16;
    short8 qf[4];
#pragma unroll
    for (int kc = 0; kc < 4; kc++)
      qf[kc] = *(const short8*)&Qh[(size_t)(wq + l15) * HD_ + kc * 32 + quad * 8];

    f32x4 oacc[8];
#pragma unroll
    for (int n = 0; n < 8; n++) oacc[n] = (f32x4){0.f, 0.f, 0.f, 0.f};
    float mst[4], lst[4];
#pragma unroll
    for (int r = 0; r < 4; r++) { mst[r] = -1e30f; lst[r] = 0.f; }

    const int niter = (q0 >> 6) + 1;
    for (int it = 0; it < niter; it++) {
      const int kt = it * 64;
      __syncthreads();
      // stage K [64][128] and V^T [128][64], source-col XOR swizzle
#pragma unroll
      for (int i = 0; i < 4; i++) {
        int cc = i * 256 + wave * 64 + lane;  // slot id 0..1023
        int kr = cc >> 4, kcs = (cc & 15) ^ (kr & 15);
        gll16(Kh + (size_t)(kt + kr) * HD_ + kcs * 8, &Kl[(i * 4 + wave) * 512]);
        int vr = cc >> 3, vcs = (cc & 7) ^ (vr & 7);
        gll16(Vh + (size_t)vr * T_ + kt + vcs * 8, &Vl[(i * 4 + wave) * 512]);
      }
      __syncthreads();

      // S' = (Q*s) K^T
      f32x4 sa[4];
#pragma unroll
      for (int ni = 0; ni < 4; ni++) sa[ni] = (f32x4){0.f, 0.f, 0.f, 0.f};
#pragma unroll
      for (int kc = 0; kc < 4; kc++) {
        const int cswK = (((kc * 4 + quad) ^ l15) * 8);
        short8 bfr[4];
#pragma unroll
        for (int ni = 0; ni < 4; ni++)
          bfr[ni] = *(const short8*)&Kl[(ni * 16 + l15) * HD_ + cswK];
#pragma unroll
        for (int ni = 0; ni < 4; ni++)
          sa[ni] = __builtin_amdgcn_mfma_f32_16x16x32_bf16(qf[kc], bfr[ni], sa[ni], 0, 0, 0);
      }

      if (kt == q0) {   // causal mask, diagonal tile only (uniform branch)
#pragma unroll
        for (int ni = 0; ni < 4; ni++) {
          int gcol = kt + ni * 16 + l15;
#pragma unroll
          for (int r = 0; r < 4; r++) {
            int grow = wq + quad * 4 + r;
            if (gcol > grow) sa[ni][r] = -1e30f;
          }
        }
      }

      // online softmax, base-2
      float rmax[4] = {-1e30f, -1e30f, -1e30f, -1e30f};
#pragma unroll
      for (int ni = 0; ni < 4; ni++)
#pragma unroll
        for (int r = 0; r < 4; r++) rmax[r] = fmaxf(rmax[r], sa[ni][r]);
#pragma unroll
      for (int r = 0; r < 4; r++)
#pragma unroll
        for (int off = 1; off < 16; off <<= 1)
          rmax[r] = fmaxf(rmax[r], __shfl_xor(rmax[r], off));
      float alpha[4];
#pragma unroll
      for (int r = 0; r < 4; r++) {
        float mnew = fmaxf(mst[r], rmax[r]);
        alpha[r] = fexp2(fminf(mst[r] - mnew, 0.f));
        mst[r] = mnew;
      }
      float rsum[4] = {0.f, 0.f, 0.f, 0.f};
#pragma unroll
      for (int ni = 0; ni < 4; ni++)
#pragma unroll
        for (int r = 0; r < 4; r++) {
          float p = fexp2(fminf(sa[ni][r] - mst[r], 0.f));
          sa[ni][r] = p;
          rsum[r] += p;
        }
#pragma unroll
      for (int r = 0; r < 4; r++) {
#pragma unroll
        for (int off = 1; off < 16; off <<= 1)
          rsum[r] += __shfl_xor(rsum[r], off);
        lst[r] = lst[r] * alpha[r] + rsum[r];
      }
#pragma unroll
      for (int nv = 0; nv < 8; nv++)
#pragma unroll
        for (int r = 0; r < 4; r++) oacc[nv][r] *= alpha[r];
#pragma unroll
      for (int ni = 0; ni < 4; ni++)
#pragma unroll
        for (int r = 0; r < 4; r++)
          Pl[wave * 16 * 72 + (quad * 4 + r) * 72 + ni * 16 + l15] = f2bf(sa[ni][r]);
      __syncthreads();

      // O += P V
      short8 pf[2];
#pragma unroll
      for (int kc = 0; kc < 2; kc++)
        pf[kc] = *(const short8*)&Pl[wave * 16 * 72 + l15 * 72 + kc * 32 + quad * 8];
#pragma unroll
      for (int kc = 0; kc < 2; kc++) {
        const int cswV = (((kc * 4 + quad) ^ (l15 & 7)) * 8);
#pragma unroll
        for (int nv = 0; nv < 8; nv++) {
          short8 vb = *(const short8*)&Vl[(nv * 16 + l15) * 64 + cswV];
          oacc[nv] = __builtin_amdgcn_mfma_f32_16x16x32_bf16(pf[kc], vb, oacc[nv], 0, 0, 0);
        }
      }
    }

    float linv[4];
#pragma unroll
    for (int r = 0; r < 4; r++) linv[r] = 1.0f / fmaxf(lst[r], 1e-20f);
#pragma unroll
    for (int nv = 0; nv < 8; nv++)
#pragma unroll
      for (int r = 0; r < 4; r++) {
        int t = wq + quad * 4 + r;
        int d = nv * 16 + l15;
        AO[((size_t)(b * T_ + t)) * C_ + h * HD_ + d] = f2bf(oacc[nv][r] * linv[r]);
      }
  }
}

// ---------------------------------------------------------------------------
// Fallback GEMM (f32 sources converted during staging) — only if ws too small.
// ---------------------------------------------------------------------------
template<int A32, int B32, int MODE>
__global__ __launch_bounds__(256, 2)
void gemm_nt(const void* __restrict__ Ap, const void* __restrict__ Bp,
             const float* __restrict__ bias,
             float* __restrict__ Cout,
             unsigned short* __restrict__ Qb,
             unsigned short* __restrict__ Kb,
             unsigned short* __restrict__ Vb,
             int N, int K)
{
  __shared__ unsigned short Al[128 * 72];
  __shared__ unsigned short Bl[128 * 72];
  const int tid  = threadIdx.x;
  const int wave = tid >> 6, lane = tid & 63;
  const int quad = lane >> 4, l15 = lane & 15;
  const int wm = wave >> 1, wn = wave & 1;
  const int n0 = blockIdx.x * 128, m0 = blockIdx.y * 128;

  f32x4 acc[4][4];
#pragma unroll
  for (int i = 0; i < 4; i++)
#pragma unroll
    for (int j = 0; j < 4; j++) acc[i][j] = (f32x4){0.f, 0.f, 0.f, 0.f};

  for (int k0 = 0; k0 < K; k0 += 64) {
    __syncthreads();
    if constexpr (A32) {
      const float* A = (const float*)Ap;
#pragma unroll
      for (int i = 0; i < 8; i++) {
        int cid = tid + i * 256;
        int r = cid >> 4, c = cid & 15;
        float4 v = *(const float4*)&A[(size_t)(m0 + r) * K + k0 + c * 4];
        ushort4 hh;
        hh.x = f2bf(v.x); hh.y = f2bf(v.y); hh.z = f2bf(v.z); hh.w = f2bf(v.w);
        *(ushort4*)&Al[r * 72 + c * 4] = hh;
      }
    } else {
      const unsigned short* A = (const unsigned short*)Ap;
#pragma unroll
      for (int i = 0; i < 4; i++) {
        int cid = tid + i * 256;
        int r = cid >> 3, c = cid & 7;
        *(float4*)&Al[r * 72 + c * 8] =
            *(const float4*)&A[(size_t)(m0 + r) * K + k0 + c * 8];
      }
    }
    if constexpr (B32) {
      const float* Bm = (const float*)Bp;
#pragma unroll
      for (int i = 0; i < 8; i++) {
        int cid = tid + i * 256;
        int r = cid >> 4, c = cid & 15;
        float4 v = *(const float4*)&Bm[(size_t)(n0 + r) * K + k0 + c * 4];
        ushort4 hh;
        hh.x = f2bf(v.x); hh.y = f2bf(v.y); hh.z = f2bf(v.z); hh.w = f2bf(v.w);
        *(ushort4*)&Bl[r * 72 + c * 4] = hh;
      }
    } else {
      const unsigned short* Bm = (const unsigned short*)Bp;
#pragma unroll
      for (int i = 0; i < 4; i++) {
        int cid = tid + i * 256;
        int r = cid >> 3, c = cid & 7;
        *(float4*)&Bl[r * 72 + c * 8] =
            *(const float4*)&Bm[(size_t)(n0 + r) * K + k0 + c * 8];
      }
    }
    __syncthreads();
#pragma unroll
    for (int kc = 0; kc < 2; kc++) {
      short8 af[4], bfr[4];
#pragma unroll
      for (int mi = 0; mi < 4; mi++)
        af[mi] = *(const short8*)&Al[(wm * 64 + mi * 16 + l15) * 72 + kc * 32 + quad * 8];
#pragma unroll
      for (int ni = 0; ni < 4; ni++)
        bfr[ni] = *(const short8*)&Bl[(wn * 64 + ni * 16 + l15) * 72 + kc * 32 + quad * 8];
#pragma unroll
      for (int mi = 0; mi < 4; mi++)
#pragma unroll
        for (int ni = 0; ni < 4; ni++)
          acc[mi][ni] = __builtin_amdgcn_mfma_f32_16x16x32_bf16(af[mi], bfr[ni], acc[mi][ni], 0, 0, 0);
    }
  }

  if constexpr (MODE == 0) {
#pragma unroll
    for (int mi = 0; mi < 4; mi++)
#pragma unroll
      for (int ni = 0; ni < 4; ni++) {
        int col = n0 + wn * 64 + ni * 16 + l15;
        float bv = bias[col];
#pragma unroll
        for (int r = 0; r < 4; r++) {
          int row = m0 + wm * 64 + mi * 16 + quad * 4 + r;
          Cout[(size_t)row * N + col] = acc[mi][ni][r] + bv;
        }
      }
  } else {
    int which = n0 >> 11;
    int h = (n0 >> 7) & 15;
    unsigned short* P = (which == 0) ? Qb : (which == 1) ? Kb : Vb;
#pragma unroll
    for (int mi = 0; mi < 4; mi++)
#pragma unroll
      for (int ni = 0; ni < 4; ni++) {
        int d = wn * 64 + ni * 16 + l15;
        float bv = bias[n0 + d];
#pragma unroll
        for (int r = 0; r < 4; r++) {
          int m = m0 + wm * 64 + mi * 16 + quad * 4 + r;
          int b = m >> 11, t = m & (T_ - 1);
          size_t addr = (which == 2)
              ? ((size_t)((b * H_ + h) * HD_ + d)) * T_ + t
              : ((size_t)((b * H_ + h) * T_ + t)) * HD_ + d;
          P[addr] = f2bf(acc[mi][ni][r] + bv);
        }
      }
  }
}

// ---------------------------------------------------------------------------
extern "C" void kernel_launch(void* const* d_in, const int* in_sizes, int n_in,
                              void* d_out, int out_size, void* d_ws, size_t ws_size,
                              hipStream_t stream)
{
  const float* x    = (const float*)d_in[0];  // [2,2048,2048] f32
  const float* Wqkv = (const float*)d_in[1];  // [6144,2048]   f32
  const float* bqkv = (const float*)d_in[2];  // [6144]        f32
  const float* Wo   = (const float*)d_in[3];  // [2048,2048]   f32
  const float* bo   = (const float*)d_in[4];  // [2048]        f32
  float* out = (float*)d_out;                 // [2,2048,2048] f32

  const size_t SZ   = (size_t)B_ * H_ * T_ * HD_;   // 8,388,608
  const size_t NX   = SZ;
  const size_t NWQ  = (size_t)3 * C_ * C_;
  const size_t NWO  = (size_t)C_ * C_;
  unsigned short* ws = (unsigned short*)d_ws;

  dim3 blk(256, 1, 1);
  dim3 blk512(512, 1, 1);
  const size_t need = (NX + NWQ + 3 * SZ) * sizeof(unsigned short);  // 92.3 MB

  if (ws_size >= need) {
    unsigned short* xb    = ws;
    unsigned short* Wqkvb = xb + NX;
    unsigned short* Qb    = Wqkvb + NWQ;
    unsigned short* Kb    = Qb + SZ;
    unsigned short* Vb    = Kb + SZ;      // transposed [bh][d][t]
    unsigned short* AO    = xb;           // alias: x dead after QKV GEMM
    unsigned short* Wob   = Wqkvb;        // alias: Wqkv dead after QKV GEMM

    cvt_k<<<dim3((unsigned)(NX / 1024)), blk, 0, stream>>>(x, xb, (int)(NX / 4));
    cvt_k<<<dim3((unsigned)(NWQ / 1024)), blk, 0, stream>>>(Wqkv, Wqkvb, (int)(NWQ / 4));
    // QKV: M=4096, N=6144 -> grid (24 x 16) = 384 blocks (256^2 tiles)
    gemm256<1><<<dim3(24, 16, 1), blk512, 0, stream>>>(
        xb, Wqkvb, bqkv, nullptr, Qb, Kb, Vb, 6144, 2048);
    cvt_k<<<dim3((unsigned)(NWO / 1024)), blk, 0, stream>>>(Wo, Wob, (int)(NWO / 4));
    rope_k<<<dim3((B_ * H_ * T_) / 4, 1, 1), blk, 0, stream>>>(Qb, Kb);
    attn_k<<<dim3(512, 1, 1), blk, 0, stream>>>(Qb, Kb, Vb, AO);
    // out-proj: M=4096, N=2048 -> grid (8 x 16) = 128 blocks
    gemm256<0><<<dim3(8, 16, 1), blk512, 0, stream>>>(
        AO, Wob, bo, out, nullptr, nullptr, nullptr, 2048, 2048);
  } else {
    unsigned short* Qb = ws;
    unsigned short* Kb = Qb + SZ;
    unsigned short* Vb = Kb + SZ;
    unsigned short* AO = Vb + SZ;
    gemm_nt<1, 1, 1><<<dim3(48, 32, 1), blk, 0, stream>>>(
        (const void*)x, (const void*)Wqkv, bqkv, nullptr, Qb, Kb, Vb, 6144, 2048);
    rope_k<<<dim3((B_ * H_ * T_) / 4, 1, 1), blk, 0, stream>>>(Qb, Kb);
    attn_k<<<dim3(512, 1, 1), blk, 0, stream>>>(Qb, Kb, Vb, AO);
    gemm_nt<0, 1, 0><<<dim3(16, 32, 1), blk, 0, stream>>>(
        (const void*)AO, (const void*)Wo, bo, out, nullptr, nullptr, nullptr, 2048, 2048);
  }
}

// Round 7
// 397.772 us; speedup vs baseline: 1.0950x; 1.0574x over previous
//
#include <hip/hip_runtime.h>
#include <hip/hip_bf16.h>

// Problem: B=2, T=2048, C=2048, H=16, HD=128.
// Round 10 (resubmit; round-6 bench lost to GPU-broker timeout).
// GEMM campaign closed (r6-r9: 4 structures, none beat round-0's gemm_bt;
// 256^2 tile = 1 block/CU + 1.5-round grid quantization negates the phase
// schedule). GEMMs reverted to round-0 gemm_bt (proven 149/50 us).
// This round attacks attn_k (~135 us, untouched):
//  - K/V LDS double-buffer + counted vmcnt(8): stage next tile right after
//    the WAR barrier, retire current tile's 8 loads with vmwait<8> (never 0
//    mid-loop). Ledger verified incl. qf loads / AO stores as older ops.
//  - 3 full-drain __syncthreads/iter -> 2 raw s_barrier/iter. The mid sync
//    between P-write and PV removed: Pl is wave-private, per-wave DS ops are
//    in-order; lgkmcnt(0) suffices.
//  - exact VALU trims: redundant fminf clamps dropped (diffs <=0 by
//    construction); alpha-rescale skipped via __any(max-grew) (alpha==1 is
//    identity -> bitwise-equal results).

typedef __attribute__((ext_vector_type(8))) short short8;   // 8 bf16 MFMA A/B frag
typedef __attribute__((ext_vector_type(4))) float f32x4;    // MFMA C/D frag

#define B_  2
#define T_  2048
#define C_  2048
#define H_  16
#define HD_ 128

#define BARRIER() asm volatile("s_barrier" ::: "memory")
#define LGKM0()   asm volatile("s_waitcnt lgkmcnt(0)" ::: "memory")

template<int N> __device__ __forceinline__ void vmwait() {
  if constexpr (N == 8)      asm volatile("s_waitcnt vmcnt(8)" ::: "memory");
  else if constexpr (N == 0) asm volatile("s_waitcnt vmcnt(0)" ::: "memory");
}

__device__ __forceinline__ float bf2f(unsigned short u) {
  union { unsigned int i; float f; } v; v.i = ((unsigned int)u) << 16; return v.f;
}
__device__ __forceinline__ unsigned short f2bf(float f) {
  union { float f; unsigned int i; } v; v.f = f;
  unsigned int x = v.i;
  return (unsigned short)((x + 0x7fffu + ((x >> 16) & 1u)) >> 16);  // RNE
}
__device__ __forceinline__ float fexp2(float x) {
#if __has_builtin(__builtin_amdgcn_exp2f)
  return __builtin_amdgcn_exp2f(x);
#else
  return exp2f(x);
#endif
}

// async 16B global->LDS; lds base wave-uniform, lane l lands at base + l*16.
__device__ __forceinline__ void gll16(const unsigned short* g, unsigned short* lds_base) {
  __builtin_amdgcn_global_load_lds(
      (const __attribute__((address_space(1))) void*)g,
      (__attribute__((address_space(3))) void*)lds_base, 16, 0, 0);
}

// ---------------------------------------------------------------------------
// f32 -> bf16 elementwise convert, 4 elems/thread.
// ---------------------------------------------------------------------------
__global__ void cvt_k(const float* __restrict__ src, unsigned short* __restrict__ dst, int n4)
{
  int i = blockIdx.x * blockDim.x + threadIdx.x;
  if (i < n4) {
    float4 v = ((const float4*)src)[i];
    ushort4 h;
    h.x = f2bf(v.x); h.y = f2bf(v.y); h.z = f2bf(v.z); h.w = f2bf(v.w);
    ((ushort4*)dst)[i] = h;
  }
}

// ---------------------------------------------------------------------------
// m97-style NT GEMM (bf16 x bf16): C[M][N] = A[M][K]*Bw[N][K]^T + bias.
// 128x128 tile, BK=64, 2x2 waves of 64x64, 4x4 16x16x32 MFMA frags,
// global_load_lds width=16 staging, XOR-swizzled LDS columns.
// MODE 0: f32 row-major store. MODE 1: bf16 qkv scatter:
//   Q,K -> [bh][t][d];  V -> TRANSPOSED [bh][d][t].
// MFMA layouts (HW-verified m89/m91): A: A[m=lane&15][k=quad*8+j];
// B: B[k=quad*8+j][n=lane&15]; C/D: col=lane&15, row=quad*4+reg.
// (round-0 kernel, restored verbatim: QKV 148.9 us @ MfmaUtil 30%.)
// ---------------------------------------------------------------------------
template<int MODE>
__global__ __launch_bounds__(256, 2)
void gemm_bt(const unsigned short* __restrict__ A,
             const unsigned short* __restrict__ Bw,
             const float* __restrict__ bias,
             float* __restrict__ Cout,
             unsigned short* __restrict__ Qb,
             unsigned short* __restrict__ Kb,
             unsigned short* __restrict__ Vb,
             int N, int K)
{
  __shared__ unsigned short Al[128 * 64];
  __shared__ unsigned short Bl[128 * 64];
  const int tid  = threadIdx.x;
  const int wave = tid >> 6, lane = tid & 63;
  const int quad = lane >> 4, l15 = lane & 15;
  const int wm = wave >> 1, wn = wave & 1;
  const int n0 = blockIdx.x * 128, m0 = blockIdx.y * 128;

  f32x4 acc[4][4];
#pragma unroll
  for (int i = 0; i < 4; i++)
#pragma unroll
    for (int j = 0; j < 4; j++) acc[i][j] = (f32x4){0.f, 0.f, 0.f, 0.f};

  for (int k0 = 0; k0 < K; k0 += 64) {
    __syncthreads();
    const unsigned short* Ag = A + (size_t)m0 * K + k0;
    const unsigned short* Bg = Bw + (size_t)n0 * K + k0;
#pragma unroll
    for (int i = 0; i < 4; i++) {
      int cc = i * 256 + wave * 64 + lane;      // LDS 16B-slot id, 0..1023
      int r = cc >> 3;
      int c8 = (cc & 7) ^ (r & 7);              // swizzled source col chunk
      gll16(Ag + (size_t)r * K + c8 * 8, &Al[(i * 4 + wave) * 512]);
      gll16(Bg + (size_t)r * K + c8 * 8, &Bl[(i * 4 + wave) * 512]);
    }
    __syncthreads();
#pragma unroll
    for (int kc = 0; kc < 2; kc++) {
      // swizzled col offset: row&7 == l15&7 for all mi/ni (offsets are *8)
      const int csw = (((kc * 4 + quad) ^ (l15 & 7)) * 8);
      short8 af[4], bfr[4];
#pragma unroll
      for (int mi = 0; mi < 4; mi++)
        af[mi] = *(const short8*)&Al[(wm * 64 + mi * 16 + l15) * 64 + csw];
#pragma unroll
      for (int ni = 0; ni < 4; ni++)
        bfr[ni] = *(const short8*)&Bl[(wn * 64 + ni * 16 + l15) * 64 + csw];
#pragma unroll
      for (int mi = 0; mi < 4; mi++)
#pragma unroll
        for (int ni = 0; ni < 4; ni++)
          acc[mi][ni] = __builtin_amdgcn_mfma_f32_16x16x32_bf16(af[mi], bfr[ni], acc[mi][ni], 0, 0, 0);
    }
  }

  if constexpr (MODE == 0) {
#pragma unroll
    for (int mi = 0; mi < 4; mi++)
#pragma unroll
      for (int ni = 0; ni < 4; ni++) {
        int col = n0 + wn * 64 + ni * 16 + l15;
        float bv = bias[col];
#pragma unroll
        for (int r = 0; r < 4; r++) {
          int row = m0 + wm * 64 + mi * 16 + quad * 4 + r;
          Cout[(size_t)row * N + col] = acc[mi][ni][r] + bv;
        }
      }
  } else {
    int which = n0 >> 11;
    int h = (n0 >> 7) & 15;
    unsigned short* P = (which == 0) ? Qb : (which == 1) ? Kb : Vb;
#pragma unroll
    for (int mi = 0; mi < 4; mi++)
#pragma unroll
      for (int ni = 0; ni < 4; ni++) {
        int d = wn * 64 + ni * 16 + l15;
        float bv = bias[n0 + d];
#pragma unroll
        for (int r = 0; r < 4; r++) {
          int m = m0 + wm * 64 + mi * 16 + quad * 4 + r;
          int b = m >> 11, t = m & (T_ - 1);
          size_t addr = (which == 2)
              ? ((size_t)((b * H_ + h) * HD_ + d)) * T_ + t    // V transposed
              : ((size_t)((b * H_ + h) * T_ + t)) * HD_ + d;   // Q,K row-major
          P[addr] = f2bf(acc[mi][ni][r] + bv);
        }
      }
  }
}

// ---------------------------------------------------------------------------
// RoPE in-place on bf16 Q and K, layout [B*H*T][128].
// theta_p = 10000^(-(2**p)/128) (faithful 2**p quirk), pos 1-indexed,
// pair (d, d+64). Q pre-scaled by 1/sqrt(HD)*log2(e) for exp2 softmax.
// ---------------------------------------------------------------------------
__global__ void rope_k(unsigned short* __restrict__ Q, unsigned short* __restrict__ K)
{
  const int tid = threadIdx.x;
  const int w = tid >> 6, l = tid & 63;
  const int r = blockIdx.x * 4 + w;
  const int t = r & (T_ - 1);
  const float pos = (float)(t + 1);
  const float theta = expf(-exp2f((float)l) * 0.07195578415606394f); // ln(1e4)/128
  const float ang = pos * theta;
  const float c = cosf(ang), s = sinf(ang);
  const float QS = 0.08838834764831845f * 1.4426950408889634f; // 1/sqrt(128)*log2(e)
  const size_t base = (size_t)r * HD_;

  float q0 = bf2f(Q[base + l]), q1 = bf2f(Q[base + l + 64]);
  Q[base + l]      = f2bf((q0 * c - q1 * s) * QS);
  Q[base + l + 64] = f2bf((q1 * c + q0 * s) * QS);
  float k0 = bf2f(K[base + l]), k1 = bf2f(K[base + l + 64]);
  K[base + l]      = f2bf(k0 * c - k1 * s);
  K[base + l + 64] = f2bf(k1 * c + k0 * s);
}

// ---------------------------------------------------------------------------
// Flash-style causal attention, round-10 revision.
// Grid 512 = (bh 32, XCD-swizzled) x (qpair 16); each block does Q-tiles
// qp*64 and (31-qp)*64 -> uniform 33 k-iters. 4 waves x 16 rows.
// K/V double-buffered (73 KB total LDS, 2 blocks/CU): next tile's 8 gll16
// issued after the WAR barrier; vmwait<8> retires exactly the current
// buffer's loads (counted, never 0 mid-loop); second barrier publishes them.
// Ledger: at iter-it vmwait, older ops = {prev-iter 8 stage loads} (+ qf
// loads / AO stores at tile starts, which must drain anyway) -> wait<=8
// retires all-but-the-8-new. Pl is wave-private -> no barrier between P-write
// and PV read; per-wave DS in-order + lgkmcnt(0).
// Kl [64][128]: slot (r,c16) holds global (r, c16^(r&15)); read col-chunk
// (kc*4+quad)^l15. Vl [128][64]: slot (r,c8) holds (r, c8^(r&7)); read
// (kc*4+quad)^(l15&7). Both -> residual 2-way bank aliasing (free).
// ---------------------------------------------------------------------------
__global__ __launch_bounds__(256, 2)
void attn_k(const unsigned short* __restrict__ Q,
            const unsigned short* __restrict__ K,
            const unsigned short* __restrict__ Vt_g,
            unsigned short* __restrict__ AO)
{
  __shared__ unsigned short Kl[2][64 * 128];
  __shared__ unsigned short Vl[2][128 * 64];
  __shared__ unsigned short Pl[4 * 16 * 72];

  const int tid  = threadIdx.x;
  const int wave = tid >> 6, lane = tid & 63;
  const int quad = lane >> 4, l15 = lane & 15;
  const int blk = blockIdx.x;
  const int bh = (blk & 7) + 8 * ((blk >> 3) & 3);
  const int qp = (blk >> 5) & 15;
  const unsigned short* Qh = Q    + (size_t)bh * T_ * HD_;
  const unsigned short* Kh = K    + (size_t)bh * T_ * HD_;
  const unsigned short* Vh = Vt_g + (size_t)bh * T_ * HD_;  // [d][t]
  const int b = bh >> 4, h = bh & 15;

#pragma unroll
  for (int tile = 0; tile < 2; tile++) {
    const int q0 = (tile == 0 ? qp : 31 - qp) * 64;
    const int wq = q0 + wave * 16;
    short8 qf[4];
#pragma unroll
    for (int kc = 0; kc < 4; kc++)
      qf[kc] = *(const short8*)&Qh[(size_t)(wq + l15) * HD_ + kc * 32 + quad * 8];

    f32x4 oacc[8];
#pragma unroll
    for (int n = 0; n < 8; n++) oacc[n] = (f32x4){0.f, 0.f, 0.f, 0.f};
    float mst[4], lst[4];
#pragma unroll
    for (int r = 0; r < 4; r++) { mst[r] = -1e30f; lst[r] = 0.f; }

    const int niter = (q0 >> 6) + 1;

    // prologue: stage k-tile 0 -> buffer 0 (barrier: WAR vs previous tile's
    // last PV reads of buffer 0)
    BARRIER();
#pragma unroll
    for (int i = 0; i < 4; i++) {
      int cc = i * 256 + wave * 64 + lane;  // slot id 0..1023
      int kr = cc >> 4, kcs = (cc & 15) ^ (kr & 15);
      gll16(Kh + (size_t)kr * HD_ + kcs * 8, &Kl[0][(i * 4 + wave) * 512]);
      int vr = cc >> 3, vcs = (cc & 7) ^ (vr & 7);
      gll16(Vh + (size_t)vr * T_ + vcs * 8, &Vl[0][(i * 4 + wave) * 512]);
    }

    for (int it = 0; it < niter; it++) {
      const int buf = it & 1;
      BARRIER();                       // all waves done reading buf^1
      if (it + 1 < niter) {            // stage next k-tile into buf^1
        const int kt1 = (it + 1) * 64;
#pragma unroll
        for (int i = 0; i < 4; i++) {
          int cc = i * 256 + wave * 64 + lane;
          int kr = cc >> 4, kcs = (cc & 15) ^ (kr & 15);
          gll16(Kh + (size_t)(kt1 + kr) * HD_ + kcs * 8, &Kl[buf ^ 1][(i * 4 + wave) * 512]);
          int vr = cc >> 3, vcs = (cc & 7) ^ (vr & 7);
          gll16(Vh + (size_t)vr * T_ + kt1 + vcs * 8, &Vl[buf ^ 1][(i * 4 + wave) * 512]);
        }
        vmwait<8>();                   // retire buf's loads; keep 8 in flight
      } else {
        vmwait<0>();
      }
      BARRIER();                       // all waves' buf loads retired

      const int kt = it * 64;
      // S' = (Q*s) K^T
      f32x4 sa[4];
#pragma unroll
      for (int ni = 0; ni < 4; ni++) sa[ni] = (f32x4){0.f, 0.f, 0.f, 0.f};
#pragma unroll
      for (int kc = 0; kc < 4; kc++) {
        const int cswK = (((kc * 4 + quad) ^ l15) * 8);
        short8 bfr[4];
#pragma unroll
        for (int ni = 0; ni < 4; ni++)
          bfr[ni] = *(const short8*)&Kl[buf][(ni * 16 + l15) * HD_ + cswK];
#pragma unroll
        for (int ni = 0; ni < 4; ni++)
          sa[ni] = __builtin_amdgcn_mfma_f32_16x16x32_bf16(qf[kc], bfr[ni], sa[ni], 0, 0, 0);
      }

      if (kt == q0) {   // causal mask, diagonal tile only (uniform branch)
#pragma unroll
        for (int ni = 0; ni < 4; ni++) {
          int gcol = kt + ni * 16 + l15;
#pragma unroll
          for (int r = 0; r < 4; r++) {
            int grow = wq + quad * 4 + r;
            if (gcol > grow) sa[ni][r] = -1e30f;
          }
        }
      }

      // online softmax, base-2. (sa <= rmax <= mst by construction -> no
      // clamps needed; exp2 of the -1e30 paths underflows to 0 correctly.)
      float rmax[4] = {-1e30f, -1e30f, -1e30f, -1e30f};
#pragma unroll
      for (int ni = 0; ni < 4; ni++)
#pragma unroll
        for (int r = 0; r < 4; r++) rmax[r] = fmaxf(rmax[r], sa[ni][r]);
#pragma unroll
      for (int r = 0; r < 4; r++)
#pragma unroll
        for (int off = 1; off < 16; off <<= 1)
          rmax[r] = fmaxf(rmax[r], __shfl_xor(rmax[r], off));
      // T13-style skip: if no row's max grew, alpha == 1 exactly -> skip the
      // rescale (bitwise-identical result).
      int grew = (rmax[0] > mst[0]) | (rmax[1] > mst[1]) |
                 (rmax[2] > mst[2]) | (rmax[3] > mst[3]);
      if (__any(grew)) {
        float alpha[4];
#pragma unroll
        for (int r = 0; r < 4; r++) {
          float mnew = fmaxf(mst[r], rmax[r]);
          alpha[r] = fexp2(mst[r] - mnew);
          mst[r] = mnew;
          lst[r] *= alpha[r];
        }
#pragma unroll
        for (int nv = 0; nv < 8; nv++)
#pragma unroll
          for (int r = 0; r < 4; r++) oacc[nv][r] *= alpha[r];
      }
      float rsum[4] = {0.f, 0.f, 0.f, 0.f};
#pragma unroll
      for (int ni = 0; ni < 4; ni++)
#pragma unroll
        for (int r = 0; r < 4; r++) {
          float p = fexp2(sa[ni][r] - mst[r]);
          sa[ni][r] = p;
          rsum[r] += p;
        }
#pragma unroll
      for (int r = 0; r < 4; r++) {
#pragma unroll
        for (int off = 1; off < 16; off <<= 1)
          rsum[r] += __shfl_xor(rsum[r], off);
        lst[r] += rsum[r];
      }
      // P -> LDS (wave-private region; per-wave DS ops are in-order, so an
      // lgkmcnt(0) suffices -- no block barrier between write and read).
#pragma unroll
      for (int ni = 0; ni < 4; ni++)
#pragma unroll
        for (int r = 0; r < 4; r++)
          Pl[wave * 16 * 72 + (quad * 4 + r) * 72 + ni * 16 + l15] = f2bf(sa[ni][r]);
      LGKM0();

      // O += P V
      short8 pf[2];
#pragma unroll
      for (int kc = 0; kc < 2; kc++)
        pf[kc] = *(const short8*)&Pl[wave * 16 * 72 + l15 * 72 + kc * 32 + quad * 8];
#pragma unroll
      for (int kc = 0; kc < 2; kc++) {
        const int cswV = (((kc * 4 + quad) ^ (l15 & 7)) * 8);
#pragma unroll
        for (int nv = 0; nv < 8; nv++) {
          short8 vb = *(const short8*)&Vl[buf][(nv * 16 + l15) * 64 + cswV];
          oacc[nv] = __builtin_amdgcn_mfma_f32_16x16x32_bf16(pf[kc], vb, oacc[nv], 0, 0, 0);
        }
      }
    }

    float linv[4];
#pragma unroll
    for (int r = 0; r < 4; r++) linv[r] = 1.0f / fmaxf(lst[r], 1e-20f);
#pragma unroll
    for (int nv = 0; nv < 8; nv++)
#pragma unroll
      for (int r = 0; r < 4; r++) {
        int t = wq + quad * 4 + r;
        int d = nv * 16 + l15;
        AO[((size_t)(b * T_ + t)) * C_ + h * HD_ + d] = f2bf(oacc[nv][r] * linv[r]);
      }
  }
}

// ---------------------------------------------------------------------------
// Fallback GEMM (f32 sources converted during staging) — only if ws too small.
// ---------------------------------------------------------------------------
template<int A32, int B32, int MODE>
__global__ __launch_bounds__(256, 2)
void gemm_nt(const void* __restrict__ Ap, const void* __restrict__ Bp,
             const float* __restrict__ bias,
             float* __restrict__ Cout,
             unsigned short* __restrict__ Qb,
             unsigned short* __restrict__ Kb,
             unsigned short* __restrict__ Vb,
             int N, int K)
{
  __shared__ unsigned short Al[128 * 72];
  __shared__ unsigned short Bl[128 * 72];
  const int tid  = threadIdx.x;
  const int wave = tid >> 6, lane = tid & 63;
  const int quad = lane >> 4, l15 = lane & 15;
  const int wm = wave >> 1, wn = wave & 1;
  const int n0 = blockIdx.x * 128, m0 = blockIdx.y * 128;

  f32x4 acc[4][4];
#pragma unroll
  for (int i = 0; i < 4; i++)
#pragma unroll
    for (int j = 0; j < 4; j++) acc[i][j] = (f32x4){0.f, 0.f, 0.f, 0.f};

  for (int k0 = 0; k0 < K; k0 += 64) {
    __syncthreads();
    if constexpr (A32) {
      const float* A = (const float*)Ap;
#pragma unroll
      for (int i = 0; i < 8; i++) {
        int cid = tid + i * 256;
        int r = cid >> 4, c = cid & 15;
        float4 v = *(const float4*)&A[(size_t)(m0 + r) * K + k0 + c * 4];
        ushort4 hh;
        hh.x = f2bf(v.x); hh.y = f2bf(v.y); hh.z = f2bf(v.z); hh.w = f2bf(v.w);
        *(ushort4*)&Al[r * 72 + c * 4] = hh;
      }
    } else {
      const unsigned short* A = (const unsigned short*)Ap;
#pragma unroll
      for (int i = 0; i < 4; i++) {
        int cid = tid + i * 256;
        int r = cid >> 3, c = cid & 7;
        *(float4*)&Al[r * 72 + c * 8] =
            *(const float4*)&A[(size_t)(m0 + r) * K + k0 + c * 8];
      }
    }
    if constexpr (B32) {
      const float* Bm = (const float*)Bp;
#pragma unroll
      for (int i = 0; i < 8; i++) {
        int cid = tid + i * 256;
        int r = cid >> 4, c = cid & 15;
        float4 v = *(const float4*)&Bm[(size_t)(n0 + r) * K + k0 + c * 4];
        ushort4 hh;
        hh.x = f2bf(v.x); hh.y = f2bf(v.y); hh.z = f2bf(v.z); hh.w = f2bf(v.w);
        *(ushort4*)&Bl[r * 72 + c * 4] = hh;
      }
    } else {
      const unsigned short* Bm = (const unsigned short*)Bp;
#pragma unroll
      for (int i = 0; i < 4; i++) {
        int cid = tid + i * 256;
        int r = cid >> 3, c = cid & 7;
        *(float4*)&Bl[r * 72 + c * 8] =
            *(const float4*)&Bm[(size_t)(n0 + r) * K + k0 + c * 8];
      }
    }
    __syncthreads();
#pragma unroll
    for (int kc = 0; kc < 2; kc++) {
      short8 af[4], bfr[4];
#pragma unroll
      for (int mi = 0; mi < 4; mi++)
        af[mi] = *(const short8*)&Al[(wm * 64 + mi * 16 + l15) * 72 + kc * 32 + quad * 8];
#pragma unroll
      for (int ni = 0; ni < 4; ni++)
        bfr[ni] = *(const short8*)&Bl[(wn * 64 + ni * 16 + l15) * 72 + kc * 32 + quad * 8];
#pragma unroll
      for (int mi = 0; mi < 4; mi++)
#pragma unroll
        for (int ni = 0; ni < 4; ni++)
          acc[mi][ni] = __builtin_amdgcn_mfma_f32_16x16x32_bf16(af[mi], bfr[ni], acc[mi][ni], 0, 0, 0);
    }
  }

  if constexpr (MODE == 0) {
#pragma unroll
    for (int mi = 0; mi < 4; mi++)
#pragma unroll
      for (int ni = 0; ni < 4; ni++) {
        int col = n0 + wn * 64 + ni * 16 + l15;
        float bv = bias[col];
#pragma unroll
        for (int r = 0; r < 4; r++) {
          int row = m0 + wm * 64 + mi * 16 + quad * 4 + r;
          Cout[(size_t)row * N + col] = acc[mi][ni][r] + bv;
        }
      }
  } else {
    int which = n0 >> 11;
    int h = (n0 >> 7) & 15;
    unsigned short* P = (which == 0) ? Qb : (which == 1) ? Kb : Vb;
#pragma unroll
    for (int mi = 0; mi < 4; mi++)
#pragma unroll
      for (int ni = 0; ni < 4; ni++) {
        int d = wn * 64 + ni * 16 + l15;
        float bv = bias[n0 + d];
#pragma unroll
        for (int r = 0; r < 4; r++) {
          int m = m0 + wm * 64 + mi * 16 + quad * 4 + r;
          int b = m >> 11, t = m & (T_ - 1);
          size_t addr = (which == 2)
              ? ((size_t)((b * H_ + h) * HD_ + d)) * T_ + t
              : ((size_t)((b * H_ + h) * T_ + t)) * HD_ + d;
          P[addr] = f2bf(acc[mi][ni][r] + bv);
        }
      }
  }
}

// ---------------------------------------------------------------------------
extern "C" void kernel_launch(void* const* d_in, const int* in_sizes, int n_in,
                              void* d_out, int out_size, void* d_ws, size_t ws_size,
                              hipStream_t stream)
{
  const float* x    = (const float*)d_in[0];  // [2,2048,2048] f32
  const float* Wqkv = (const float*)d_in[1];  // [6144,2048]   f32
  const float* bqkv = (const float*)d_in[2];  // [6144]        f32
  const float* Wo   = (const float*)d_in[3];  // [2048,2048]   f32
  const float* bo   = (const float*)d_in[4];  // [2048]        f32
  float* out = (float*)d_out;                 // [2,2048,2048] f32

  const size_t SZ   = (size_t)B_ * H_ * T_ * HD_;   // 8,388,608
  const size_t NX   = SZ;
  const size_t NWQ  = (size_t)3 * C_ * C_;
  const size_t NWO  = (size_t)C_ * C_;
  unsigned short* ws = (unsigned short*)d_ws;

  dim3 blk(256, 1, 1);
  const size_t need = (NX + NWQ + 3 * SZ) * sizeof(unsigned short);  // 92.3 MB

  if (ws_size >= need) {
    unsigned short* xb    = ws;
    unsigned short* Wqkvb = xb + NX;
    unsigned short* Qb    = Wqkvb + NWQ;
    unsigned short* Kb    = Qb + SZ;
    unsigned short* Vb    = Kb + SZ;      // transposed [bh][d][t]
    unsigned short* AO    = xb;           // alias: x dead after QKV GEMM
    unsigned short* Wob   = Wqkvb;        // alias: Wqkv dead after QKV GEMM

    cvt_k<<<dim3((unsigned)(NX / 1024)), blk, 0, stream>>>(x, xb, (int)(NX / 4));
    cvt_k<<<dim3((unsigned)(NWQ / 1024)), blk, 0, stream>>>(Wqkv, Wqkvb, (int)(NWQ / 4));
    gemm_bt<1><<<dim3(48, 32, 1), blk, 0, stream>>>(
        xb, Wqkvb, bqkv, nullptr, Qb, Kb, Vb, 6144, 2048);
    cvt_k<<<dim3((unsigned)(NWO / 1024)), blk, 0, stream>>>(Wo, Wob, (int)(NWO / 4));
    rope_k<<<dim3((B_ * H_ * T_) / 4, 1, 1), blk, 0, stream>>>(Qb, Kb);
    attn_k<<<dim3(512, 1, 1), blk, 0, stream>>>(Qb, Kb, Vb, AO);
    gemm_bt<0><<<dim3(16, 32, 1), blk, 0, stream>>>(
        AO, Wob, bo, out, nullptr, nullptr, nullptr, 2048, 2048);
  } else {
    unsigned short* Qb = ws;
    unsigned short* Kb = Qb + SZ;
    unsigned short* Vb = Kb + SZ;
    unsigned short* AO = Vb + SZ;
    gemm_nt<1, 1, 1><<<dim3(48, 32, 1), blk, 0, stream>>>(
        (const void*)x, (const void*)Wqkv, bqkv, nullptr, Qb, Kb, Vb, 6144, 2048);
    rope_k<<<dim3((B_ * H_ * T_) / 4, 1, 1), blk, 0, stream>>>(Qb, Kb);
    attn_k<<<dim3(512, 1, 1), blk, 0, stream>>>(Qb, Kb, Vb, AO);
    gemm_nt<0, 1, 0><<<dim3(16, 32, 1), blk, 0, stream>>>(
        (const void*)AO, (const void*)Wo, bo, out, nullptr, nullptr, nullptr, 2048, 2048);
  }
}

// Round 9
// 395.466 us; speedup vs baseline: 1.1014x; 1.0058x over previous
//
#include <hip/hip_runtime.h>
#include <hip/hip_bf16.h>

// Problem: B=2, T=2048, C=2048, H=16, HD=128.
// Round 11 (resubmit; round-8 bench lost to GPU-broker timeout).
// Attribution + safe-trims. r7 (attn double-buffer + counted vmcnt rewrite)
// raised non-GEMM time ~40 us even as QKV improved with machine state
// (149->123 us). Revert attn to the round-0 proven structure (single-buffer
// staging, __syncthreads drains - the implicit 2-blocks/CU cross-block
// overlap already hides the drain, m114) keeping only the three orthogonal
// safe trims from r7:
//   (a) P-write -> PV barrier replaced by lgkmcnt(0): Pl is wave-private,
//       per-wave DS ops in-order; strictly removes a full-drain barrier.
//   (b) fminf clamps dropped: sa <= rmax <= mst by construction.
//   (c) alpha-rescale skip via __any(grew): alpha==1 is bitwise identity.
// GEMMs remain round-0 gemm_bt (proven; r6-r9 established the 128^2
// 2-barrier structure beats every pipelined variant tried at this shape).

typedef __attribute__((ext_vector_type(8))) short short8;   // 8 bf16 MFMA A/B frag
typedef __attribute__((ext_vector_type(4))) float f32x4;    // MFMA C/D frag

#define B_  2
#define T_  2048
#define C_  2048
#define H_  16
#define HD_ 128

#define LGKM0()   asm volatile("s_waitcnt lgkmcnt(0)" ::: "memory")

__device__ __forceinline__ float bf2f(unsigned short u) {
  union { unsigned int i; float f; } v; v.i = ((unsigned int)u) << 16; return v.f;
}
__device__ __forceinline__ unsigned short f2bf(float f) {
  union { float f; unsigned int i; } v; v.f = f;
  unsigned int x = v.i;
  return (unsigned short)((x + 0x7fffu + ((x >> 16) & 1u)) >> 16);  // RNE
}
__device__ __forceinline__ float fexp2(float x) {
#if __has_builtin(__builtin_amdgcn_exp2f)
  return __builtin_amdgcn_exp2f(x);
#else
  return exp2f(x);
#endif
}

// async 16B global->LDS; lds base wave-uniform, lane l lands at base + l*16.
__device__ __forceinline__ void gll16(const unsigned short* g, unsigned short* lds_base) {
  __builtin_amdgcn_global_load_lds(
      (const __attribute__((address_space(1))) void*)g,
      (__attribute__((address_space(3))) void*)lds_base, 16, 0, 0);
}

// ---------------------------------------------------------------------------
// f32 -> bf16 elementwise convert, 4 elems/thread.
// ---------------------------------------------------------------------------
__global__ void cvt_k(const float* __restrict__ src, unsigned short* __restrict__ dst, int n4)
{
  int i = blockIdx.x * blockDim.x + threadIdx.x;
  if (i < n4) {
    float4 v = ((const float4*)src)[i];
    ushort4 h;
    h.x = f2bf(v.x); h.y = f2bf(v.y); h.z = f2bf(v.z); h.w = f2bf(v.w);
    ((ushort4*)dst)[i] = h;
  }
}

// ---------------------------------------------------------------------------
// m97-style NT GEMM (bf16 x bf16): C[M][N] = A[M][K]*Bw[N][K]^T + bias.
// 128x128 tile, BK=64, 2x2 waves of 64x64, 4x4 16x16x32 MFMA frags,
// global_load_lds width=16 staging, XOR-swizzled LDS columns.
// MODE 0: f32 row-major store. MODE 1: bf16 qkv scatter:
//   Q,K -> [bh][t][d];  V -> TRANSPOSED [bh][d][t].
// MFMA layouts (HW-verified m89/m91): A: A[m=lane&15][k=quad*8+j];
// B: B[k=quad*8+j][n=lane&15]; C/D: col=lane&15, row=quad*4+reg.
// (round-0 kernel, verbatim.)
// ---------------------------------------------------------------------------
template<int MODE>
__global__ __launch_bounds__(256, 2)
void gemm_bt(const unsigned short* __restrict__ A,
             const unsigned short* __restrict__ Bw,
             const float* __restrict__ bias,
             float* __restrict__ Cout,
             unsigned short* __restrict__ Qb,
             unsigned short* __restrict__ Kb,
             unsigned short* __restrict__ Vb,
             int N, int K)
{
  __shared__ unsigned short Al[128 * 64];
  __shared__ unsigned short Bl[128 * 64];
  const int tid  = threadIdx.x;
  const int wave = tid >> 6, lane = tid & 63;
  const int quad = lane >> 4, l15 = lane & 15;
  const int wm = wave >> 1, wn = wave & 1;
  const int n0 = blockIdx.x * 128, m0 = blockIdx.y * 128;

  f32x4 acc[4][4];
#pragma unroll
  for (int i = 0; i < 4; i++)
#pragma unroll
    for (int j = 0; j < 4; j++) acc[i][j] = (f32x4){0.f, 0.f, 0.f, 0.f};

  for (int k0 = 0; k0 < K; k0 += 64) {
    __syncthreads();
    const unsigned short* Ag = A + (size_t)m0 * K + k0;
    const unsigned short* Bg = Bw + (size_t)n0 * K + k0;
#pragma unroll
    for (int i = 0; i < 4; i++) {
      int cc = i * 256 + wave * 64 + lane;      // LDS 16B-slot id, 0..1023
      int r = cc >> 3;
      int c8 = (cc & 7) ^ (r & 7);              // swizzled source col chunk
      gll16(Ag + (size_t)r * K + c8 * 8, &Al[(i * 4 + wave) * 512]);
      gll16(Bg + (size_t)r * K + c8 * 8, &Bl[(i * 4 + wave) * 512]);
    }
    __syncthreads();
#pragma unroll
    for (int kc = 0; kc < 2; kc++) {
      // swizzled col offset: row&7 == l15&7 for all mi/ni (offsets are *8)
      const int csw = (((kc * 4 + quad) ^ (l15 & 7)) * 8);
      short8 af[4], bfr[4];
#pragma unroll
      for (int mi = 0; mi < 4; mi++)
        af[mi] = *(const short8*)&Al[(wm * 64 + mi * 16 + l15) * 64 + csw];
#pragma unroll
      for (int ni = 0; ni < 4; ni++)
        bfr[ni] = *(const short8*)&Bl[(wn * 64 + ni * 16 + l15) * 64 + csw];
#pragma unroll
      for (int mi = 0; mi < 4; mi++)
#pragma unroll
        for (int ni = 0; ni < 4; ni++)
          acc[mi][ni] = __builtin_amdgcn_mfma_f32_16x16x32_bf16(af[mi], bfr[ni], acc[mi][ni], 0, 0, 0);
    }
  }

  if constexpr (MODE == 0) {
#pragma unroll
    for (int mi = 0; mi < 4; mi++)
#pragma unroll
      for (int ni = 0; ni < 4; ni++) {
        int col = n0 + wn * 64 + ni * 16 + l15;
        float bv = bias[col];
#pragma unroll
        for (int r = 0; r < 4; r++) {
          int row = m0 + wm * 64 + mi * 16 + quad * 4 + r;
          Cout[(size_t)row * N + col] = acc[mi][ni][r] + bv;
        }
      }
  } else {
    int which = n0 >> 11;
    int h = (n0 >> 7) & 15;
    unsigned short* P = (which == 0) ? Qb : (which == 1) ? Kb : Vb;
#pragma unroll
    for (int mi = 0; mi < 4; mi++)
#pragma unroll
      for (int ni = 0; ni < 4; ni++) {
        int d = wn * 64 + ni * 16 + l15;
        float bv = bias[n0 + d];
#pragma unroll
        for (int r = 0; r < 4; r++) {
          int m = m0 + wm * 64 + mi * 16 + quad * 4 + r;
          int b = m >> 11, t = m & (T_ - 1);
          size_t addr = (which == 2)
              ? ((size_t)((b * H_ + h) * HD_ + d)) * T_ + t    // V transposed
              : ((size_t)((b * H_ + h) * T_ + t)) * HD_ + d;   // Q,K row-major
          P[addr] = f2bf(acc[mi][ni][r] + bv);
        }
      }
  }
}

// ---------------------------------------------------------------------------
// RoPE in-place on bf16 Q and K, layout [B*H*T][128].
// theta_p = 10000^(-(2**p)/128) (faithful 2**p quirk), pos 1-indexed,
// pair (d, d+64). Q pre-scaled by 1/sqrt(HD)*log2(e) for exp2 softmax.
// ---------------------------------------------------------------------------
__global__ void rope_k(unsigned short* __restrict__ Q, unsigned short* __restrict__ K)
{
  const int tid = threadIdx.x;
  const int w = tid >> 6, l = tid & 63;
  const int r = blockIdx.x * 4 + w;
  const int t = r & (T_ - 1);
  const float pos = (float)(t + 1);
  const float theta = expf(-exp2f((float)l) * 0.07195578415606394f); // ln(1e4)/128
  const float ang = pos * theta;
  const float c = cosf(ang), s = sinf(ang);
  const float QS = 0.08838834764831845f * 1.4426950408889634f; // 1/sqrt(128)*log2(e)
  const size_t base = (size_t)r * HD_;

  float q0 = bf2f(Q[base + l]), q1 = bf2f(Q[base + l + 64]);
  Q[base + l]      = f2bf((q0 * c - q1 * s) * QS);
  Q[base + l + 64] = f2bf((q1 * c + q0 * s) * QS);
  float k0 = bf2f(K[base + l]), k1 = bf2f(K[base + l + 64]);
  K[base + l]      = f2bf(k0 * c - k1 * s);
  K[base + l + 64] = f2bf(k1 * c + k0 * s);
}

// ---------------------------------------------------------------------------
// Flash-style causal attention — round-0 structure + safe trims only.
// Grid 512 = (bh 32, XCD-swizzled) x (qpair 16); each block does Q-tiles
// qp*64 and (31-qp)*64 -> uniform 33 k-iters. 4 waves x 16 rows.
// Single-buffer K/V staging with __syncthreads drains (proven; implicit
// cross-block overlap at 2 blocks/CU hides the drain). Trims vs r0:
//  (a) Pl barrier -> lgkmcnt(0) (Pl wave-private, per-wave DS in-order);
//  (b) no fminf clamps (sa <= rmax <= mst by construction);
//  (c) alpha-skip via __any(grew) (alpha==1 identity).
// Kl [64][128]: slot (r,c16) holds global (r, c16^(r&15)); read col-chunk
// (kc*4+quad)^l15. Vl [128][64]: slot (r,c8) holds (r, c8^(r&7)); read
// (kc*4+quad)^(l15&7). Both -> residual 2-way bank aliasing (free).
// ---------------------------------------------------------------------------
__global__ __launch_bounds__(256, 2)
void attn_k(const unsigned short* __restrict__ Q,
            const unsigned short* __restrict__ K,
            const unsigned short* __restrict__ Vt_g,
            unsigned short* __restrict__ AO)
{
  __shared__ unsigned short Kl[64 * 128];
  __shared__ unsigned short Vl[128 * 64];
  __shared__ unsigned short Pl[4 * 16 * 72];

  const int tid  = threadIdx.x;
  const int wave = tid >> 6, lane = tid & 63;
  const int quad = lane >> 4, l15 = lane & 15;
  const int blk = blockIdx.x;
  const int bh = (blk & 7) + 8 * ((blk >> 3) & 3);
  const int qp = (blk >> 5) & 15;
  const unsigned short* Qh = Q    + (size_t)bh * T_ * HD_;
  const unsigned short* Kh = K    + (size_t)bh * T_ * HD_;
  const unsigned short* Vh = Vt_g + (size_t)bh * T_ * HD_;  // [d][t]
  const int b = bh >> 4, h = bh & 15;

#pragma unroll
  for (int tile = 0; tile < 2; tile++) {
    const int q0 = (tile == 0 ? qp : 31 - qp) * 64;
    const int wq = q0 + wave * 16;
    short8 qf[4];
#pragma unroll
    for (int kc = 0; kc < 4; kc++)
      qf[kc] = *(const short8*)&Qh[(size_t)(wq + l15) * HD_ + kc * 32 + quad * 8];

    f32x4 oacc[8];
#pragma unroll
    for (int n = 0; n < 8; n++) oacc[n] = (f32x4){0.f, 0.f, 0.f, 0.f};
    float mst[4], lst[4];
#pragma unroll
    for (int r = 0; r < 4; r++) { mst[r] = -1e30f; lst[r] = 0.f; }

    const int niter = (q0 >> 6) + 1;
    for (int it = 0; it < niter; it++) {
      const int kt = it * 64;
      __syncthreads();
      // stage K [64][128] and V^T [128][64], source-col XOR swizzle
#pragma unroll
      for (int i = 0; i < 4; i++) {
        int cc = i * 256 + wave * 64 + lane;  // slot id 0..1023
        int kr = cc >> 4, kcs = (cc & 15) ^ (kr & 15);
        gll16(Kh + (size_t)(kt + kr) * HD_ + kcs * 8, &Kl[(i * 4 + wave) * 512]);
        int vr = cc >> 3, vcs = (cc & 7) ^ (vr & 7);
        gll16(Vh + (size_t)vr * T_ + kt + vcs * 8, &Vl[(i * 4 + wave) * 512]);
      }
      __syncthreads();

      // S' = (Q*s) K^T
      f32x4 sa[4];
#pragma unroll
      for (int ni = 0; ni < 4; ni++) sa[ni] = (f32x4){0.f, 0.f, 0.f, 0.f};
#pragma unroll
      for (int kc = 0; kc < 4; kc++) {
        const int cswK = (((kc * 4 + quad) ^ l15) * 8);
        short8 bfr[4];
#pragma unroll
        for (int ni = 0; ni < 4; ni++)
          bfr[ni] = *(const short8*)&Kl[(ni * 16 + l15) * HD_ + cswK];
#pragma unroll
        for (int ni = 0; ni < 4; ni++)
          sa[ni] = __builtin_amdgcn_mfma_f32_16x16x32_bf16(qf[kc], bfr[ni], sa[ni], 0, 0, 0);
      }

      if (kt == q0) {   // causal mask, diagonal tile only (uniform branch)
#pragma unroll
        for (int ni = 0; ni < 4; ni++) {
          int gcol = kt + ni * 16 + l15;
#pragma unroll
          for (int r = 0; r < 4; r++) {
            int grow = wq + quad * 4 + r;
            if (gcol > grow) sa[ni][r] = -1e30f;
          }
        }
      }

      // online softmax, base-2. (sa <= rmax <= mst by construction -> no
      // clamps; exp2 of -1e30 underflows to 0 correctly.)
      float rmax[4] = {-1e30f, -1e30f, -1e30f, -1e30f};
#pragma unroll
      for (int ni = 0; ni < 4; ni++)
#pragma unroll
        for (int r = 0; r < 4; r++) rmax[r] = fmaxf(rmax[r], sa[ni][r]);
#pragma unroll
      for (int r = 0; r < 4; r++)
#pragma unroll
        for (int off = 1; off < 16; off <<= 1)
          rmax[r] = fmaxf(rmax[r], __shfl_xor(rmax[r], off));
      // alpha-skip: if no row's max grew, alpha == 1 exactly -> skip the
      // rescale (bitwise-identical result).
      int grew = (rmax[0] > mst[0]) | (rmax[1] > mst[1]) |
                 (rmax[2] > mst[2]) | (rmax[3] > mst[3]);
      if (__any(grew)) {
        float alpha[4];
#pragma unroll
        for (int r = 0; r < 4; r++) {
          float mnew = fmaxf(mst[r], rmax[r]);
          alpha[r] = fexp2(mst[r] - mnew);
          mst[r] = mnew;
          lst[r] *= alpha[r];
        }
#pragma unroll
        for (int nv = 0; nv < 8; nv++)
#pragma unroll
          for (int r = 0; r < 4; r++) oacc[nv][r] *= alpha[r];
      }
      float rsum[4] = {0.f, 0.f, 0.f, 0.f};
#pragma unroll
      for (int ni = 0; ni < 4; ni++)
#pragma unroll
        for (int r = 0; r < 4; r++) {
          float p = fexp2(sa[ni][r] - mst[r]);
          sa[ni][r] = p;
          rsum[r] += p;
        }
#pragma unroll
      for (int r = 0; r < 4; r++) {
#pragma unroll
        for (int off = 1; off < 16; off <<= 1)
          rsum[r] += __shfl_xor(rsum[r], off);
        lst[r] += rsum[r];
      }
      // P -> LDS (wave-private region; per-wave DS ops in-order, so
      // lgkmcnt(0) suffices -- no block barrier between write and read).
#pragma unroll
      for (int ni = 0; ni < 4; ni++)
#pragma unroll
        for (int r = 0; r < 4; r++)
          Pl[wave * 16 * 72 + (quad * 4 + r) * 72 + ni * 16 + l15] = f2bf(sa[ni][r]);
      LGKM0();

      // O += P V
      short8 pf[2];
#pragma unroll
      for (int kc = 0; kc < 2; kc++)
        pf[kc] = *(const short8*)&Pl[wave * 16 * 72 + l15 * 72 + kc * 32 + quad * 8];
#pragma unroll
      for (int kc = 0; kc < 2; kc++) {
        const int cswV = (((kc * 4 + quad) ^ (l15 & 7)) * 8);
#pragma unroll
        for (int nv = 0; nv < 8; nv++) {
          short8 vb = *(const short8*)&Vl[(nv * 16 + l15) * 64 + cswV];
          oacc[nv] = __builtin_amdgcn_mfma_f32_16x16x32_bf16(pf[kc], vb, oacc[nv], 0, 0, 0);
        }
      }
    }

    float linv[4];
#pragma unroll
    for (int r = 0; r < 4; r++) linv[r] = 1.0f / fmaxf(lst[r], 1e-20f);
#pragma unroll
    for (int nv = 0; nv < 8; nv++)
#pragma unroll
      for (int r = 0; r < 4; r++) {
        int t = wq + quad * 4 + r;
        int d = nv * 16 + l15;
        AO[((size_t)(b * T_ + t)) * C_ + h * HD_ + d] = f2bf(oacc[nv][r] * linv[r]);
      }
  }
}

// ---------------------------------------------------------------------------
// Fallback GEMM (f32 sources converted during staging) — only if ws too small.
// ---------------------------------------------------------------------------
template<int A32, int B32, int MODE>
__global__ __launch_bounds__(256, 2)
void gemm_nt(const void* __restrict__ Ap, const void* __restrict__ Bp,
             const float* __restrict__ bias,
             float* __restrict__ Cout,
             unsigned short* __restrict__ Qb,
             unsigned short* __restrict__ Kb,
             unsigned short* __restrict__ Vb,
             int N, int K)
{
  __shared__ unsigned short Al[128 * 72];
  __shared__ unsigned short Bl[128 * 72];
  const int tid  = threadIdx.x;
  const int wave = tid >> 6, lane = tid & 63;
  const int quad = lane >> 4, l15 = lane & 15;
  const int wm = wave >> 1, wn = wave & 1;
  const int n0 = blockIdx.x * 128, m0 = blockIdx.y * 128;

  f32x4 acc[4][4];
#pragma unroll
  for (int i = 0; i < 4; i++)
#pragma unroll
    for (int j = 0; j < 4; j++) acc[i][j] = (f32x4){0.f, 0.f, 0.f, 0.f};

  for (int k0 = 0; k0 < K; k0 += 64) {
    __syncthreads();
    if constexpr (A32) {
      const float* A = (const float*)Ap;
#pragma unroll
      for (int i = 0; i < 8; i++) {
        int cid = tid + i * 256;
        int r = cid >> 4, c = cid & 15;
        float4 v = *(const float4*)&A[(size_t)(m0 + r) * K + k0 + c * 4];
        ushort4 hh;
        hh.x = f2bf(v.x); hh.y = f2bf(v.y); hh.z = f2bf(v.z); hh.w = f2bf(v.w);
        *(ushort4*)&Al[r * 72 + c * 4] = hh;
      }
    } else {
      const unsigned short* A = (const unsigned short*)Ap;
#pragma unroll
      for (int i = 0; i < 4; i++) {
        int cid = tid + i * 256;
        int r = cid >> 3, c = cid & 7;
        *(float4*)&Al[r * 72 + c * 8] =
            *(const float4*)&A[(size_t)(m0 + r) * K + k0 + c * 8];
      }
    }
    if constexpr (B32) {
      const float* Bm = (const float*)Bp;
#pragma unroll
      for (int i = 0; i < 8; i++) {
        int cid = tid + i * 256;
        int r = cid >> 4, c = cid & 15;
        float4 v = *(const float4*)&Bm[(size_t)(n0 + r) * K + k0 + c * 4];
        ushort4 hh;
        hh.x = f2bf(v.x); hh.y = f2bf(v.y); hh.z = f2bf(v.z); hh.w = f2bf(v.w);
        *(ushort4*)&Bl[r * 72 + c * 4] = hh;
      }
    } else {
      const unsigned short* Bm = (const unsigned short*)Bp;
#pragma unroll
      for (int i = 0; i < 4; i++) {
        int cid = tid + i * 256;
        int r = cid >> 3, c = cid & 7;
        *(float4*)&Bl[r * 72 + c * 8] =
            *(const float4*)&Bm[(size_t)(n0 + r) * K + k0 + c * 8];
      }
    }
    __syncthreads();
#pragma unroll
    for (int kc = 0; kc < 2; kc++) {
      short8 af[4], bfr[4];
#pragma unroll
      for (int mi = 0; mi < 4; mi++)
        af[mi] = *(const short8*)&Al[(wm * 64 + mi * 16 + l15) * 72 + kc * 32 + quad * 8];
#pragma unroll
      for (int ni = 0; ni < 4; ni++)
        bfr[ni] = *(const short8*)&Bl[(wn * 64 + ni * 16 + l15) * 72 + kc * 32 + quad * 8];
#pragma unroll
      for (int mi = 0; mi < 4; mi++)
#pragma unroll
        for (int ni = 0; ni < 4; ni++)
          acc[mi][ni] = __builtin_amdgcn_mfma_f32_16x16x32_bf16(af[mi], bfr[ni], acc[mi][ni], 0, 0, 0);
    }
  }

  if constexpr (MODE == 0) {
#pragma unroll
    for (int mi = 0; mi < 4; mi++)
#pragma unroll
      for (int ni = 0; ni < 4; ni++) {
        int col = n0 + wn * 64 + ni * 16 + l15;
        float bv = bias[col];
#pragma unroll
        for (int r = 0; r < 4; r++) {
          int row = m0 + wm * 64 + mi * 16 + quad * 4 + r;
          Cout[(size_t)row * N + col] = acc[mi][ni][r] + bv;
        }
      }
  } else {
    int which = n0 >> 11;
    int h = (n0 >> 7) & 15;
    unsigned short* P = (which == 0) ? Qb : (which == 1) ? Kb : Vb;
#pragma unroll
    for (int mi = 0; mi < 4; mi++)
#pragma unroll
      for (int ni = 0; ni < 4; ni++) {
        int d = wn * 64 + ni * 16 + l15;
        float bv = bias[n0 + d];
#pragma unroll
        for (int r = 0; r < 4; r++) {
          int m = m0 + wm * 64 + mi * 16 + quad * 4 + r;
          int b = m >> 11, t = m & (T_ - 1);
          size_t addr = (which == 2)
              ? ((size_t)((b * H_ + h) * HD_ + d)) * T_ + t
              : ((size_t)((b * H_ + h) * T_ + t)) * HD_ + d;
          P[addr] = f2bf(acc[mi][ni][r] + bv);
        }
      }
  }
}

// ---------------------------------------------------------------------------
extern "C" void kernel_launch(void* const* d_in, const int* in_sizes, int n_in,
                              void* d_out, int out_size, void* d_ws, size_t ws_size,
                              hipStream_t stream)
{
  const float* x    = (const float*)d_in[0];  // [2,2048,2048] f32
  const float* Wqkv = (const float*)d_in[1];  // [6144,2048]   f32
  const float* bqkv = (const float*)d_in[2];  // [6144]        f32
  const float* Wo   = (const float*)d_in[3];  // [2048,2048]   f32
  const float* bo   = (const float*)d_in[4];  // [2048]        f32
  float* out = (float*)d_out;                 // [2,2048,2048] f32

  const size_t SZ   = (size_t)B_ * H_ * T_ * HD_;   // 8,388,608
  const size_t NX   = SZ;
  const size_t NWQ  = (size_t)3 * C_ * C_;
  const size_t NWO  = (size_t)C_ * C_;
  unsigned short* ws = (unsigned short*)d_ws;

  dim3 blk(256, 1, 1);
  const size_t need = (NX + NWQ + 3 * SZ) * sizeof(unsigned short);  // 92.3 MB

  if (ws_size >= need) {
    unsigned short* xb    = ws;
    unsigned short* Wqkvb = xb + NX;
    unsigned short* Qb    = Wqkvb + NWQ;
    unsigned short* Kb    = Qb + SZ;
    unsigned short* Vb    = Kb + SZ;      // transposed [bh][d][t]
    unsigned short* AO    = xb;           // alias: x dead after QKV GEMM
    unsigned short* Wob   = Wqkvb;        // alias: Wqkv dead after QKV GEMM

    cvt_k<<<dim3((unsigned)(NX / 1024)), blk, 0, stream>>>(x, xb, (int)(NX / 4));
    cvt_k<<<dim3((unsigned)(NWQ / 1024)), blk, 0, stream>>>(Wqkv, Wqkvb, (int)(NWQ / 4));
    gemm_bt<1><<<dim3(48, 32, 1), blk, 0, stream>>>(
        xb, Wqkvb, bqkv, nullptr, Qb, Kb, Vb, 6144, 2048);
    cvt_k<<<dim3((unsigned)(NWO / 1024)), blk, 0, stream>>>(Wo, Wob, (int)(NWO / 4));
    rope_k<<<dim3((B_ * H_ * T_) / 4, 1, 1), blk, 0, stream>>>(Qb, Kb);
    attn_k<<<dim3(512, 1, 1), blk, 0, stream>>>(Qb, Kb, Vb, AO);
    gemm_bt<0><<<dim3(16, 32, 1), blk, 0, stream>>>(
        AO, Wob, bo, out, nullptr, nullptr, nullptr, 2048, 2048);
  } else {
    unsigned short* Qb = ws;
    unsigned short* Kb = Qb + SZ;
    unsigned short* Vb = Kb + SZ;
    unsigned short* AO = Vb + SZ;
    gemm_nt<1, 1, 1><<<dim3(48, 32, 1), blk, 0, stream>>>(
        (const void*)x, (const void*)Wqkv, bqkv, nullptr, Qb, Kb, Vb, 6144, 2048);
    rope_k<<<dim3((B_ * H_ * T_) / 4, 1, 1), blk, 0, stream>>>(Qb, Kb);
    attn_k<<<dim3(512, 1, 1), blk, 0, stream>>>(Qb, Kb, Vb, AO);
    gemm_nt<0, 1, 0><<<dim3(16, 32, 1), blk, 0, stream>>>(
        (const void*)AO, (const void*)Wo, bo, out, nullptr, nullptr, nullptr, 2048, 2048);
  }
}

// Round 10
// 391.678 us; speedup vs baseline: 1.1120x; 1.0097x over previous
//
#include <hip/hip_runtime.h>
#include <hip/hip_bf16.h>

// Problem: B=2, T=2048, C=2048, H=16, HD=128.
// Round 12: launch-graph surgery. r7 vs r9 at matched clocks showed the attn
// rewrite was noise (397.8 vs 395.5); QKV sits AT the m97-structure ceiling
// (MfmaUtil 37%). Budget analysis leaves ~60-80 us in launch boundaries +
// the rope pass. Changes (numerics-preserving):
//  1. RoPE fused into gemm_bt<1> epilogue for Q/K blocks: each block = one
//     head (n0 128-aligned), pair (d,d+64) exchanged through the dead Al/Bl
//     LDS (exactly 32 KB = 128x128 bf16). Value path f2bf->LDS->bf2f->
//     rotate(f32)->f2bf is identical to the old store->rope_k->store chain.
//     Deletes rope_k launch + 67 MB HBM traffic.
//  2. cvt launches merged: cvt3_k (x,Wqkv,Wo) pre-GEMM when ws fits a
//     non-aliased Wo buffer (need2), else cvt2_k + post-GEMM Wo cvt.
//  Launches 7 -> 4 (or 5). attn (r9-proven) and GEMM loops untouched.

typedef __attribute__((ext_vector_type(8))) short short8;   // 8 bf16 MFMA A/B frag
typedef __attribute__((ext_vector_type(4))) float f32x4;    // MFMA C/D frag

#define B_  2
#define T_  2048
#define C_  2048
#define H_  16
#define HD_ 128

#define LGKM0()   asm volatile("s_waitcnt lgkmcnt(0)" ::: "memory")

__device__ __forceinline__ float bf2f(unsigned short u) {
  union { unsigned int i; float f; } v; v.i = ((unsigned int)u) << 16; return v.f;
}
__device__ __forceinline__ unsigned short f2bf(float f) {
  union { float f; unsigned int i; } v; v.f = f;
  unsigned int x = v.i;
  return (unsigned short)((x + 0x7fffu + ((x >> 16) & 1u)) >> 16);  // RNE
}
__device__ __forceinline__ float fexp2(float x) {
#if __has_builtin(__builtin_amdgcn_exp2f)
  return __builtin_amdgcn_exp2f(x);
#else
  return exp2f(x);
#endif
}

// async 16B global->LDS; lds base wave-uniform, lane l lands at base + l*16.
__device__ __forceinline__ void gll16(const unsigned short* g, unsigned short* lds_base) {
  __builtin_amdgcn_global_load_lds(
      (const __attribute__((address_space(1))) void*)g,
      (__attribute__((address_space(3))) void*)lds_base, 16, 0, 0);
}

__device__ __forceinline__ ushort4 cvt4(float4 v) {
  ushort4 h;
  h.x = f2bf(v.x); h.y = f2bf(v.y); h.z = f2bf(v.z); h.w = f2bf(v.w);
  return h;
}

// ---------------------------------------------------------------------------
// f32 -> bf16 converts. cvt_k: single buffer. cvt2_k: x+Wqkv (contiguous
// dst). cvt3_k: x+Wqkv (contiguous dst) + Wo (separate dst).
// ---------------------------------------------------------------------------
__global__ void cvt_k(const float* __restrict__ src, unsigned short* __restrict__ dst, int n4)
{
  int i = blockIdx.x * blockDim.x + threadIdx.x;
  if (i < n4) ((ushort4*)dst)[i] = cvt4(((const float4*)src)[i]);
}

__global__ void cvt2_k(const float* __restrict__ a, const float* __restrict__ b,
                       unsigned short* __restrict__ dab, int na4, int n4)
{
  int i = blockIdx.x * blockDim.x + threadIdx.x;
  if (i >= n4) return;
  float4 v = (i < na4) ? ((const float4*)a)[i] : ((const float4*)b)[i - na4];
  ((ushort4*)dab)[i] = cvt4(v);
}

__global__ void cvt3_k(const float* __restrict__ a, const float* __restrict__ b,
                       const float* __restrict__ c,
                       unsigned short* __restrict__ dab, unsigned short* __restrict__ dc,
                       int na4, int nab4, int n4)
{
  int i = blockIdx.x * blockDim.x + threadIdx.x;
  if (i >= n4) return;
  if (i < nab4) {
    float4 v = (i < na4) ? ((const float4*)a)[i] : ((const float4*)b)[i - na4];
    ((ushort4*)dab)[i] = cvt4(v);
  } else {
    ((ushort4*)dc)[i - nab4] = cvt4(((const float4*)c)[i - nab4]);
  }
}

// ---------------------------------------------------------------------------
// m97-style NT GEMM (bf16 x bf16): C[M][N] = A[M][K]*Bw[N][K]^T + bias.
// 128x128 tile, BK=64, 2x2 waves of 64x64, 4x4 16x16x32 MFMA frags,
// global_load_lds width=16 staging, XOR-swizzled LDS columns.
// MODE 0: f32 row-major store. MODE 1: bf16 qkv scatter:
//   Q,K -> [bh][t][d] with FUSED ROPE (LDS pair-exchange; bit-identical to
//   the old store->rope_k path);  V -> TRANSPOSED [bh][d][t].
// MFMA layouts (HW-verified m89/m91): A: A[m=lane&15][k=quad*8+j];
// B: B[k=quad*8+j][n=lane&15]; C/D: col=lane&15, row=quad*4+reg.
// ---------------------------------------------------------------------------
template<int MODE>
__global__ __launch_bounds__(256, 2)
void gemm_bt(const unsigned short* __restrict__ A,
             const unsigned short* __restrict__ Bw,
             const float* __restrict__ bias,
             float* __restrict__ Cout,
             unsigned short* __restrict__ Qb,
             unsigned short* __restrict__ Kb,
             unsigned short* __restrict__ Vb,
             int N, int K)
{
  __shared__ unsigned short Lsh[128 * 128];   // 32 KB: Al|Bl during K-loop,
  unsigned short* const Al = Lsh;             // 128x128 rope tile in epilogue
  unsigned short* const Bl = Lsh + 128 * 64;
  const int tid  = threadIdx.x;
  const int wave = tid >> 6, lane = tid & 63;
  const int quad = lane >> 4, l15 = lane & 15;
  const int wm = wave >> 1, wn = wave & 1;
  const int n0 = blockIdx.x * 128, m0 = blockIdx.y * 128;

  f32x4 acc[4][4];
#pragma unroll
  for (int i = 0; i < 4; i++)
#pragma unroll
    for (int j = 0; j < 4; j++) acc[i][j] = (f32x4){0.f, 0.f, 0.f, 0.f};

  for (int k0 = 0; k0 < K; k0 += 64) {
    __syncthreads();
    const unsigned short* Ag = A + (size_t)m0 * K + k0;
    const unsigned short* Bg = Bw + (size_t)n0 * K + k0;
#pragma unroll
    for (int i = 0; i < 4; i++) {
      int cc = i * 256 + wave * 64 + lane;      // LDS 16B-slot id, 0..1023
      int r = cc >> 3;
      int c8 = (cc & 7) ^ (r & 7);              // swizzled source col chunk
      gll16(Ag + (size_t)r * K + c8 * 8, &Al[(i * 4 + wave) * 512]);
      gll16(Bg + (size_t)r * K + c8 * 8, &Bl[(i * 4 + wave) * 512]);
    }
    __syncthreads();
#pragma unroll
    for (int kc = 0; kc < 2; kc++) {
      // swizzled col offset: row&7 == l15&7 for all mi/ni (offsets are *8)
      const int csw = (((kc * 4 + quad) ^ (l15 & 7)) * 8);
      short8 af[4], bfr[4];
#pragma unroll
      for (int mi = 0; mi < 4; mi++)
        af[mi] = *(const short8*)&Al[(wm * 64 + mi * 16 + l15) * 64 + csw];
#pragma unroll
      for (int ni = 0; ni < 4; ni++)
        bfr[ni] = *(const short8*)&Bl[(wn * 64 + ni * 16 + l15) * 64 + csw];
#pragma unroll
      for (int mi = 0; mi < 4; mi++)
#pragma unroll
        for (int ni = 0; ni < 4; ni++)
          acc[mi][ni] = __builtin_amdgcn_mfma_f32_16x16x32_bf16(af[mi], bfr[ni], acc[mi][ni], 0, 0, 0);
    }
  }

  if constexpr (MODE == 0) {
#pragma unroll
    for (int mi = 0; mi < 4; mi++)
#pragma unroll
      for (int ni = 0; ni < 4; ni++) {
        int col = n0 + wn * 64 + ni * 16 + l15;
        float bv = bias[col];
#pragma unroll
        for (int r = 0; r < 4; r++) {
          int row = m0 + wm * 64 + mi * 16 + quad * 4 + r;
          Cout[(size_t)row * N + col] = acc[mi][ni][r] + bv;
        }
      }
  } else {
    const int which = n0 >> 11;      // block never straddles Q/K/V
    const int h = (n0 >> 7) & 15;    // block covers exactly one head
    unsigned short* P = (which == 0) ? Qb : (which == 1) ? Kb : Vb;
    if (which == 2) {
      // V: transposed scatter (unchanged)
#pragma unroll
      for (int mi = 0; mi < 4; mi++)
#pragma unroll
        for (int ni = 0; ni < 4; ni++) {
          int d = wn * 64 + ni * 16 + l15;
          float bv = bias[n0 + d];
#pragma unroll
          for (int r = 0; r < 4; r++) {
            int m = m0 + wm * 64 + mi * 16 + quad * 4 + r;
            int b = m >> 11, t = m & (T_ - 1);
            P[((size_t)((b * H_ + h) * HD_ + d)) * T_ + t] = f2bf(acc[mi][ni][r] + bv);
          }
        }
    } else {
      // Q/K: fused rope via LDS pair-exchange. Stage 1: bf16(acc+bias) into
      // Lsh[row][col] (value-identical to the old global store). Stage 2:
      // read pair (d, d+64), rotate in f32, (Q: scale), store — identical
      // float expressions to the old rope_k.
      __syncthreads();                 // all Al/Bl reads complete
#pragma unroll
      for (int mi = 0; mi < 4; mi++)
#pragma unroll
        for (int ni = 0; ni < 4; ni++) {
          int colL = wn * 64 + ni * 16 + l15;
          float bv = bias[n0 + colL];
#pragma unroll
          for (int r = 0; r < 4; r++) {
            int rowL = wm * 64 + mi * 16 + quad * 4 + r;
            Lsh[rowL * 128 + colL] = f2bf(acc[mi][ni][r] + bv);
          }
        }
      __syncthreads();
      const int d  = tid & 63;
      const int c0 = tid >> 6;
      const float theta = expf(-exp2f((float)d) * 0.07195578415606394f); // ln(1e4)/128
      const float QS = 0.08838834764831845f * 1.4426950408889634f; // 1/sqrt(128)*log2(e)
#pragma unroll
      for (int i = 0; i < 32; i++) {
        int rowL = c0 * 32 + i;
        int m = m0 + rowL;
        int b = m >> 11, t = m & (T_ - 1);
        float ang = (float)(t + 1) * theta;
        float cc = cosf(ang), ss = sinf(ang);
        float q0 = bf2f(Lsh[rowL * 128 + d]);
        float q1 = bf2f(Lsh[rowL * 128 + 64 + d]);
        float o0 = q0 * cc - q1 * ss;
        float o1 = q1 * cc + q0 * ss;
        if (which == 0) { o0 *= QS; o1 *= QS; }
        size_t base = ((size_t)((b * H_ + h) * T_ + t)) * HD_;
        P[base + d]      = f2bf(o0);
        P[base + 64 + d] = f2bf(o1);
      }
    }
  }
}

// ---------------------------------------------------------------------------
// RoPE in-place on bf16 Q and K — retained for the fallback (gemm_nt) path.
// ---------------------------------------------------------------------------
__global__ void rope_k(unsigned short* __restrict__ Q, unsigned short* __restrict__ K)
{
  const int tid = threadIdx.x;
  const int w = tid >> 6, l = tid & 63;
  const int r = blockIdx.x * 4 + w;
  const int t = r & (T_ - 1);
  const float pos = (float)(t + 1);
  const float theta = expf(-exp2f((float)l) * 0.07195578415606394f); // ln(1e4)/128
  const float ang = pos * theta;
  const float c = cosf(ang), s = sinf(ang);
  const float QS = 0.08838834764831845f * 1.4426950408889634f; // 1/sqrt(128)*log2(e)
  const size_t base = (size_t)r * HD_;

  float q0 = bf2f(Q[base + l]), q1 = bf2f(Q[base + l + 64]);
  Q[base + l]      = f2bf((q0 * c - q1 * s) * QS);
  Q[base + l + 64] = f2bf((q1 * c + q0 * s) * QS);
  float k0 = bf2f(K[base + l]), k1 = bf2f(K[base + l + 64]);
  K[base + l]      = f2bf(k0 * c - k1 * s);
  K[base + l + 64] = f2bf(k1 * c + k0 * s);
}

// ---------------------------------------------------------------------------
// Flash-style causal attention — r9-proven (round-0 structure + safe trims).
// Grid 512 = (bh 32, XCD-swizzled) x (qpair 16); each block does Q-tiles
// qp*64 and (31-qp)*64 -> uniform 33 k-iters. 4 waves x 16 rows.
// Kl [64][128]: slot (r,c16) holds global (r, c16^(r&15)); read col-chunk
// (kc*4+quad)^l15. Vl [128][64]: slot (r,c8) holds (r, c8^(r&7)); read
// (kc*4+quad)^(l15&7). Both -> residual 2-way bank aliasing (free).
// ---------------------------------------------------------------------------
__global__ __launch_bounds__(256, 2)
void attn_k(const unsigned short* __restrict__ Q,
            const unsigned short* __restrict__ K,
            const unsigned short* __restrict__ Vt_g,
            unsigned short* __restrict__ AO)
{
  __shared__ unsigned short Kl[64 * 128];
  __shared__ unsigned short Vl[128 * 64];
  __shared__ unsigned short Pl[4 * 16 * 72];

  const int tid  = threadIdx.x;
  const int wave = tid >> 6, lane = tid & 63;
  const int quad = lane >> 4, l15 = lane & 15;
  const int blk = blockIdx.x;
  const int bh = (blk & 7) + 8 * ((blk >> 3) & 3);
  const int qp = (blk >> 5) & 15;
  const unsigned short* Qh = Q    + (size_t)bh * T_ * HD_;
  const unsigned short* Kh = K    + (size_t)bh * T_ * HD_;
  const unsigned short* Vh = Vt_g + (size_t)bh * T_ * HD_;  // [d][t]
  const int b = bh >> 4, h = bh & 15;

#pragma unroll
  for (int tile = 0; tile < 2; tile++) {
    const int q0 = (tile == 0 ? qp : 31 - qp) * 64;
    const int wq = q0 + wave * 16;
    short8 qf[4];
#pragma unroll
    for (int kc = 0; kc < 4; kc++)
      qf[kc] = *(const short8*)&Qh[(size_t)(wq + l15) * HD_ + kc * 32 + quad * 8];

    f32x4 oacc[8];
#pragma unroll
    for (int n = 0; n < 8; n++) oacc[n] = (f32x4){0.f, 0.f, 0.f, 0.f};
    float mst[4], lst[4];
#pragma unroll
    for (int r = 0; r < 4; r++) { mst[r] = -1e30f; lst[r] = 0.f; }

    const int niter = (q0 >> 6) + 1;
    for (int it = 0; it < niter; it++) {
      const int kt = it * 64;
      __syncthreads();
      // stage K [64][128] and V^T [128][64], source-col XOR swizzle
#pragma unroll
      for (int i = 0; i < 4; i++) {
        int cc = i * 256 + wave * 64 + lane;  // slot id 0..1023
        int kr = cc >> 4, kcs = (cc & 15) ^ (kr & 15);
        gll16(Kh + (size_t)(kt + kr) * HD_ + kcs * 8, &Kl[(i * 4 + wave) * 512]);
        int vr = cc >> 3, vcs = (cc & 7) ^ (vr & 7);
        gll16(Vh + (size_t)vr * T_ + kt + vcs * 8, &Vl[(i * 4 + wave) * 512]);
      }
      __syncthreads();

      // S' = (Q*s) K^T
      f32x4 sa[4];
#pragma unroll
      for (int ni = 0; ni < 4; ni++) sa[ni] = (f32x4){0.f, 0.f, 0.f, 0.f};
#pragma unroll
      for (int kc = 0; kc < 4; kc++) {
        const int cswK = (((kc * 4 + quad) ^ l15) * 8);
        short8 bfr[4];
#pragma unroll
        for (int ni = 0; ni < 4; ni++)
          bfr[ni] = *(const short8*)&Kl[(ni * 16 + l15) * HD_ + cswK];
#pragma unroll
        for (int ni = 0; ni < 4; ni++)
          sa[ni] = __builtin_amdgcn_mfma_f32_16x16x32_bf16(qf[kc], bfr[ni], sa[ni], 0, 0, 0);
      }

      if (kt == q0) {   // causal mask, diagonal tile only (uniform branch)
#pragma unroll
        for (int ni = 0; ni < 4; ni++) {
          int gcol = kt + ni * 16 + l15;
#pragma unroll
          for (int r = 0; r < 4; r++) {
            int grow = wq + quad * 4 + r;
            if (gcol > grow) sa[ni][r] = -1e30f;
          }
        }
      }

      // online softmax, base-2. (sa <= rmax <= mst by construction -> no
      // clamps; exp2 of -1e30 underflows to 0 correctly.)
      float rmax[4] = {-1e30f, -1e30f, -1e30f, -1e30f};
#pragma unroll
      for (int ni = 0; ni < 4; ni++)
#pragma unroll
        for (int r = 0; r < 4; r++) rmax[r] = fmaxf(rmax[r], sa[ni][r]);
#pragma unroll
      for (int r = 0; r < 4; r++)
#pragma unroll
        for (int off = 1; off < 16; off <<= 1)
          rmax[r] = fmaxf(rmax[r], __shfl_xor(rmax[r], off));
      // alpha-skip: if no row's max grew, alpha == 1 exactly -> skip the
      // rescale (bitwise-identical result).
      int grew = (rmax[0] > mst[0]) | (rmax[1] > mst[1]) |
                 (rmax[2] > mst[2]) | (rmax[3] > mst[3]);
      if (__any(grew)) {
        float alpha[4];
#pragma unroll
        for (int r = 0; r < 4; r++) {
          float mnew = fmaxf(mst[r], rmax[r]);
          alpha[r] = fexp2(mst[r] - mnew);
          mst[r] = mnew;
          lst[r] *= alpha[r];
        }
#pragma unroll
        for (int nv = 0; nv < 8; nv++)
#pragma unroll
          for (int r = 0; r < 4; r++) oacc[nv][r] *= alpha[r];
      }
      float rsum[4] = {0.f, 0.f, 0.f, 0.f};
#pragma unroll
      for (int ni = 0; ni < 4; ni++)
#pragma unroll
        for (int r = 0; r < 4; r++) {
          float p = fexp2(sa[ni][r] - mst[r]);
          sa[ni][r] = p;
          rsum[r] += p;
        }
#pragma unroll
      for (int r = 0; r < 4; r++) {
#pragma unroll
        for (int off = 1; off < 16; off <<= 1)
          rsum[r] += __shfl_xor(rsum[r], off);
        lst[r] += rsum[r];
      }
      // P -> LDS (wave-private region; per-wave DS ops in-order, so
      // lgkmcnt(0) suffices -- no block barrier between write and read).
#pragma unroll
      for (int ni = 0; ni < 4; ni++)
#pragma unroll
        for (int r = 0; r < 4; r++)
          Pl[wave * 16 * 72 + (quad * 4 + r) * 72 + ni * 16 + l15] = f2bf(sa[ni][r]);
      LGKM0();

      // O += P V
      short8 pf[2];
#pragma unroll
      for (int kc = 0; kc < 2; kc++)
        pf[kc] = *(const short8*)&Pl[wave * 16 * 72 + l15 * 72 + kc * 32 + quad * 8];
#pragma unroll
      for (int kc = 0; kc < 2; kc++) {
        const int cswV = (((kc * 4 + quad) ^ (l15 & 7)) * 8);
#pragma unroll
        for (int nv = 0; nv < 8; nv++) {
          short8 vb = *(const short8*)&Vl[(nv * 16 + l15) * 64 + cswV];
          oacc[nv] = __builtin_amdgcn_mfma_f32_16x16x32_bf16(pf[kc], vb, oacc[nv], 0, 0, 0);
        }
      }
    }

    float linv[4];
#pragma unroll
    for (int r = 0; r < 4; r++) linv[r] = 1.0f / fmaxf(lst[r], 1e-20f);
#pragma unroll
    for (int nv = 0; nv < 8; nv++)
#pragma unroll
      for (int r = 0; r < 4; r++) {
        int t = wq + quad * 4 + r;
        int d = nv * 16 + l15;
        AO[((size_t)(b * T_ + t)) * C_ + h * HD_ + d] = f2bf(oacc[nv][r] * linv[r]);
      }
  }
}

// ---------------------------------------------------------------------------
// Fallback GEMM (f32 sources converted during staging) — only if ws too small.
// ---------------------------------------------------------------------------
template<int A32, int B32, int MODE>
__global__ __launch_bounds__(256, 2)
void gemm_nt(const void* __restrict__ Ap, const void* __restrict__ Bp,
             const float* __restrict__ bias,
             float* __restrict__ Cout,
             unsigned short* __restrict__ Qb,
             unsigned short* __restrict__ Kb,
             unsigned short* __restrict__ Vb,
             int N, int K)
{
  __shared__ unsigned short Al[128 * 72];
  __shared__ unsigned short Bl[128 * 72];
  const int tid  = threadIdx.x;
  const int wave = tid >> 6, lane = tid & 63;
  const int quad = lane >> 4, l15 = lane & 15;
  const int wm = wave >> 1, wn = wave & 1;
  const int n0 = blockIdx.x * 128, m0 = blockIdx.y * 128;

  f32x4 acc[4][4];
#pragma unroll
  for (int i = 0; i < 4; i++)
#pragma unroll
    for (int j = 0; j < 4; j++) acc[i][j] = (f32x4){0.f, 0.f, 0.f, 0.f};

  for (int k0 = 0; k0 < K; k0 += 64) {
    __syncthreads();
    if constexpr (A32) {
      const float* A = (const float*)Ap;
#pragma unroll
      for (int i = 0; i < 8; i++) {
        int cid = tid + i * 256;
        int r = cid >> 4, c = cid & 15;
        float4 v = *(const float4*)&A[(size_t)(m0 + r) * K + k0 + c * 4];
        *(ushort4*)&Al[r * 72 + c * 4] = cvt4(v);
      }
    } else {
      const unsigned short* A = (const unsigned short*)Ap;
#pragma unroll
      for (int i = 0; i < 4; i++) {
        int cid = tid + i * 256;
        int r = cid >> 3, c = cid & 7;
        *(float4*)&Al[r * 72 + c * 8] =
            *(const float4*)&A[(size_t)(m0 + r) * K + k0 + c * 8];
      }
    }
    if constexpr (B32) {
      const float* Bm = (const float*)Bp;
#pragma unroll
      for (int i = 0; i < 8; i++) {
        int cid = tid + i * 256;
        int r = cid >> 4, c = cid & 15;
        float4 v = *(const float4*)&Bm[(size_t)(n0 + r) * K + k0 + c * 4];
        *(ushort4*)&Bl[r * 72 + c * 4] = cvt4(v);
      }
    } else {
      const unsigned short* Bm = (const unsigned short*)Bp;
#pragma unroll
      for (int i = 0; i < 4; i++) {
        int cid = tid + i * 256;
        int r = cid >> 3, c = cid & 7;
        *(float4*)&Bl[r * 72 + c * 8] =
            *(const float4*)&Bm[(size_t)(n0 + r) * K + k0 + c * 8];
      }
    }
    __syncthreads();
#pragma unroll
    for (int kc = 0; kc < 2; kc++) {
      short8 af[4], bfr[4];
#pragma unroll
      for (int mi = 0; mi < 4; mi++)
        af[mi] = *(const short8*)&Al[(wm * 64 + mi * 16 + l15) * 72 + kc * 32 + quad * 8];
#pragma unroll
      for (int ni = 0; ni < 4; ni++)
        bfr[ni] = *(const short8*)&Bl[(wn * 64 + ni * 16 + l15) * 72 + kc * 32 + quad * 8];
#pragma unroll
      for (int mi = 0; mi < 4; mi++)
#pragma unroll
        for (int ni = 0; ni < 4; ni++)
          acc[mi][ni] = __builtin_amdgcn_mfma_f32_16x16x32_bf16(af[mi], bfr[ni], acc[mi][ni], 0, 0, 0);
    }
  }

  if constexpr (MODE == 0) {
#pragma unroll
    for (int mi = 0; mi < 4; mi++)
#pragma unroll
      for (int ni = 0; ni < 4; ni++) {
        int col = n0 + wn * 64 + ni * 16 + l15;
        float bv = bias[col];
#pragma unroll
        for (int r = 0; r < 4; r++) {
          int row = m0 + wm * 64 + mi * 16 + quad * 4 + r;
          Cout[(size_t)row * N + col] = acc[mi][ni][r] + bv;
        }
      }
  } else {
    int which = n0 >> 11;
    int h = (n0 >> 7) & 15;
    unsigned short* P = (which == 0) ? Qb : (which == 1) ? Kb : Vb;
#pragma unroll
    for (int mi = 0; mi < 4; mi++)
#pragma unroll
      for (int ni = 0; ni < 4; ni++) {
        int d = wn * 64 + ni * 16 + l15;
        float bv = bias[n0 + d];
#pragma unroll
        for (int r = 0; r < 4; r++) {
          int m = m0 + wm * 64 + mi * 16 + quad * 4 + r;
          int b = m >> 11, t = m & (T_ - 1);
          size_t addr = (which == 2)
              ? ((size_t)((b * H_ + h) * HD_ + d)) * T_ + t
              : ((size_t)((b * H_ + h) * T_ + t)) * HD_ + d;
          P[addr] = f2bf(acc[mi][ni][r] + bv);
        }
      }
  }
}

// ---------------------------------------------------------------------------
extern "C" void kernel_launch(void* const* d_in, const int* in_sizes, int n_in,
                              void* d_out, int out_size, void* d_ws, size_t ws_size,
                              hipStream_t stream)
{
  const float* x    = (const float*)d_in[0];  // [2,2048,2048] f32
  const float* Wqkv = (const float*)d_in[1];  // [6144,2048]   f32
  const float* bqkv = (const float*)d_in[2];  // [6144]        f32
  const float* Wo   = (const float*)d_in[3];  // [2048,2048]   f32
  const float* bo   = (const float*)d_in[4];  // [2048]        f32
  float* out = (float*)d_out;                 // [2,2048,2048] f32

  const size_t SZ   = (size_t)B_ * H_ * T_ * HD_;   // 8,388,608
  const size_t NX   = SZ;
  const size_t NWQ  = (size_t)3 * C_ * C_;
  const size_t NWO  = (size_t)C_ * C_;
  unsigned short* ws = (unsigned short*)d_ws;

  dim3 blk(256, 1, 1);
  const size_t need  = (NX + NWQ + 3 * SZ) * sizeof(unsigned short);  // 92.3 MB
  const size_t need2 = need + NWO * sizeof(unsigned short);           // +8.4 MB

  if (ws_size >= need) {
    unsigned short* xb    = ws;
    unsigned short* Wqkvb = xb + NX;
    unsigned short* Qb    = Wqkvb + NWQ;
    unsigned short* Kb    = Qb + SZ;
    unsigned short* Vb    = Kb + SZ;      // transposed [bh][d][t]
    unsigned short* AO    = xb;           // alias: x dead after QKV GEMM
    const bool sepWo = (ws_size >= need2);
    unsigned short* Wob = sepWo ? (Vb + SZ) : Wqkvb;  // alias if tight

    if (sepWo) {
      // single convert pass for x, Wqkv, Wo (4 launches total)
      cvt3_k<<<dim3((unsigned)((NX + NWQ + NWO) / 1024)), blk, 0, stream>>>(
          x, Wqkv, Wo, xb, Wob,
          (int)(NX / 4), (int)((NX + NWQ) / 4), (int)((NX + NWQ + NWO) / 4));
      gemm_bt<1><<<dim3(48, 32, 1), blk, 0, stream>>>(
          xb, Wqkvb, bqkv, nullptr, Qb, Kb, Vb, 6144, 2048);  // rope fused
    } else {
      cvt2_k<<<dim3((unsigned)((NX + NWQ) / 1024)), blk, 0, stream>>>(
          x, Wqkv, xb, (int)(NX / 4), (int)((NX + NWQ) / 4));
      gemm_bt<1><<<dim3(48, 32, 1), blk, 0, stream>>>(
          xb, Wqkvb, bqkv, nullptr, Qb, Kb, Vb, 6144, 2048);  // rope fused
      cvt_k<<<dim3((unsigned)(NWO / 1024)), blk, 0, stream>>>(Wo, Wob, (int)(NWO / 4));
    }
    attn_k<<<dim3(512, 1, 1), blk, 0, stream>>>(Qb, Kb, Vb, AO);
    gemm_bt<0><<<dim3(16, 32, 1), blk, 0, stream>>>(
        AO, Wob, bo, out, nullptr, nullptr, nullptr, 2048, 2048);
  } else {
    unsigned short* Qb = ws;
    unsigned short* Kb = Qb + SZ;
    unsigned short* Vb = Kb + SZ;
    unsigned short* AO = Vb + SZ;
    gemm_nt<1, 1, 1><<<dim3(48, 32, 1), blk, 0, stream>>>(
        (const void*)x, (const void*)Wqkv, bqkv, nullptr, Qb, Kb, Vb, 6144, 2048);
    rope_k<<<dim3((B_ * H_ * T_) / 4, 1, 1), blk, 0, stream>>>(Qb, Kb);
    attn_k<<<dim3(512, 1, 1), blk, 0, stream>>>(Qb, Kb, Vb, AO);
    gemm_nt<0, 1, 0><<<dim3(16, 32, 1), blk, 0, stream>>>(
        (const void*)AO, (const void*)Wo, bo, out, nullptr, nullptr, nullptr, 2048, 2048);
  }
}